// Round 19
// baseline (3373.412 us; speedup 1.0000x reference)
//
#include <hip/hip_runtime.h>
#include <math.h>

#define BB   2048
#define NN_  768
#define MM   3072
#define LAMBD 0.1f

typedef __attribute__((ext_vector_type(8))) _Float16 half8;
typedef __attribute__((ext_vector_type(4))) float  f32x4;
typedef __attribute__((ext_vector_type(4))) unsigned short us4;

union HB { _Float16 f; unsigned short u; };
struct HL { unsigned short h, l; };

__device__ __forceinline__ unsigned short h_bits(float f) {
    HB b; b.f = (_Float16)f; return b.u;
}
__device__ __forceinline__ HL split2h(float f) {
    HL r;
    HB b; b.f = (_Float16)f;
    r.h = b.u;
    const float fh = (float)b.f;
    HB c; c.f = (_Float16)(f - fh);
    r.l = c.u;
    return r;
}
__device__ __forceinline__ float clampl(float x) {
    return fminf(fmaxf(x, -LAMBD), LAMBD);
}
__device__ __forceinline__ float4 cvt4h(const unsigned short* p) {
    const us4 u = *(const us4*)p;
    HB a, b, c, d;
    a.u = u.x; b.u = u.y; c.u = u.z; d.u = u.w;
    float4 f;
    f.x = (float)a.f; f.y = (float)b.f; f.z = (float)c.f; f.w = (float)d.f;
    return f;
}

// ---------------------------------------------------------------------------
// Split-K small GEMM (768x768 out, fp16 3-term), 64x64 tile, BK=64,
// reg-prefetch, single LDS buffer + transposed epilogue. Grid: (12, 12, KS).
// ---------------------------------------------------------------------------
template<int APRE>
__global__ __launch_bounds__(256)
void gemm_sk(const float* __restrict__ A,
             const unsigned short* __restrict__ Ah,
             const unsigned short* __restrict__ Al,
             int lda,
             const unsigned short* __restrict__ Bh,
             const unsigned short* __restrict__ Bl,
             int ldb,
             float* __restrict__ P, int Kper)
{
    __shared__ __align__(16) char smem[36864];
    unsigned short (*AsH)[72] = (unsigned short (*)[72])(smem);
    unsigned short (*AsL)[72] = (unsigned short (*)[72])(smem + 9216);
    unsigned short (*BsH)[72] = (unsigned short (*)[72])(smem + 18432);
    unsigned short (*BsL)[72] = (unsigned short (*)[72])(smem + 27648);

    const int tid  = threadIdx.x;
    const int brow = blockIdx.y * 64;
    const int bcol = blockIdx.x * 64;
    const int koff = blockIdx.z * Kper;
    const int wave = tid >> 6, lane = tid & 63;
    const int wr = wave >> 1, wc = wave & 1;
    const int lrow = lane & 15, kg = lane >> 4;

    uint4  rAh[2], rAl[2], rBh[2], rBl[2];
    float4 rAf[2][2];

    auto LOAD = [&](int k0) {
        #pragma unroll
        for (int p = 0; p < 2; ++p) {
            const int idx = p * 256 + tid;
            const int row = idx >> 3, k8 = (idx & 7) * 8;
            const size_t ga = (size_t)(brow + row) * lda + k0 + k8;
            const size_t gb = (size_t)(bcol + row) * ldb + k0 + k8;
            if constexpr (APRE) {
                rAh[p] = *(const uint4*)(Ah + ga);
                rAl[p] = *(const uint4*)(Al + ga);
            } else {
                rAf[p][0] = *(const float4*)(A + ga);
                rAf[p][1] = *(const float4*)(A + ga + 4);
            }
            rBh[p] = *(const uint4*)(Bh + gb);
            rBl[p] = *(const uint4*)(Bl + gb);
        }
    };
    auto STORE = [&]() {
        #pragma unroll
        for (int p = 0; p < 2; ++p) {
            const int idx = p * 256 + tid;
            const int row = idx >> 3, k8 = (idx & 7) * 8;
            if constexpr (APRE) {
                *(uint4*)&AsH[row][k8] = rAh[p];
                *(uint4*)&AsL[row][k8] = rAl[p];
            } else {
                half8 h0, l0;
                const float vf[8] = {rAf[p][0].x, rAf[p][0].y, rAf[p][0].z, rAf[p][0].w,
                                     rAf[p][1].x, rAf[p][1].y, rAf[p][1].z, rAf[p][1].w};
                #pragma unroll
                for (int j = 0; j < 8; ++j) {
                    const HL s = split2h(vf[j]);
                    HB hb, lb; hb.u = s.h; lb.u = s.l;
                    h0[j] = hb.f; l0[j] = lb.f;
                }
                *(half8*)&AsH[row][k8] = h0;
                *(half8*)&AsL[row][k8] = l0;
            }
            *(uint4*)&BsH[row][k8] = rBh[p];
            *(uint4*)&BsL[row][k8] = rBl[p];
        }
    };

    f32x4 acc[2][2];
    #pragma unroll
    for (int m = 0; m < 2; ++m)
        #pragma unroll
        for (int n = 0; n < 2; ++n)
            #pragma unroll
            for (int q = 0; q < 4; ++q) acc[m][n][q] = 0.0f;

    const int NK = Kper / 64;
    LOAD(koff);
    STORE();
    __syncthreads();

    for (int ki = 0; ki < NK; ++ki) {
        if (ki + 1 < NK) LOAD(koff + (ki + 1) * 64);

        #pragma unroll
        for (int sub = 0; sub < 2; ++sub) {
            const int kc = sub * 32 + kg * 8;
            half8 ahi[2], alo[2], bhi[2], blo[2];
            #pragma unroll
            for (int m = 0; m < 2; ++m) {
                const int r = wr * 32 + m * 16 + lrow;
                ahi[m] = *(const half8*)&AsH[r][kc];
                alo[m] = *(const half8*)&AsL[r][kc];
            }
            #pragma unroll
            for (int n = 0; n < 2; ++n) {
                const int c = wc * 32 + n * 16 + lrow;
                bhi[n] = *(const half8*)&BsH[c][kc];
                blo[n] = *(const half8*)&BsL[c][kc];
            }
            #pragma unroll
            for (int m = 0; m < 2; ++m)
                #pragma unroll
                for (int n = 0; n < 2; ++n) {
                    acc[m][n] = __builtin_amdgcn_mfma_f32_16x16x32_f16(ahi[m], bhi[n], acc[m][n], 0, 0, 0);
                    acc[m][n] = __builtin_amdgcn_mfma_f32_16x16x32_f16(ahi[m], blo[n], acc[m][n], 0, 0, 0);
                    acc[m][n] = __builtin_amdgcn_mfma_f32_16x16x32_f16(alo[m], bhi[n], acc[m][n], 0, 0, 0);
                }
        }
        __syncthreads();
        if (ki + 1 < NK) { STORE(); __syncthreads(); }
    }

    // transposed epilogue: acc -> LDS [64][65] -> coalesced float4 rows
    float* eb = (float*)smem;
    #pragma unroll
    for (int m = 0; m < 2; ++m)
        #pragma unroll
        for (int n = 0; n < 2; ++n)
            #pragma unroll
            for (int r = 0; r < 4; ++r)
                eb[(wr * 32 + m * 16 + kg * 4 + r) * 65 + wc * 32 + n * 16 + lrow] = acc[m][n][r];
    __syncthreads();
    float* Pk = P + (size_t)blockIdx.z * NN_ * NN_;
    #pragma unroll
    for (int j = 0; j < 4; ++j) {
        const int row = wave * 16 + j * 4 + (lane >> 4);
        const int col = (lane & 15) * 4;
        const float4 v = *(const float4*)&eb[row * 65 + col];
        *(float4*)(Pk + (size_t)(brow + row) * NN_ + bcol + col) = v;
    }
}

// Reduce 4 split-K partials with epilogue. MODE: 0 plain, 1 +I, 2 2*E1-sum.
template<int MODE>
__global__ __launch_bounds__(256)
void red_ns(const float* __restrict__ P,
            const float* __restrict__ E1,
            float* __restrict__ C,
            unsigned short* __restrict__ Ch,
            unsigned short* __restrict__ Cl)
{
    const size_t i4 = ((size_t)blockIdx.x * 256 + threadIdx.x) * 4;
    const size_t sz = (size_t)NN_ * NN_;
    float4 s = *(const float4*)(P + i4);
    const float4 s1 = *(const float4*)(P + sz + i4);
    const float4 s2 = *(const float4*)(P + 2 * sz + i4);
    const float4 s3 = *(const float4*)(P + 3 * sz + i4);
    s.x = (s.x + s1.x) + (s2.x + s3.x);
    s.y = (s.y + s1.y) + (s2.y + s3.y);
    s.z = (s.z + s1.z) + (s2.z + s3.z);
    s.w = (s.w + s1.w) + (s2.w + s3.w);
    float v[4] = {s.x, s.y, s.z, s.w};
    if constexpr (MODE == 1) {
        const int row = (int)(i4 / NN_);
        const int col = (int)(i4 - (size_t)row * NN_);
        #pragma unroll
        for (int j = 0; j < 4; ++j) if (row == col + j) v[j] += 1.0f;
    }
    if constexpr (MODE == 2) {
        const float4 e = *(const float4*)(E1 + i4);
        v[0] = 2.0f * e.x - v[0]; v[1] = 2.0f * e.y - v[1];
        v[2] = 2.0f * e.z - v[2]; v[3] = 2.0f * e.w - v[3];
    }
    float4 o; o.x = v[0]; o.y = v[1]; o.z = v[2]; o.w = v[3];
    *(float4*)(C + i4) = o;
    us4 h, l;
    const HL a = split2h(v[0]), b = split2h(v[1]);
    const HL c = split2h(v[2]), d = split2h(v[3]);
    h.x = a.h; l.x = a.l; h.y = b.h; l.y = b.l;
    h.z = c.h; l.z = c.l; h.w = d.h; l.w = d.l;
    *(us4*)(Ch + i4) = h;
    *(us4*)(Cl + i4) = l;
}

// ---------------------------------------------------------------------------
// Big fp16 GEMM: 64x64 tile, 4 waves, template BK (64 or 128), reg-prefetch,
// single LDS buffer + transposed epilogue.
// AMODE: 0 f32 A -> cvt; 1 pre-cvt fp16 (Ah); 4 fp16 pair Ah/Ah+psz summed.
// BS: 1 = B single fp16; 0 = B 2-term h/l.
// EPI: 0 C=acc f32 (+EMIT); 3 ADMM w-update; 4 fp16 partial -> Y2[cks*ks+gi].
// EMIT: 0 none, 1 Y2=fp16, 2 EH/EL=split, 4 Y2+EH=fp16(acc), NO C.
// ---------------------------------------------------------------------------
template<int BK, int NBM, int NBN, int KS, int PM, int PN, int AMODE, int BS, int EPI, int EMIT, int LASTZ>
__global__ __launch_bounds__(256)
void gemm_big(const float* __restrict__ A,
              const unsigned short* __restrict__ Ah,
              int lda, size_t psz,
              const unsigned short* __restrict__ Bh,
              const unsigned short* __restrict__ Bl,
              int ldb,
              float* __restrict__ C, int ldc, size_t cks, int Kper,
              const unsigned short* __restrict__ F1h,
              unsigned short* __restrict__ Wh,
              float* __restrict__ OutZ,
              unsigned short* __restrict__ Y2,
              unsigned short* __restrict__ EH,
              unsigned short* __restrict__ EL)
{
    static_assert(NBM % PM == 0 && NBN % PN == 0, "patch divides grid");
    constexpr int XM = NBM / PM, XN = NBN / PN;
    static_assert(XM * XN * KS == 8, "patches x KS must equal 8 XCDs");
    static_assert(PM * PN == (NBM * NBN * KS) / 8, "slot count");
    constexpr int LDR = BK + 8;            // LDS row stride (elems)
    constexpr int CH  = BK / 32;           // uint4 chunks / thread / matrix
    constexpr int CPR = BK / 8;            // chunks per row
    constexpr int MSZ = 64 * LDR * 2;      // bytes per staged matrix
    constexpr int SMB_STAGE = (BS ? 2 : 3) * MSZ;
    constexpr int SMB = SMB_STAGE > 16640 ? SMB_STAGE : 16640;

    __shared__ __align__(16) char smem[SMB];
    unsigned short (*AsH)[LDR] = (unsigned short (*)[LDR])(smem);
    unsigned short (*BsH)[LDR] = (unsigned short (*)[LDR])(smem + MSZ);
    unsigned short (*BsL)[LDR] = (unsigned short (*)[LDR])(smem + 2 * MSZ);

    const int bid  = blockIdx.x;
    const int xcd  = bid & 7;
    const int slot = bid >> 3;
    const int ks   = xcd % KS;
    const int rest = xcd / KS;
    const int xn   = rest % XN;
    const int xm   = rest / XN;
    const int m_   = xm * PM + slot / PN;
    const int n_   = xn * PN + slot % PN;
    const int brow = m_ * 64;
    const int bcol = n_ * 64;
    const int koff = ks * Kper;

    const int tid  = threadIdx.x;
    const int wave = tid >> 6, lane = tid & 63;
    const int wr = wave >> 1, wc = wave & 1;
    const int lrow = lane & 15, kg = lane >> 4;

    uint4  pA[CH], pA2[CH], pB[CH], pB2[CH];
    float4 pF[2 * CH];

    auto LOAD = [&](int k0) {
        #pragma unroll
        for (int q = 0; q < CH; ++q) {
            const int idx = q * 256 + tid;
            const int row = idx / CPR, k8 = (idx % CPR) * 8;
            const size_t ga = (size_t)(brow + row) * lda + k0 + k8;
            if constexpr (AMODE == 1) {
                pA[q] = *(const uint4*)(Ah + ga);
            } else if constexpr (AMODE == 4) {
                pA[q]  = *(const uint4*)(Ah + ga);
                pA2[q] = *(const uint4*)(Ah + ga + psz);
            } else {
                pF[2 * q]     = *(const float4*)(A + ga);
                pF[2 * q + 1] = *(const float4*)(A + ga + 4);
            }
            const size_t gb = (size_t)(bcol + row) * ldb + k0 + k8;
            pB[q] = *(const uint4*)(Bh + gb);
            if constexpr (!BS) pB2[q] = *(const uint4*)(Bl + gb);
        }
    };
    auto STORE = [&]() {
        #pragma unroll
        for (int q = 0; q < CH; ++q) {
            const int idx = q * 256 + tid;
            const int row = idx / CPR, k8 = (idx % CPR) * 8;
            if constexpr (AMODE == 1) {
                *(uint4*)&AsH[row][k8] = pA[q];
            } else if constexpr (AMODE == 4) {
                half8 s = *(half8*)&pA[q] + *(half8*)&pA2[q];
                *(half8*)&AsH[row][k8] = s;
            } else {
                half8 h0;
                const float vf[8] = {pF[2*q].x, pF[2*q].y, pF[2*q].z, pF[2*q].w,
                                     pF[2*q+1].x, pF[2*q+1].y, pF[2*q+1].z, pF[2*q+1].w};
                #pragma unroll
                for (int j = 0; j < 8; ++j) h0[j] = (_Float16)vf[j];
                *(half8*)&AsH[row][k8] = h0;
            }
            *(uint4*)&BsH[row][k8] = pB[q];
            if constexpr (!BS) *(uint4*)&BsL[row][k8] = pB2[q];
        }
    };

    f32x4 acc[2][2];
    #pragma unroll
    for (int m = 0; m < 2; ++m)
        #pragma unroll
        for (int n = 0; n < 2; ++n)
            #pragma unroll
            for (int q = 0; q < 4; ++q) acc[m][n][q] = 0.0f;

    const int NK = Kper / BK;
    LOAD(koff);
    STORE();
    __syncthreads();

    for (int ki = 0; ki < NK; ++ki) {
        if (ki + 1 < NK) LOAD(koff + (ki + 1) * BK);

        #pragma unroll
        for (int sub = 0; sub < BK / 32; ++sub) {
            const int kc = sub * 32 + kg * 8;
            half8 a[2], bh[2], bl[2];
            #pragma unroll
            for (int m = 0; m < 2; ++m)
                a[m] = *(const half8*)&AsH[wr * 32 + m * 16 + lrow][kc];
            #pragma unroll
            for (int n = 0; n < 2; ++n) {
                const int c = wc * 32 + n * 16 + lrow;
                bh[n] = *(const half8*)&BsH[c][kc];
                if constexpr (!BS) bl[n] = *(const half8*)&BsL[c][kc];
            }
            #pragma unroll
            for (int m = 0; m < 2; ++m)
                #pragma unroll
                for (int n = 0; n < 2; ++n) {
                    acc[m][n] = __builtin_amdgcn_mfma_f32_16x16x32_f16(a[m], bh[n], acc[m][n], 0, 0, 0);
                    if constexpr (!BS)
                        acc[m][n] = __builtin_amdgcn_mfma_f32_16x16x32_f16(a[m], bl[n], acc[m][n], 0, 0, 0);
                }
        }
        __syncthreads();
        if (ki + 1 < NK) { STORE(); __syncthreads(); }
    }

    // ---- transposed epilogue: acc -> LDS [64][65] -> whole-row float4 I/O ----
    float* eb = (float*)smem;
    #pragma unroll
    for (int m = 0; m < 2; ++m)
        #pragma unroll
        for (int n = 0; n < 2; ++n)
            #pragma unroll
            for (int r = 0; r < 4; ++r)
                eb[(wr * 32 + m * 16 + kg * 4 + r) * 65 + wc * 32 + n * 16 + lrow] = acc[m][n][r];
    __syncthreads();

    #pragma unroll
    for (int j = 0; j < 4; ++j) {
        const int row = wave * 16 + j * 4 + (lane >> 4);
        const int col = (lane & 15) * 4;
        const float4 v = *(const float4*)&eb[row * 65 + col];
        const size_t gi = (size_t)(brow + row) * ldc + bcol + col;
        if constexpr (EPI == 0) {
            if constexpr (EMIT != 4)
                *(float4*)(C + cks * ks + gi) = v;
            if constexpr (EMIT == 1) {
                us4 h;
                h.x = h_bits(v.x); h.y = h_bits(v.y);
                h.z = h_bits(v.z); h.w = h_bits(v.w);
                *(us4*)(Y2 + gi) = h;
            }
            if constexpr (EMIT == 2) {
                const HL a = split2h(v.x), b = split2h(v.y);
                const HL c2 = split2h(v.z), d = split2h(v.w);
                us4 h, l;
                h.x = a.h; l.x = a.l; h.y = b.h; l.y = b.l;
                h.z = c2.h; l.z = c2.l; h.w = d.h; l.w = d.l;
                *(us4*)(EH + gi) = h;
                *(us4*)(EL + gi) = l;
            }
            if constexpr (EMIT == 4) {
                us4 h;
                h.x = h_bits(v.x); h.y = h_bits(v.y);
                h.z = h_bits(v.z); h.w = h_bits(v.w);
                *(us4*)(Y2 + gi) = h;
                *(us4*)(EH + gi) = h;
            }
        } else if constexpr (EPI == 4) {
            us4 h;
            h.x = h_bits(v.x); h.y = h_bits(v.y);
            h.z = h_bits(v.z); h.w = h_bits(v.w);
            *(us4*)(Y2 + cks * ks + gi) = h;
        } else { // EPI == 3
            const float4 f1 = cvt4h(F1h + gi);
            const float4 ww = cvt4h(Wh + gi);
            const float f1v[4] = {f1.x, f1.y, f1.z, f1.w};
            const float wwv[4] = {ww.x, ww.y, ww.z, ww.w};
            const float vv[4]  = {v.x, v.y, v.z, v.w};
            float wn[4];
            #pragma unroll
            for (int q = 0; q < 4; ++q)
                wn[q] = f1v[q] + wwv[q] - clampl(wwv[q]) - vv[q];
            if constexpr (LASTZ) {
                float4 o;
                o.x = wn[0] - clampl(wn[0]); o.y = wn[1] - clampl(wn[1]);
                o.z = wn[2] - clampl(wn[2]); o.w = wn[3] - clampl(wn[3]);
                *(float4*)(OutZ + gi) = o;
            } else {
                us4 hh, y;
                #pragma unroll
                for (int q = 0; q < 4; ++q) {
                    ((unsigned short*)&hh)[q] = h_bits(wn[q]);
                    ((unsigned short*)&y)[q]  = h_bits(f1v[q] + wn[q] - 2.0f * clampl(wn[q]));
                }
                *(us4*)(Wh + gi) = hh;
                *(us4*)(Y2 + gi) = y;
            }
        }
    }
}

// Normalize rows of weight (3072x768); emit fp16 h/l of wn (row-major only).
__global__ __launch_bounds__(256)
void rownorm_kernel(const float* __restrict__ W,
                    unsigned short* __restrict__ wnH, unsigned short* __restrict__ wnL)
{
    __shared__ float red[256];
    const int row = blockIdx.x;
    const int t = threadIdx.x;
    const float* wr = W + (size_t)row * NN_;
    float s = 0.0f;
    for (int k = t; k < NN_; k += 256) { const float w = wr[k]; s += w * w; }
    red[t] = s; __syncthreads();
    for (int off = 128; off > 0; off >>= 1) {
        if (t < off) red[t] += red[t + off];
        __syncthreads();
    }
    const float rn = 1.0f / sqrtf(red[0]);
    for (int k = t; k < NN_; k += 256) {
        const float v = wr[k] * rn;
        const HL s2 = split2h(v);
        wnH[(size_t)row * NN_ + k] = s2.h;
        wnL[(size_t)row * NN_ + k] = s2.l;
    }
}

// Tiled transpose: wn (3072x768) h/l -> wnT (768x3072) h/l, LDS-coalesced.
// Grid: (MM/64, NN_/64) = (48, 12).
__global__ __launch_bounds__(256)
void transp_kernel(const unsigned short* __restrict__ SH,
                   const unsigned short* __restrict__ SL,
                   unsigned short* __restrict__ DH,
                   unsigned short* __restrict__ DL)
{
    __shared__ unsigned short tH[64][68];
    __shared__ unsigned short tL[64][68];
    const int tid = threadIdx.x;
    const int r0 = blockIdx.x * 64;   // row in wn (3072-dim)
    const int c0 = blockIdx.y * 64;   // col in wn (768-dim)
    #pragma unroll
    for (int p = 0; p < 2; ++p) {
        const int idx = p * 256 + tid;
        const int r = idx >> 3, c8 = (idx & 7) * 8;
        const size_t g = (size_t)(r0 + r) * NN_ + c0 + c8;
        *(uint4*)&tH[r][c8] = *(const uint4*)(SH + g);
        *(uint4*)&tL[r][c8] = *(const uint4*)(SL + g);
    }
    __syncthreads();
    #pragma unroll
    for (int p = 0; p < 2; ++p) {
        const int idx = p * 256 + tid;
        const int k = idx >> 3, m8 = (idx & 7) * 8;
        us4 h0, h1, l0, l1;
        h0.x = tH[m8+0][k]; h0.y = tH[m8+1][k]; h0.z = tH[m8+2][k]; h0.w = tH[m8+3][k];
        h1.x = tH[m8+4][k]; h1.y = tH[m8+5][k]; h1.z = tH[m8+6][k]; h1.w = tH[m8+7][k];
        l0.x = tL[m8+0][k]; l0.y = tL[m8+1][k]; l0.z = tL[m8+2][k]; l0.w = tL[m8+3][k];
        l1.x = tL[m8+4][k]; l1.y = tL[m8+5][k]; l1.z = tL[m8+6][k]; l1.w = tL[m8+7][k];
        const size_t g = (size_t)(c0 + k) * MM + r0 + m8;
        *(us4*)(DH + g)     = h0;
        *(us4*)(DH + g + 4) = h1;
        *(us4*)(DL + g)     = l0;
        *(us4*)(DL + g + 4) = l1;
    }
}

__global__ __launch_bounds__(256)
void rowabs_kernel(const float* __restrict__ G, float* __restrict__ rowsum)
{
    __shared__ float red[256];
    const int row = blockIdx.x;
    const int t = threadIdx.x;
    const float* gr = G + (size_t)row * NN_;
    float s = 0.0f;
    for (int k = t; k < NN_; k += 256) s += fabsf(gr[k]);
    red[t] = s; __syncthreads();
    for (int off = 128; off > 0; off >>= 1) {
        if (t < off) red[t] += red[t + off];
        __syncthreads();
    }
    if (t == 0) rowsum[row] = red[0];
}

__global__ __launch_bounds__(256)
void cmax_kernel(const float* __restrict__ rowsum, float* __restrict__ cbuf)
{
    __shared__ float red[256];
    const int t = threadIdx.x;
    float mx = 0.0f;
    for (int k = t; k < NN_; k += 256) mx = fmaxf(mx, rowsum[k]);
    red[t] = mx; __syncthreads();
    for (int off = 128; off > 0; off >>= 1) {
        if (t < off) red[t] = fmaxf(red[t], red[t + off]);
        __syncthreads();
    }
    if (t == 0) cbuf[0] = 2.0f / (1.0f + red[0]);
}

__global__ __launch_bounds__(256)
void initdiag_kernel(float* __restrict__ X, const float* __restrict__ c)
{
    const int idx = blockIdx.x * 256 + threadIdx.x;
    const int p = idx / NN_, q = idx - p * NN_;
    X[idx] = (p == q) ? c[0] : 0.0f;
}

// dec = p0 + p1 (float4)
__global__ __launch_bounds__(256)
void add2_kernel(const float* __restrict__ p0, size_t ps, float* __restrict__ o)
{
    const size_t i = ((size_t)blockIdx.x * 256 + threadIdx.x) * 4;
    const float4 a = *(const float4*)(p0 + i);
    const float4 b = *(const float4*)(p0 + ps + i);
    float4 v;
    v.x = a.x + b.x; v.y = a.y + b.y;
    v.z = a.z + b.z; v.w = a.w + b.w;
    *(float4*)(o + i) = v;
}

extern "C" void kernel_launch(void* const* d_in, const int* in_sizes, int n_in,
                              void* d_out, int out_size, void* d_ws, size_t ws_size,
                              hipStream_t stream)
{
    const float* x = (const float*)d_in[0];   // (2048, 768)
    const float* w = (const float*)d_in[1];   // (3072, 768)

    float* out = (float*)d_out;
    float* z   = out;                          // (2048, 3072)
    float* dec = out + (size_t)BB * MM;        // (2048, 768)

    char* wsb = (char*)d_ws;
    size_t off = 0;
    auto alloc = [&](size_t bytes) -> void* {
        void* p = wsb + off;
        off += (bytes + 255) & ~(size_t)255;
        return p;
    };
    // --- persistent ---
    unsigned short* wnH  = (unsigned short*)alloc((size_t)MM * NN_ * 2);
    unsigned short* wnL  = (unsigned short*)alloc((size_t)MM * NN_ * 2);
    unsigned short* wnTH = (unsigned short*)alloc((size_t)MM * NN_ * 2);
    unsigned short* wnTL = (unsigned short*)alloc((size_t)MM * NN_ * 2);
    unsigned short* adh  = (unsigned short*)alloc((size_t)BB * MM * 2);  // fp16 adotb
    unsigned short* wbh  = (unsigned short*)alloc((size_t)BB * MM * 2);  // fp16 w state
    unsigned short* y2h  = (unsigned short*)alloc((size_t)BB * MM * 2);
    unsigned short* QH  = (unsigned short*)alloc((size_t)NN_ * NN_ * 2);
    unsigned short* QL  = (unsigned short*)alloc((size_t)NN_ * NN_ * 2);
    unsigned short* RTH = (unsigned short*)alloc((size_t)MM * NN_ * 2);
    unsigned short* RTL = (unsigned short*)alloc((size_t)MM * NN_ * 2);
    unsigned short* Thp = (unsigned short*)alloc((size_t)2 * BB * NN_ * 2); // fp16 T partials
    // --- overlay: NS temps (dead after RT) aliased with Tp (decode partials) ---
    const size_t overlay = off;
    float* G  = (float*)alloc((size_t)NN_ * NN_ * 4);
    unsigned short* GH  = (unsigned short*)alloc((size_t)NN_ * NN_ * 2);
    unsigned short* GL  = (unsigned short*)alloc((size_t)NN_ * NN_ * 2);
    float* X0 = (float*)alloc((size_t)NN_ * NN_ * 4);
    float* X1 = (float*)alloc((size_t)NN_ * NN_ * 4);
    float* Yb = (float*)alloc((size_t)NN_ * NN_ * 4);
    unsigned short* YbH = (unsigned short*)alloc((size_t)NN_ * NN_ * 2);
    unsigned short* YbL = (unsigned short*)alloc((size_t)NN_ * NN_ * 2);
    float* rowsum = (float*)alloc(NN_ * 4);
    float* cbuf   = (float*)alloc(256);
    float* Pp = (float*)alloc((size_t)4 * NN_ * NN_ * 4);  // split-K f32 partials
    // Tp aliases the NS-temp region; NS temps dead before first Tp use.
    float* Tp = (float*)(wsb + overlay);
    const size_t TPS = (size_t)BB * NN_;

    (void)hipMemsetAsync(wbh, 0, (size_t)BB * MM * sizeof(unsigned short), stream);

    const dim3 blk(256);
    const dim3 gsk(NN_ / 64, NN_ / 64, 4);
    const int  RED = (NN_ * NN_ / 4) / 256;   // 576

    rownorm_kernel<<<MM, blk, 0, stream>>>(w, wnH, wnL);
    transp_kernel<<<dim3(MM / 64, NN_ / 64), blk, 0, stream>>>(wnH, wnL, wnTH, wnTL);

    // adotb = x @ wn^T (M2048 N3072 K768); emit y2_0 AND adh (fp16, no f32 C).
    gemm_big<64,32,48,1,8,24,0,0,0,4,0><<<1536, blk, 0, stream>>>(
        x, nullptr, NN_, 0, wnH, wnL, NN_, nullptr, MM, 0, NN_,
        nullptr, nullptr, nullptr, y2h, adh, nullptr);

    // G = wn^T wn + I (768x768, K=3072), split-K=4 + reduce(+I, split)
    gemm_sk<1><<<gsk, blk, 0, stream>>>(
        nullptr, wnTH, wnTL, MM, wnTH, wnTL, MM, Pp, MM / 4);
    red_ns<1><<<RED, blk, 0, stream>>>(Pp, nullptr, G, GH, GL);

    rowabs_kernel<<<NN_, blk, 0, stream>>>(G, rowsum);
    cmax_kernel<<<1, blk, 0, stream>>>(rowsum, cbuf);
    initdiag_kernel<<<(NN_ * NN_) / 256, blk, 0, stream>>>(X0, cbuf);

    // Newton-Schulz X <- 2X - XGX, 7 iterations, split-K=4 per GEMM
    float* Xc = X0;
    float* Xn = X1;
    for (int it = 0; it < 7; ++it) {
        gemm_sk<0><<<gsk, blk, 0, stream>>>(
            Xc, nullptr, nullptr, NN_, GH, GL, NN_, Pp, NN_ / 4);
        red_ns<0><<<RED, blk, 0, stream>>>(Pp, nullptr, Yb, YbH, YbL);
        gemm_sk<0><<<gsk, blk, 0, stream>>>(
            Xc, nullptr, nullptr, NN_, YbH, YbL, NN_, Pp, NN_ / 4);
        red_ns<2><<<RED, blk, 0, stream>>>(Pp, Xc, Xn, QH, QL);
        float* t = Xc; Xc = Xn; Xn = t;
    }
    // QH/QL = fp16 split of G^{-1}

    // RT = wn @ Ginv (M3072 N768 K768); emit RTH/RTL. B 2-term, BK=64.
    gemm_big<64,48,12,1,12,6,1,0,0,2,0><<<576, blk, 0, stream>>>(
        nullptr, wnH, NN_, 0, QH, QL, NN_, Tp, NN_, 0, NN_,
        nullptr, nullptr, nullptr, nullptr, RTH, RTL);

    // ADMM loop: T = y2 @ wn -> fp16 partials Thp (KS=2, B single, BK=128);
    // w-update: A = Thp pair (AMODE=4), B = RT single fp16, BK=128.
    for (int it = 0; it < 20; ++it) {
        gemm_big<128,32,12,2,16,6,1,1,4,0,0><<<768, blk, 0, stream>>>(
            nullptr, y2h, MM, 0, wnTH, nullptr, MM, nullptr, NN_, TPS, MM / 2,
            nullptr, nullptr, nullptr, Thp, nullptr, nullptr);
        if (it < 19) {
            gemm_big<128,32,48,1,8,24,4,1,3,0,0><<<1536, blk, 0, stream>>>(
                nullptr, Thp, NN_, TPS, RTH, nullptr, NN_, nullptr, MM, 0, NN_,
                adh, wbh, nullptr, y2h, nullptr, nullptr);
        } else {
            gemm_big<128,32,48,1,8,24,4,1,3,0,1><<<1536, blk, 0, stream>>>(
                nullptr, Thp, NN_, TPS, RTH, nullptr, NN_, nullptr, MM, 0, NN_,
                adh, wbh, z, y2h, nullptr, nullptr);
        }
    }

    // decoded = z @ wn (M2048 N768 K3072), KS=2 f32 partials + reduce. BK=64.
    gemm_big<64,32,12,2,16,6,0,0,0,0,0><<<768, blk, 0, stream>>>(
        z, nullptr, MM, 0, wnTH, wnTL, MM, Tp, NN_, TPS, MM / 2,
        nullptr, nullptr, nullptr, nullptr, nullptr, nullptr);
    add2_kernel<<<(BB * NN_ / 4) / 256, blk, 0, stream>>>(Tp, TPS, dec);
}

// Round 20
// 1379.026 us; speedup vs baseline: 2.4462x; 2.4462x over previous
//
#include <hip/hip_runtime.h>
#include <math.h>

#define BB   2048
#define NN_  768
#define MM   3072
#define LAMBD 0.1f

typedef __attribute__((ext_vector_type(8))) _Float16 half8;
typedef __attribute__((ext_vector_type(4))) float  f32x4;
typedef __attribute__((ext_vector_type(4))) unsigned short us4;

union HB { _Float16 f; unsigned short u; };
struct HL { unsigned short h, l; };

__device__ __forceinline__ unsigned short h_bits(float f) {
    HB b; b.f = (_Float16)f; return b.u;
}
__device__ __forceinline__ HL split2h(float f) {
    HL r;
    HB b; b.f = (_Float16)f;
    r.h = b.u;
    const float fh = (float)b.f;
    HB c; c.f = (_Float16)(f - fh);
    r.l = c.u;
    return r;
}
__device__ __forceinline__ float clampl(float x) {
    return fminf(fmaxf(x, -LAMBD), LAMBD);
}
__device__ __forceinline__ float4 cvt4h(const unsigned short* p) {
    const us4 u = *(const us4*)p;
    HB a, b, c, d;
    a.u = u.x; b.u = u.y; c.u = u.z; d.u = u.w;
    float4 f;
    f.x = (float)a.f; f.y = (float)b.f; f.z = (float)c.f; f.w = (float)d.f;
    return f;
}

// ---------------------------------------------------------------------------
// Split-K small GEMM (768x768 out, fp16 3-term), 64x64 tile, BK=32,
// reg-prefetch, single LDS buffer + transposed epilogue. (R12/R18-proven.)
// ---------------------------------------------------------------------------
template<int APRE>
__global__ __launch_bounds__(256)
void gemm_sk(const float* __restrict__ A,
             const unsigned short* __restrict__ Ah,
             const unsigned short* __restrict__ Al,
             int lda,
             const unsigned short* __restrict__ Bh,
             const unsigned short* __restrict__ Bl,
             int ldb,
             float* __restrict__ P, int Kper)
{
    __shared__ __align__(16) char smem[20480];
    unsigned short (*AsH)[40] = (unsigned short (*)[40])(smem);
    unsigned short (*AsL)[40] = (unsigned short (*)[40])(smem + 5120);
    unsigned short (*BsH)[40] = (unsigned short (*)[40])(smem + 10240);
    unsigned short (*BsL)[40] = (unsigned short (*)[40])(smem + 15360);

    const int tid  = threadIdx.x;
    const int brow = blockIdx.y * 64;
    const int bcol = blockIdx.x * 64;
    const int koff = blockIdx.z * Kper;
    const int wave = tid >> 6, lane = tid & 63;
    const int wr = wave >> 1, wc = wave & 1;
    const int lrow = lane & 15, kg = lane >> 4;

    const int sk4  = (tid & 7) << 2;

    us4   rAh[2], rAl[2], rBh[2], rBl[2];
    float4 rAf[2];

    auto LOAD = [&](int k0) {
        #pragma unroll
        for (int p = 0; p < 2; ++p) {
            const int row = (p * 256 + tid) >> 3;
            const size_t ga = (size_t)(brow + row) * lda + k0 + sk4;
            const size_t gb = (size_t)(bcol + row) * ldb + k0 + sk4;
            if constexpr (APRE) {
                rAh[p] = *(const us4*)(Ah + ga);
                rAl[p] = *(const us4*)(Al + ga);
            } else {
                rAf[p] = *(const float4*)(A + ga);
            }
            rBh[p] = *(const us4*)(Bh + gb);
            rBl[p] = *(const us4*)(Bl + gb);
        }
    };
    auto STORE = [&]() {
        #pragma unroll
        for (int p = 0; p < 2; ++p) {
            const int row = (p * 256 + tid) >> 3;
            if constexpr (APRE) {
                *(us4*)&AsH[row][sk4] = rAh[p];
                *(us4*)&AsL[row][sk4] = rAl[p];
            } else {
                const HL sx = split2h(rAf[p].x), sy = split2h(rAf[p].y);
                const HL sz = split2h(rAf[p].z), sw = split2h(rAf[p].w);
                us4 h, l;
                h.x = sx.h; l.x = sx.l; h.y = sy.h; l.y = sy.l;
                h.z = sz.h; l.z = sz.l; h.w = sw.h; l.w = sw.l;
                *(us4*)&AsH[row][sk4] = h;
                *(us4*)&AsL[row][sk4] = l;
            }
            *(us4*)&BsH[row][sk4] = rBh[p];
            *(us4*)&BsL[row][sk4] = rBl[p];
        }
    };

    f32x4 acc[2][2];
    #pragma unroll
    for (int m = 0; m < 2; ++m)
        #pragma unroll
        for (int n = 0; n < 2; ++n)
            #pragma unroll
            for (int q = 0; q < 4; ++q) acc[m][n][q] = 0.0f;

    const int NK = Kper / 32;
    LOAD(koff);
    STORE();
    __syncthreads();

    for (int ki = 0; ki < NK; ++ki) {
        if (ki + 1 < NK) LOAD(koff + (ki + 1) * 32);

        half8 ahi[2], alo[2], bhi[2], blo[2];
        #pragma unroll
        for (int m = 0; m < 2; ++m) {
            const int r = wr * 32 + m * 16 + lrow;
            ahi[m] = *(const half8*)&AsH[r][kg * 8];
            alo[m] = *(const half8*)&AsL[r][kg * 8];
        }
        #pragma unroll
        for (int n = 0; n < 2; ++n) {
            const int c = wc * 32 + n * 16 + lrow;
            bhi[n] = *(const half8*)&BsH[c][kg * 8];
            blo[n] = *(const half8*)&BsL[c][kg * 8];
        }
        #pragma unroll
        for (int m = 0; m < 2; ++m)
            #pragma unroll
            for (int n = 0; n < 2; ++n) {
                acc[m][n] = __builtin_amdgcn_mfma_f32_16x16x32_f16(ahi[m], bhi[n], acc[m][n], 0, 0, 0);
                acc[m][n] = __builtin_amdgcn_mfma_f32_16x16x32_f16(ahi[m], blo[n], acc[m][n], 0, 0, 0);
                acc[m][n] = __builtin_amdgcn_mfma_f32_16x16x32_f16(alo[m], bhi[n], acc[m][n], 0, 0, 0);
            }
        __syncthreads();
        if (ki + 1 < NK) { STORE(); __syncthreads(); }
    }

    // transposed epilogue: acc -> LDS [64][65] -> coalesced float4 rows
    float* eb = (float*)smem;
    #pragma unroll
    for (int m = 0; m < 2; ++m)
        #pragma unroll
        for (int n = 0; n < 2; ++n)
            #pragma unroll
            for (int r = 0; r < 4; ++r)
                eb[(wr * 32 + m * 16 + kg * 4 + r) * 65 + wc * 32 + n * 16 + lrow] = acc[m][n][r];
    __syncthreads();
    float* Pk = P + (size_t)blockIdx.z * NN_ * NN_;
    #pragma unroll
    for (int j = 0; j < 4; ++j) {
        const int row = wave * 16 + j * 4 + (lane >> 4);
        const int col = (lane & 15) * 4;
        const float4 v = *(const float4*)&eb[row * 65 + col];
        *(float4*)(Pk + (size_t)(brow + row) * NN_ + bcol + col) = v;
    }
}

// Reduce 4 split-K partials with epilogue. MODE: 0 plain, 1 +I, 2 2*E1-sum.
template<int MODE>
__global__ __launch_bounds__(256)
void red_ns(const float* __restrict__ P,
            const float* __restrict__ E1,
            float* __restrict__ C,
            unsigned short* __restrict__ Ch,
            unsigned short* __restrict__ Cl)
{
    const size_t i4 = ((size_t)blockIdx.x * 256 + threadIdx.x) * 4;
    const size_t sz = (size_t)NN_ * NN_;
    float4 s = *(const float4*)(P + i4);
    const float4 s1 = *(const float4*)(P + sz + i4);
    const float4 s2 = *(const float4*)(P + 2 * sz + i4);
    const float4 s3 = *(const float4*)(P + 3 * sz + i4);
    s.x = (s.x + s1.x) + (s2.x + s3.x);
    s.y = (s.y + s1.y) + (s2.y + s3.y);
    s.z = (s.z + s1.z) + (s2.z + s3.z);
    s.w = (s.w + s1.w) + (s2.w + s3.w);
    float v[4] = {s.x, s.y, s.z, s.w};
    if constexpr (MODE == 1) {
        const int row = (int)(i4 / NN_);
        const int col = (int)(i4 - (size_t)row * NN_);
        #pragma unroll
        for (int j = 0; j < 4; ++j) if (row == col + j) v[j] += 1.0f;
    }
    if constexpr (MODE == 2) {
        const float4 e = *(const float4*)(E1 + i4);
        v[0] = 2.0f * e.x - v[0]; v[1] = 2.0f * e.y - v[1];
        v[2] = 2.0f * e.z - v[2]; v[3] = 2.0f * e.w - v[3];
    }
    float4 o; o.x = v[0]; o.y = v[1]; o.z = v[2]; o.w = v[3];
    *(float4*)(C + i4) = o;
    us4 h, l;
    const HL a = split2h(v[0]), b = split2h(v[1]);
    const HL c = split2h(v[2]), d = split2h(v[3]);
    h.x = a.h; l.x = a.l; h.y = b.h; l.y = b.l;
    h.z = c.h; l.z = c.l; h.w = d.h; l.w = d.l;
    *(us4*)(Ch + i4) = h;
    *(us4*)(Cl + i4) = l;
}

// ---------------------------------------------------------------------------
// Big fp16 GEMM: 64x64 tile, 4 waves (32x32), BK=64 (2 MFMA sub-steps per
// barrier pair), reg-prefetch, single LDS buffer + transposed epilogue.
// (R18-proven form, unchanged.)
// AMODE: 0 f32 A -> cvt; 1 pre-cvt fp16 (Ah); 4 fp16 pair Ah/Ah+psz summed.
// BS: 1 = B single fp16 (Bh only); 0 = B 2-term h/l.
// EPI: 0 C=acc f32 (+EMIT); 3 ADMM w-update on SINGLE-fp16 state streams;
//      4 fp16 partial -> Y2[cks*ks+gi].
// EMIT: 0 none, 1 Y2=fp16(acc), 2 EH/EL=split(acc), 4 Y2+EHonly=fp16(acc), NO C.
// Grid: flat NBM*NBN*KS; per-XCD 2D patch PM x PN for L2 reuse.
// ---------------------------------------------------------------------------
template<int NBM, int NBN, int KS, int PM, int PN, int AMODE, int BS, int EPI, int EMIT, int LASTZ>
__global__ __launch_bounds__(256)
void gemm_big(const float* __restrict__ A,
              const unsigned short* __restrict__ Ah,
              int lda, size_t psz,
              const unsigned short* __restrict__ Bh,
              const unsigned short* __restrict__ Bl,
              int ldb,
              float* __restrict__ C, int ldc, size_t cks, int Kper,
              const unsigned short* __restrict__ F1h,
              unsigned short* __restrict__ Wh,
              float* __restrict__ OutZ,
              unsigned short* __restrict__ Y2,
              unsigned short* __restrict__ EH,
              unsigned short* __restrict__ EL)
{
    static_assert(NBM % PM == 0 && NBN % PN == 0, "patch divides grid");
    constexpr int XM = NBM / PM, XN = NBN / PN;
    static_assert(XM * XN * KS == 8, "patches x KS must equal 8 XCDs");
    static_assert(PM * PN == (NBM * NBN * KS) / 8, "slot count");

    // LDS: A[64][72] fp16 (9216B) + B h (+ l) [64][72]; epilogue needs 16640B
    constexpr int SMB_STAGE = (BS ? 2 : 3) * 9216;
    constexpr int SMB = SMB_STAGE > 16640 ? SMB_STAGE : 16640;
    __shared__ __align__(16) char smem[SMB];
    unsigned short (*AsH)[72] = (unsigned short (*)[72])(smem);
    unsigned short (*BsH)[72] = (unsigned short (*)[72])(smem + 9216);
    unsigned short (*BsL)[72] = (unsigned short (*)[72])(smem + 18432);

    const int bid  = blockIdx.x;
    const int xcd  = bid & 7;
    const int slot = bid >> 3;
    const int ks   = xcd % KS;
    const int rest = xcd / KS;
    const int xn   = rest % XN;
    const int xm   = rest / XN;
    const int m_   = xm * PM + slot / PN;
    const int n_   = xn * PN + slot % PN;
    const int brow = m_ * 64;
    const int bcol = n_ * 64;
    const int koff = ks * Kper;

    const int tid  = threadIdx.x;
    const int wave = tid >> 6, lane = tid & 63;
    const int wr = wave >> 1, wc = wave & 1;
    const int lrow = lane & 15, kg = lane >> 4;

    const int srow = tid >> 2, sk16 = (tid & 3) << 4;   // 16 fp16 per thread

    uint4  pA0, pA1, pA2, pA3, pB0, pB1, pB2, pB3;
    float4 pF[4];

    auto LOAD = [&](int k0) {
        const size_t ga = (size_t)(brow + srow) * lda + k0 + sk16;
        if constexpr (AMODE == 1) {
            pA0 = *(const uint4*)(Ah + ga);
            pA1 = *(const uint4*)(Ah + ga + 8);
        } else if constexpr (AMODE == 4) {
            pA0 = *(const uint4*)(Ah + ga);
            pA1 = *(const uint4*)(Ah + ga + 8);
            pA2 = *(const uint4*)(Ah + ga + psz);
            pA3 = *(const uint4*)(Ah + ga + psz + 8);
        } else {
            pF[0] = *(const float4*)(A + ga);
            pF[1] = *(const float4*)(A + ga + 4);
            pF[2] = *(const float4*)(A + ga + 8);
            pF[3] = *(const float4*)(A + ga + 12);
        }
        const size_t gb = (size_t)(bcol + srow) * ldb + k0 + sk16;
        pB0 = *(const uint4*)(Bh + gb);
        pB1 = *(const uint4*)(Bh + gb + 8);
        if constexpr (!BS) {
            pB2 = *(const uint4*)(Bl + gb);
            pB3 = *(const uint4*)(Bl + gb + 8);
        }
    };
    auto STORE = [&]() {
        if constexpr (AMODE == 1) {
            *(uint4*)&AsH[srow][sk16]     = pA0;
            *(uint4*)&AsH[srow][sk16 + 8] = pA1;
        } else if constexpr (AMODE == 4) {
            half8 s0 = *(half8*)&pA0 + *(half8*)&pA2;
            half8 s1 = *(half8*)&pA1 + *(half8*)&pA3;
            *(half8*)&AsH[srow][sk16]     = s0;
            *(half8*)&AsH[srow][sk16 + 8] = s1;
        } else {
            half8 h0, h1;
            h0[0] = (_Float16)pF[0].x; h0[1] = (_Float16)pF[0].y;
            h0[2] = (_Float16)pF[0].z; h0[3] = (_Float16)pF[0].w;
            h0[4] = (_Float16)pF[1].x; h0[5] = (_Float16)pF[1].y;
            h0[6] = (_Float16)pF[1].z; h0[7] = (_Float16)pF[1].w;
            h1[0] = (_Float16)pF[2].x; h1[1] = (_Float16)pF[2].y;
            h1[2] = (_Float16)pF[2].z; h1[3] = (_Float16)pF[2].w;
            h1[4] = (_Float16)pF[3].x; h1[5] = (_Float16)pF[3].y;
            h1[6] = (_Float16)pF[3].z; h1[7] = (_Float16)pF[3].w;
            *(half8*)&AsH[srow][sk16]     = h0;
            *(half8*)&AsH[srow][sk16 + 8] = h1;
        }
        *(uint4*)&BsH[srow][sk16]     = pB0;
        *(uint4*)&BsH[srow][sk16 + 8] = pB1;
        if constexpr (!BS) {
            *(uint4*)&BsL[srow][sk16]     = pB2;
            *(uint4*)&BsL[srow][sk16 + 8] = pB3;
        }
    };

    f32x4 acc[2][2];
    #pragma unroll
    for (int m = 0; m < 2; ++m)
        #pragma unroll
        for (int n = 0; n < 2; ++n)
            #pragma unroll
            for (int q = 0; q < 4; ++q) acc[m][n][q] = 0.0f;

    const int NK = Kper / 64;
    LOAD(koff);
    STORE();
    __syncthreads();

    for (int ki = 0; ki < NK; ++ki) {
        if (ki + 1 < NK) LOAD(koff + (ki + 1) * 64);

        #pragma unroll
        for (int kk = 0; kk < 2; ++kk) {
            const int kc = kk * 32 + kg * 8;
            half8 a[2], bh[2], bl[2];
            #pragma unroll
            for (int m = 0; m < 2; ++m)
                a[m] = *(const half8*)&AsH[wr * 32 + m * 16 + lrow][kc];
            #pragma unroll
            for (int n = 0; n < 2; ++n) {
                const int c = wc * 32 + n * 16 + lrow;
                bh[n] = *(const half8*)&BsH[c][kc];
                if constexpr (!BS) bl[n] = *(const half8*)&BsL[c][kc];
            }
            #pragma unroll
            for (int m = 0; m < 2; ++m)
                #pragma unroll
                for (int n = 0; n < 2; ++n) {
                    acc[m][n] = __builtin_amdgcn_mfma_f32_16x16x32_f16(a[m], bh[n], acc[m][n], 0, 0, 0);
                    if constexpr (!BS)
                        acc[m][n] = __builtin_amdgcn_mfma_f32_16x16x32_f16(a[m], bl[n], acc[m][n], 0, 0, 0);
                }
        }
        __syncthreads();
        if (ki + 1 < NK) { STORE(); __syncthreads(); }
    }

    // ---- transposed epilogue: acc -> LDS [64][65] -> whole-row float4 I/O ----
    float* eb = (float*)smem;
    #pragma unroll
    for (int m = 0; m < 2; ++m)
        #pragma unroll
        for (int n = 0; n < 2; ++n)
            #pragma unroll
            for (int r = 0; r < 4; ++r)
                eb[(wr * 32 + m * 16 + kg * 4 + r) * 65 + wc * 32 + n * 16 + lrow] = acc[m][n][r];
    __syncthreads();

    #pragma unroll
    for (int j = 0; j < 4; ++j) {
        const int row = wave * 16 + j * 4 + (lane >> 4);
        const int col = (lane & 15) * 4;
        const float4 v = *(const float4*)&eb[row * 65 + col];
        const size_t gi = (size_t)(brow + row) * ldc + bcol + col;
        if constexpr (EPI == 0) {
            if constexpr (EMIT != 4)
                *(float4*)(C + cks * ks + gi) = v;
            if constexpr (EMIT == 1) {
                us4 h;
                h.x = h_bits(v.x); h.y = h_bits(v.y);
                h.z = h_bits(v.z); h.w = h_bits(v.w);
                *(us4*)(Y2 + gi) = h;
            }
            if constexpr (EMIT == 2) {
                const HL a = split2h(v.x), b = split2h(v.y);
                const HL c2 = split2h(v.z), d = split2h(v.w);
                us4 h, l;
                h.x = a.h; l.x = a.l; h.y = b.h; l.y = b.l;
                h.z = c2.h; l.z = c2.l; h.w = d.h; l.w = d.l;
                *(us4*)(EH + gi) = h;
                *(us4*)(EL + gi) = l;
            }
            if constexpr (EMIT == 4) {
                us4 h;
                h.x = h_bits(v.x); h.y = h_bits(v.y);
                h.z = h_bits(v.z); h.w = h_bits(v.w);
                *(us4*)(Y2 + gi) = h;
                *(us4*)(EH + gi) = h;
            }
        } else if constexpr (EPI == 4) {
            us4 h;
            h.x = h_bits(v.x); h.y = h_bits(v.y);
            h.z = h_bits(v.z); h.w = h_bits(v.w);
            *(us4*)(Y2 + cks * ks + gi) = h;
        } else { // EPI == 3
            const float4 f1 = cvt4h(F1h + gi);
            const float4 ww = cvt4h(Wh + gi);
            const float f1v[4] = {f1.x, f1.y, f1.z, f1.w};
            const float wwv[4] = {ww.x, ww.y, ww.z, ww.w};
            const float vv[4]  = {v.x, v.y, v.z, v.w};
            float wn[4];
            #pragma unroll
            for (int q = 0; q < 4; ++q)
                wn[q] = f1v[q] + wwv[q] - clampl(wwv[q]) - vv[q];
            if constexpr (LASTZ) {
                float4 o;
                o.x = wn[0] - clampl(wn[0]); o.y = wn[1] - clampl(wn[1]);
                o.z = wn[2] - clampl(wn[2]); o.w = wn[3] - clampl(wn[3]);
                *(float4*)(OutZ + gi) = o;
            } else {
                us4 hh, y;
                #pragma unroll
                for (int q = 0; q < 4; ++q) {
                    ((unsigned short*)&hh)[q] = h_bits(wn[q]);
                    ((unsigned short*)&y)[q]  = h_bits(f1v[q] + wn[q] - 2.0f * clampl(wn[q]));
                }
                *(us4*)(Wh + gi) = hh;
                *(us4*)(Y2 + gi) = y;
            }
        }
    }
}

// Normalize rows of weight (3072x768); emit fp16 h/l of wn (row-major ONLY).
__global__ __launch_bounds__(256)
void rownorm_kernel(const float* __restrict__ W,
                    unsigned short* __restrict__ wnH, unsigned short* __restrict__ wnL)
{
    __shared__ float red[256];
    const int row = blockIdx.x;
    const int t = threadIdx.x;
    const float* wr = W + (size_t)row * NN_;
    float s = 0.0f;
    for (int k = t; k < NN_; k += 256) { const float w = wr[k]; s += w * w; }
    red[t] = s; __syncthreads();
    for (int off = 128; off > 0; off >>= 1) {
        if (t < off) red[t] += red[t + off];
        __syncthreads();
    }
    const float rn = 1.0f / sqrtf(red[0]);
    for (int k = t; k < NN_; k += 256) {
        const float v = wr[k] * rn;
        const HL s2 = split2h(v);
        wnH[(size_t)row * NN_ + k] = s2.h;
        wnL[(size_t)row * NN_ + k] = s2.l;
    }
}

// Tiled transpose: wn (3072x768) h/l -> wnT (768x3072) h/l, LDS-coalesced.
// Grid: (MM/64, NN_/64) = (48, 12).
__global__ __launch_bounds__(256)
void transp_kernel(const unsigned short* __restrict__ SH,
                   const unsigned short* __restrict__ SL,
                   unsigned short* __restrict__ DH,
                   unsigned short* __restrict__ DL)
{
    __shared__ unsigned short tH[64][68];
    __shared__ unsigned short tL[64][68];
    const int tid = threadIdx.x;
    const int r0 = blockIdx.x * 64;   // row in wn (3072-dim)
    const int c0 = blockIdx.y * 64;   // col in wn (768-dim)
    #pragma unroll
    for (int p = 0; p < 2; ++p) {
        const int idx = p * 256 + tid;
        const int r = idx >> 3, c8 = (idx & 7) * 8;
        const size_t g = (size_t)(r0 + r) * NN_ + c0 + c8;
        *(uint4*)&tH[r][c8] = *(const uint4*)(SH + g);
        *(uint4*)&tL[r][c8] = *(const uint4*)(SL + g);
    }
    __syncthreads();
    #pragma unroll
    for (int p = 0; p < 2; ++p) {
        const int idx = p * 256 + tid;
        const int k = idx >> 3, m8 = (idx & 7) * 8;
        us4 h0, h1, l0, l1;
        h0.x = tH[m8+0][k]; h0.y = tH[m8+1][k]; h0.z = tH[m8+2][k]; h0.w = tH[m8+3][k];
        h1.x = tH[m8+4][k]; h1.y = tH[m8+5][k]; h1.z = tH[m8+6][k]; h1.w = tH[m8+7][k];
        l0.x = tL[m8+0][k]; l0.y = tL[m8+1][k]; l0.z = tL[m8+2][k]; l0.w = tL[m8+3][k];
        l1.x = tL[m8+4][k]; l1.y = tL[m8+5][k]; l1.z = tL[m8+6][k]; l1.w = tL[m8+7][k];
        const size_t g = (size_t)(c0 + k) * MM + r0 + m8;
        *(us4*)(DH + g)     = h0;
        *(us4*)(DH + g + 4) = h1;
        *(us4*)(DL + g)     = l0;
        *(us4*)(DL + g + 4) = l1;
    }
}

__global__ __launch_bounds__(256)
void rowabs_kernel(const float* __restrict__ G, float* __restrict__ rowsum)
{
    __shared__ float red[256];
    const int row = blockIdx.x;
    const int t = threadIdx.x;
    const float* gr = G + (size_t)row * NN_;
    float s = 0.0f;
    for (int k = t; k < NN_; k += 256) s += fabsf(gr[k]);
    red[t] = s; __syncthreads();
    for (int off = 128; off > 0; off >>= 1) {
        if (t < off) red[t] += red[t + off];
        __syncthreads();
    }
    if (t == 0) rowsum[row] = red[0];
}

__global__ __launch_bounds__(256)
void cmax_kernel(const float* __restrict__ rowsum, float* __restrict__ cbuf)
{
    __shared__ float red[256];
    const int t = threadIdx.x;
    float mx = 0.0f;
    for (int k = t; k < NN_; k += 256) mx = fmaxf(mx, rowsum[k]);
    red[t] = mx; __syncthreads();
    for (int off = 128; off > 0; off >>= 1) {
        if (t < off) red[t] = fmaxf(red[t], red[t + off]);
        __syncthreads();
    }
    if (t == 0) cbuf[0] = 2.0f / (1.0f + red[0]);
}

__global__ __launch_bounds__(256)
void initdiag_kernel(float* __restrict__ X, const float* __restrict__ c)
{
    const int idx = blockIdx.x * 256 + threadIdx.x;
    const int p = idx / NN_, q = idx - p * NN_;
    X[idx] = (p == q) ? c[0] : 0.0f;
}

// dec = p0 + p1 (float4)
__global__ __launch_bounds__(256)
void add2_kernel(const float* __restrict__ p0, size_t ps, float* __restrict__ o)
{
    const size_t i = ((size_t)blockIdx.x * 256 + threadIdx.x) * 4;
    const float4 a = *(const float4*)(p0 + i);
    const float4 b = *(const float4*)(p0 + ps + i);
    float4 v;
    v.x = a.x + b.x; v.y = a.y + b.y;
    v.z = a.z + b.z; v.w = a.w + b.w;
    *(float4*)(o + i) = v;
}

extern "C" void kernel_launch(void* const* d_in, const int* in_sizes, int n_in,
                              void* d_out, int out_size, void* d_ws, size_t ws_size,
                              hipStream_t stream)
{
    const float* x = (const float*)d_in[0];   // (2048, 768)
    const float* w = (const float*)d_in[1];   // (3072, 768)

    float* out = (float*)d_out;
    float* z   = out;                          // (2048, 3072)
    float* dec = out + (size_t)BB * MM;        // (2048, 768)

    char* wsb = (char*)d_ws;
    size_t off = 0;
    auto alloc = [&](size_t bytes) -> void* {
        void* p = wsb + off;
        off += (bytes + 255) & ~(size_t)255;
        return p;
    };
    // --- persistent ---
    unsigned short* wnH  = (unsigned short*)alloc((size_t)MM * NN_ * 2);
    unsigned short* wnL  = (unsigned short*)alloc((size_t)MM * NN_ * 2);
    unsigned short* wnTH = (unsigned short*)alloc((size_t)MM * NN_ * 2);
    unsigned short* wnTL = (unsigned short*)alloc((size_t)MM * NN_ * 2);
    unsigned short* adh  = (unsigned short*)alloc((size_t)BB * MM * 2);  // fp16 adotb
    unsigned short* wbh  = (unsigned short*)alloc((size_t)BB * MM * 2);  // fp16 w state
    unsigned short* y2h  = (unsigned short*)alloc((size_t)BB * MM * 2);
    unsigned short* QH  = (unsigned short*)alloc((size_t)NN_ * NN_ * 2);
    unsigned short* QL  = (unsigned short*)alloc((size_t)NN_ * NN_ * 2);
    unsigned short* RTH = (unsigned short*)alloc((size_t)MM * NN_ * 2);
    unsigned short* RTL = (unsigned short*)alloc((size_t)MM * NN_ * 2);
    unsigned short* Thp = (unsigned short*)alloc((size_t)2 * BB * NN_ * 2); // fp16 T partials
    // --- overlay: NS temps (dead after RT) aliased with Tp (decode partials) ---
    const size_t overlay = off;
    float* G  = (float*)alloc((size_t)NN_ * NN_ * 4);
    unsigned short* GH  = (unsigned short*)alloc((size_t)NN_ * NN_ * 2);
    unsigned short* GL  = (unsigned short*)alloc((size_t)NN_ * NN_ * 2);
    float* X0 = (float*)alloc((size_t)NN_ * NN_ * 4);
    float* X1 = (float*)alloc((size_t)NN_ * NN_ * 4);
    float* Yb = (float*)alloc((size_t)NN_ * NN_ * 4);
    unsigned short* YbH = (unsigned short*)alloc((size_t)NN_ * NN_ * 2);
    unsigned short* YbL = (unsigned short*)alloc((size_t)NN_ * NN_ * 2);
    float* rowsum = (float*)alloc(NN_ * 4);
    float* cbuf   = (float*)alloc(256);
    float* Pp = (float*)alloc((size_t)4 * NN_ * NN_ * 4);  // split-K f32 partials
    // Tp aliases the NS-temp region; NS temps dead before first Tp use.
    float* Tp = (float*)(wsb + overlay);
    const size_t TPS = (size_t)BB * NN_;

    (void)hipMemsetAsync(wbh, 0, (size_t)BB * MM * sizeof(unsigned short), stream);

    const dim3 blk(256);
    const dim3 gsk(NN_ / 64, NN_ / 64, 4);
    const int  RED = (NN_ * NN_ / 4) / 256;   // 576

    rownorm_kernel<<<MM, blk, 0, stream>>>(w, wnH, wnL);
    transp_kernel<<<dim3(MM / 64, NN_ / 64), blk, 0, stream>>>(wnH, wnL, wnTH, wnTL);

    // adotb = x @ wn^T (M2048 N3072 K768); emit y2_0 AND adh (fp16, no f32 C).
    gemm_big<32,48,1,8,24,0,0,0,4,0><<<1536, blk, 0, stream>>>(
        x, nullptr, NN_, 0, wnH, wnL, NN_, nullptr, MM, 0, NN_,
        nullptr, nullptr, nullptr, y2h, adh, nullptr);

    // G = wn^T wn + I (768x768, K=3072), split-K=4 + reduce(+I, split)
    gemm_sk<1><<<gsk, blk, 0, stream>>>(
        nullptr, wnTH, wnTL, MM, wnTH, wnTL, MM, Pp, MM / 4);
    red_ns<1><<<RED, blk, 0, stream>>>(Pp, nullptr, G, GH, GL);

    rowabs_kernel<<<NN_, blk, 0, stream>>>(G, rowsum);
    cmax_kernel<<<1, blk, 0, stream>>>(rowsum, cbuf);
    initdiag_kernel<<<(NN_ * NN_) / 256, blk, 0, stream>>>(X0, cbuf);

    // Newton-Schulz X <- 2X - XGX, 7 iterations, split-K=4 per GEMM
    float* Xc = X0;
    float* Xn = X1;
    for (int it = 0; it < 7; ++it) {
        gemm_sk<0><<<gsk, blk, 0, stream>>>(
            Xc, nullptr, nullptr, NN_, GH, GL, NN_, Pp, NN_ / 4);
        red_ns<0><<<RED, blk, 0, stream>>>(Pp, nullptr, Yb, YbH, YbL);
        gemm_sk<0><<<gsk, blk, 0, stream>>>(
            Xc, nullptr, nullptr, NN_, YbH, YbL, NN_, Pp, NN_ / 4);
        red_ns<2><<<RED, blk, 0, stream>>>(Pp, Xc, Xn, QH, QL);
        float* t = Xc; Xc = Xn; Xn = t;
    }
    // QH/QL = fp16 split of G^{-1}

    // RT = wn @ Ginv (M3072 N768 K768); emit RTH/RTL. B 2-term.
    gemm_big<48,12,1,12,6,1,0,0,2,0><<<576, blk, 0, stream>>>(
        nullptr, wnH, NN_, 0, QH, QL, NN_, Tp, NN_, 0, NN_,
        nullptr, nullptr, nullptr, nullptr, RTH, RTL);

    // ADMM loop: T = y2 @ wn -> fp16 partials Thp (KS=2, B single fp16);
    // w-update: A = Thp pair summed (AMODE=4), B = RT single fp16,
    //           state streams adh/wbh single fp16.
    for (int it = 0; it < 20; ++it) {
        gemm_big<32,12,2,16,6,1,1,4,0,0><<<768, blk, 0, stream>>>(
            nullptr, y2h, MM, 0, wnTH, nullptr, MM, nullptr, NN_, TPS, MM / 2,
            nullptr, nullptr, nullptr, Thp, nullptr, nullptr);
        if (it < 19) {
            gemm_big<32,48,1,8,24,4,1,3,0,0><<<1536, blk, 0, stream>>>(
                nullptr, Thp, NN_, TPS, RTH, nullptr, NN_, nullptr, MM, 0, NN_,
                adh, wbh, nullptr, y2h, nullptr, nullptr);
        } else {
            gemm_big<32,48,1,8,24,4,1,3,0,1><<<1536, blk, 0, stream>>>(
                nullptr, Thp, NN_, TPS, RTH, nullptr, NN_, nullptr, MM, 0, NN_,
                adh, wbh, z, y2h, nullptr, nullptr);
        }
    }

    // decoded = z @ wn (M2048 N768 K3072), KS=2 f32 partials + reduce. B 2-term.
    gemm_big<32,12,2,16,6,0,0,0,0,0><<<768, blk, 0, stream>>>(
        z, nullptr, MM, 0, wnTH, wnTL, MM, Tp, NN_, TPS, MM / 2,
        nullptr, nullptr, nullptr, nullptr, nullptr, nullptr);
    add2_kernel<<<(BB * NN_ / 4) / 256, blk, 0, stream>>>(Tp, TPS, dec);
}

// Round 21
// 1329.217 us; speedup vs baseline: 2.5379x; 1.0375x over previous
//
#include <hip/hip_runtime.h>
#include <math.h>

#define BB   2048
#define NN_  768
#define MM   3072
#define LAMBD 0.1f

typedef __attribute__((ext_vector_type(8))) _Float16 half8;
typedef __attribute__((ext_vector_type(4))) float  f32x4;
typedef __attribute__((ext_vector_type(4))) unsigned short us4;

union HB { _Float16 f; unsigned short u; };
struct HL { unsigned short h, l; };

__device__ __forceinline__ unsigned short h_bits(float f) {
    HB b; b.f = (_Float16)f; return b.u;
}
__device__ __forceinline__ HL split2h(float f) {
    HL r;
    HB b; b.f = (_Float16)f;
    r.h = b.u;
    const float fh = (float)b.f;
    HB c; c.f = (_Float16)(f - fh);
    r.l = c.u;
    return r;
}
__device__ __forceinline__ float clampl(float x) {
    return fminf(fmaxf(x, -LAMBD), LAMBD);
}
__device__ __forceinline__ float4 cvt4h(const unsigned short* p) {
    const us4 u = *(const us4*)p;
    HB a, b, c, d;
    a.u = u.x; b.u = u.y; c.u = u.z; d.u = u.w;
    float4 f;
    f.x = (float)a.f; f.y = (float)b.f; f.z = (float)c.f; f.w = (float)d.f;
    return f;
}

// ---------------------------------------------------------------------------
// Split-K small GEMM (768x768 out, fp16 3-term), 64x64 tile, BK=32,
// reg-prefetch, single LDS buffer + transposed epilogue. (R12/R18-proven.)
// ---------------------------------------------------------------------------
template<int APRE>
__global__ __launch_bounds__(256)
void gemm_sk(const float* __restrict__ A,
             const unsigned short* __restrict__ Ah,
             const unsigned short* __restrict__ Al,
             int lda,
             const unsigned short* __restrict__ Bh,
             const unsigned short* __restrict__ Bl,
             int ldb,
             float* __restrict__ P, int Kper)
{
    __shared__ __align__(16) char smem[20480];
    unsigned short (*AsH)[40] = (unsigned short (*)[40])(smem);
    unsigned short (*AsL)[40] = (unsigned short (*)[40])(smem + 5120);
    unsigned short (*BsH)[40] = (unsigned short (*)[40])(smem + 10240);
    unsigned short (*BsL)[40] = (unsigned short (*)[40])(smem + 15360);

    const int tid  = threadIdx.x;
    const int brow = blockIdx.y * 64;
    const int bcol = blockIdx.x * 64;
    const int koff = blockIdx.z * Kper;
    const int wave = tid >> 6, lane = tid & 63;
    const int wr = wave >> 1, wc = wave & 1;
    const int lrow = lane & 15, kg = lane >> 4;

    const int sk4  = (tid & 7) << 2;

    us4   rAh[2], rAl[2], rBh[2], rBl[2];
    float4 rAf[2];

    auto LOAD = [&](int k0) {
        #pragma unroll
        for (int p = 0; p < 2; ++p) {
            const int row = (p * 256 + tid) >> 3;
            const size_t ga = (size_t)(brow + row) * lda + k0 + sk4;
            const size_t gb = (size_t)(bcol + row) * ldb + k0 + sk4;
            if constexpr (APRE) {
                rAh[p] = *(const us4*)(Ah + ga);
                rAl[p] = *(const us4*)(Al + ga);
            } else {
                rAf[p] = *(const float4*)(A + ga);
            }
            rBh[p] = *(const us4*)(Bh + gb);
            rBl[p] = *(const us4*)(Bl + gb);
        }
    };
    auto STORE = [&]() {
        #pragma unroll
        for (int p = 0; p < 2; ++p) {
            const int row = (p * 256 + tid) >> 3;
            if constexpr (APRE) {
                *(us4*)&AsH[row][sk4] = rAh[p];
                *(us4*)&AsL[row][sk4] = rAl[p];
            } else {
                const HL sx = split2h(rAf[p].x), sy = split2h(rAf[p].y);
                const HL sz = split2h(rAf[p].z), sw = split2h(rAf[p].w);
                us4 h, l;
                h.x = sx.h; l.x = sx.l; h.y = sy.h; l.y = sy.l;
                h.z = sz.h; l.z = sz.l; h.w = sw.h; l.w = sw.l;
                *(us4*)&AsH[row][sk4] = h;
                *(us4*)&AsL[row][sk4] = l;
            }
            *(us4*)&BsH[row][sk4] = rBh[p];
            *(us4*)&BsL[row][sk4] = rBl[p];
        }
    };

    f32x4 acc[2][2];
    #pragma unroll
    for (int m = 0; m < 2; ++m)
        #pragma unroll
        for (int n = 0; n < 2; ++n)
            #pragma unroll
            for (int q = 0; q < 4; ++q) acc[m][n][q] = 0.0f;

    const int NK = Kper / 32;
    LOAD(koff);
    STORE();
    __syncthreads();

    for (int ki = 0; ki < NK; ++ki) {
        if (ki + 1 < NK) LOAD(koff + (ki + 1) * 32);

        half8 ahi[2], alo[2], bhi[2], blo[2];
        #pragma unroll
        for (int m = 0; m < 2; ++m) {
            const int r = wr * 32 + m * 16 + lrow;
            ahi[m] = *(const half8*)&AsH[r][kg * 8];
            alo[m] = *(const half8*)&AsL[r][kg * 8];
        }
        #pragma unroll
        for (int n = 0; n < 2; ++n) {
            const int c = wc * 32 + n * 16 + lrow;
            bhi[n] = *(const half8*)&BsH[c][kg * 8];
            blo[n] = *(const half8*)&BsL[c][kg * 8];
        }
        #pragma unroll
        for (int m = 0; m < 2; ++m)
            #pragma unroll
            for (int n = 0; n < 2; ++n) {
                acc[m][n] = __builtin_amdgcn_mfma_f32_16x16x32_f16(ahi[m], bhi[n], acc[m][n], 0, 0, 0);
                acc[m][n] = __builtin_amdgcn_mfma_f32_16x16x32_f16(ahi[m], blo[n], acc[m][n], 0, 0, 0);
                acc[m][n] = __builtin_amdgcn_mfma_f32_16x16x32_f16(alo[m], bhi[n], acc[m][n], 0, 0, 0);
            }
        __syncthreads();
        if (ki + 1 < NK) { STORE(); __syncthreads(); }
    }

    // transposed epilogue: acc -> LDS [64][65] -> coalesced float4 rows
    float* eb = (float*)smem;
    #pragma unroll
    for (int m = 0; m < 2; ++m)
        #pragma unroll
        for (int n = 0; n < 2; ++n)
            #pragma unroll
            for (int r = 0; r < 4; ++r)
                eb[(wr * 32 + m * 16 + kg * 4 + r) * 65 + wc * 32 + n * 16 + lrow] = acc[m][n][r];
    __syncthreads();
    float* Pk = P + (size_t)blockIdx.z * NN_ * NN_;
    #pragma unroll
    for (int j = 0; j < 4; ++j) {
        const int row = wave * 16 + j * 4 + (lane >> 4);
        const int col = (lane & 15) * 4;
        const float4 v = *(const float4*)&eb[row * 65 + col];
        *(float4*)(Pk + (size_t)(brow + row) * NN_ + bcol + col) = v;
    }
}

// Reduce 4 split-K partials with epilogue. MODE: 0 plain, 1 +I, 2 2*E1-sum.
template<int MODE>
__global__ __launch_bounds__(256)
void red_ns(const float* __restrict__ P,
            const float* __restrict__ E1,
            float* __restrict__ C,
            unsigned short* __restrict__ Ch,
            unsigned short* __restrict__ Cl)
{
    const size_t i4 = ((size_t)blockIdx.x * 256 + threadIdx.x) * 4;
    const size_t sz = (size_t)NN_ * NN_;
    float4 s = *(const float4*)(P + i4);
    const float4 s1 = *(const float4*)(P + sz + i4);
    const float4 s2 = *(const float4*)(P + 2 * sz + i4);
    const float4 s3 = *(const float4*)(P + 3 * sz + i4);
    s.x = (s.x + s1.x) + (s2.x + s3.x);
    s.y = (s.y + s1.y) + (s2.y + s3.y);
    s.z = (s.z + s1.z) + (s2.z + s3.z);
    s.w = (s.w + s1.w) + (s2.w + s3.w);
    float v[4] = {s.x, s.y, s.z, s.w};
    if constexpr (MODE == 1) {
        const int row = (int)(i4 / NN_);
        const int col = (int)(i4 - (size_t)row * NN_);
        #pragma unroll
        for (int j = 0; j < 4; ++j) if (row == col + j) v[j] += 1.0f;
    }
    if constexpr (MODE == 2) {
        const float4 e = *(const float4*)(E1 + i4);
        v[0] = 2.0f * e.x - v[0]; v[1] = 2.0f * e.y - v[1];
        v[2] = 2.0f * e.z - v[2]; v[3] = 2.0f * e.w - v[3];
    }
    float4 o; o.x = v[0]; o.y = v[1]; o.z = v[2]; o.w = v[3];
    *(float4*)(C + i4) = o;
    us4 h, l;
    const HL a = split2h(v[0]), b = split2h(v[1]);
    const HL c = split2h(v[2]), d = split2h(v[3]);
    h.x = a.h; l.x = a.l; h.y = b.h; l.y = b.l;
    h.z = c.h; l.z = c.l; h.w = d.h; l.w = d.l;
    *(us4*)(Ch + i4) = h;
    *(us4*)(Cl + i4) = l;
}

// ---------------------------------------------------------------------------
// Big fp16 GEMM: 64x64 tile, 4 waves (32x32), BK=64 or 128 (R18 body; BK=128
// adds a second named register set qA*/qB* for k+64, same mapping).
// AMODE: 0 f32 A -> cvt; 1 pre-cvt fp16 (Ah); 4 fp16 pair Ah/Ah+psz summed.
// BS: 1 = B single fp16 (Bh only); 0 = B 2-term h/l.
// EPI: 0 C=acc f32 (+EMIT); 3 ADMM w-update; 4 fp16 partial -> Y2[cks*ks+gi].
// EMIT: 0 none, 1 Y2=fp16, 2 EH/EL=split, 4 Y2+EH=fp16(acc), NO C.
// ---------------------------------------------------------------------------
template<int BK, int NBM, int NBN, int KS, int PM, int PN, int AMODE, int BS, int EPI, int EMIT, int LASTZ>
__global__ __launch_bounds__(256)
void gemm_big(const float* __restrict__ A,
              const unsigned short* __restrict__ Ah,
              int lda, size_t psz,
              const unsigned short* __restrict__ Bh,
              const unsigned short* __restrict__ Bl,
              int ldb,
              float* __restrict__ C, int ldc, size_t cks, int Kper,
              const unsigned short* __restrict__ F1h,
              unsigned short* __restrict__ Wh,
              float* __restrict__ OutZ,
              unsigned short* __restrict__ Y2,
              unsigned short* __restrict__ EH,
              unsigned short* __restrict__ EL)
{
    static_assert(NBM % PM == 0 && NBN % PN == 0, "patch divides grid");
    constexpr int XM = NBM / PM, XN = NBN / PN;
    static_assert(XM * XN * KS == 8, "patches x KS must equal 8 XCDs");
    static_assert(PM * PN == (NBM * NBN * KS) / 8, "slot count");
    static_assert(BK == 64 || BK == 128, "BK");

    constexpr int LDR = BK + 8;
    constexpr int MSZ = 64 * LDR * 2;
    constexpr int SMB_STAGE = (BS ? 2 : 3) * MSZ;
    constexpr int SMB = SMB_STAGE > 16640 ? SMB_STAGE : 16640;
    __shared__ __align__(16) char smem[SMB];
    unsigned short (*AsH)[LDR] = (unsigned short (*)[LDR])(smem);
    unsigned short (*BsH)[LDR] = (unsigned short (*)[LDR])(smem + MSZ);
    unsigned short (*BsL)[LDR] = (unsigned short (*)[LDR])(smem + 2 * MSZ);

    const int bid  = blockIdx.x;
    const int xcd  = bid & 7;
    const int slot = bid >> 3;
    const int ks   = xcd % KS;
    const int rest = xcd / KS;
    const int xn   = rest % XN;
    const int xm   = rest / XN;
    const int m_   = xm * PM + slot / PN;
    const int n_   = xn * PN + slot % PN;
    const int brow = m_ * 64;
    const int bcol = n_ * 64;
    const int koff = ks * Kper;

    const int tid  = threadIdx.x;
    const int wave = tid >> 6, lane = tid & 63;
    const int wr = wave >> 1, wc = wave & 1;
    const int lrow = lane & 15, kg = lane >> 4;

    const int srow = tid >> 2, sk16 = (tid & 3) << 4;   // 16 fp16 per thread per 64-half

    // half-0 registers (R18-identical)
    uint4  pA0, pA1, pA2, pA3, pB0, pB1, pB2, pB3;
    float4 pF[4];
    // half-1 registers (BK=128 only)
    uint4  qA0, qA1, qA2, qA3, qB0, qB1;

    auto LOAD = [&](int k0) {
        {
            const size_t ga = (size_t)(brow + srow) * lda + k0 + sk16;
            if constexpr (AMODE == 1) {
                pA0 = *(const uint4*)(Ah + ga);
                pA1 = *(const uint4*)(Ah + ga + 8);
            } else if constexpr (AMODE == 4) {
                pA0 = *(const uint4*)(Ah + ga);
                pA1 = *(const uint4*)(Ah + ga + 8);
                pA2 = *(const uint4*)(Ah + ga + psz);
                pA3 = *(const uint4*)(Ah + ga + psz + 8);
            } else {
                pF[0] = *(const float4*)(A + ga);
                pF[1] = *(const float4*)(A + ga + 4);
                pF[2] = *(const float4*)(A + ga + 8);
                pF[3] = *(const float4*)(A + ga + 12);
            }
            const size_t gb = (size_t)(bcol + srow) * ldb + k0 + sk16;
            pB0 = *(const uint4*)(Bh + gb);
            pB1 = *(const uint4*)(Bh + gb + 8);
            if constexpr (!BS) {
                pB2 = *(const uint4*)(Bl + gb);
                pB3 = *(const uint4*)(Bl + gb + 8);
            }
        }
        if constexpr (BK == 128) {
            const size_t ga = (size_t)(brow + srow) * lda + k0 + 64 + sk16;
            if constexpr (AMODE == 1) {
                qA0 = *(const uint4*)(Ah + ga);
                qA1 = *(const uint4*)(Ah + ga + 8);
            } else if constexpr (AMODE == 4) {
                qA0 = *(const uint4*)(Ah + ga);
                qA1 = *(const uint4*)(Ah + ga + 8);
                qA2 = *(const uint4*)(Ah + ga + psz);
                qA3 = *(const uint4*)(Ah + ga + psz + 8);
            }
            const size_t gb = (size_t)(bcol + srow) * ldb + k0 + 64 + sk16;
            qB0 = *(const uint4*)(Bh + gb);
            qB1 = *(const uint4*)(Bh + gb + 8);
        }
    };
    auto STORE = [&]() {
        {
            if constexpr (AMODE == 1) {
                *(uint4*)&AsH[srow][sk16]     = pA0;
                *(uint4*)&AsH[srow][sk16 + 8] = pA1;
            } else if constexpr (AMODE == 4) {
                half8 s0 = *(half8*)&pA0 + *(half8*)&pA2;
                half8 s1 = *(half8*)&pA1 + *(half8*)&pA3;
                *(half8*)&AsH[srow][sk16]     = s0;
                *(half8*)&AsH[srow][sk16 + 8] = s1;
            } else {
                half8 h0, h1;
                h0[0] = (_Float16)pF[0].x; h0[1] = (_Float16)pF[0].y;
                h0[2] = (_Float16)pF[0].z; h0[3] = (_Float16)pF[0].w;
                h0[4] = (_Float16)pF[1].x; h0[5] = (_Float16)pF[1].y;
                h0[6] = (_Float16)pF[1].z; h0[7] = (_Float16)pF[1].w;
                h1[0] = (_Float16)pF[2].x; h1[1] = (_Float16)pF[2].y;
                h1[2] = (_Float16)pF[2].z; h1[3] = (_Float16)pF[2].w;
                h1[4] = (_Float16)pF[3].x; h1[5] = (_Float16)pF[3].y;
                h1[6] = (_Float16)pF[3].z; h1[7] = (_Float16)pF[3].w;
                *(half8*)&AsH[srow][sk16]     = h0;
                *(half8*)&AsH[srow][sk16 + 8] = h1;
            }
            *(uint4*)&BsH[srow][sk16]     = pB0;
            *(uint4*)&BsH[srow][sk16 + 8] = pB1;
            if constexpr (!BS) {
                *(uint4*)&BsL[srow][sk16]     = pB2;
                *(uint4*)&BsL[srow][sk16 + 8] = pB3;
            }
        }
        if constexpr (BK == 128) {
            const int k2 = 64 + sk16;
            if constexpr (AMODE == 1) {
                *(uint4*)&AsH[srow][k2]     = qA0;
                *(uint4*)&AsH[srow][k2 + 8] = qA1;
            } else if constexpr (AMODE == 4) {
                half8 s0 = *(half8*)&qA0 + *(half8*)&qA2;
                half8 s1 = *(half8*)&qA1 + *(half8*)&qA3;
                *(half8*)&AsH[srow][k2]     = s0;
                *(half8*)&AsH[srow][k2 + 8] = s1;
            }
            *(uint4*)&BsH[srow][k2]     = qB0;
            *(uint4*)&BsH[srow][k2 + 8] = qB1;
        }
    };

    f32x4 acc[2][2];
    #pragma unroll
    for (int m = 0; m < 2; ++m)
        #pragma unroll
        for (int n = 0; n < 2; ++n)
            #pragma unroll
            for (int q = 0; q < 4; ++q) acc[m][n][q] = 0.0f;

    const int NK = Kper / BK;
    LOAD(koff);
    STORE();
    __syncthreads();

    for (int ki = 0; ki < NK; ++ki) {
        if (ki + 1 < NK) LOAD(koff + (ki + 1) * BK);

        #pragma unroll
        for (int kk = 0; kk < BK / 32; ++kk) {
            const int kc = kk * 32 + kg * 8;
            half8 a[2], bh[2], bl[2];
            #pragma unroll
            for (int m = 0; m < 2; ++m)
                a[m] = *(const half8*)&AsH[wr * 32 + m * 16 + lrow][kc];
            #pragma unroll
            for (int n = 0; n < 2; ++n) {
                const int c = wc * 32 + n * 16 + lrow;
                bh[n] = *(const half8*)&BsH[c][kc];
                if constexpr (!BS) bl[n] = *(const half8*)&BsL[c][kc];
            }
            #pragma unroll
            for (int m = 0; m < 2; ++m)
                #pragma unroll
                for (int n = 0; n < 2; ++n) {
                    acc[m][n] = __builtin_amdgcn_mfma_f32_16x16x32_f16(a[m], bh[n], acc[m][n], 0, 0, 0);
                    if constexpr (!BS)
                        acc[m][n] = __builtin_amdgcn_mfma_f32_16x16x32_f16(a[m], bl[n], acc[m][n], 0, 0, 0);
                }
        }
        __syncthreads();
        if (ki + 1 < NK) { STORE(); __syncthreads(); }
    }

    // ---- transposed epilogue: acc -> LDS [64][65] -> whole-row float4 I/O ----
    float* eb = (float*)smem;
    #pragma unroll
    for (int m = 0; m < 2; ++m)
        #pragma unroll
        for (int n = 0; n < 2; ++n)
            #pragma unroll
            for (int r = 0; r < 4; ++r)
                eb[(wr * 32 + m * 16 + kg * 4 + r) * 65 + wc * 32 + n * 16 + lrow] = acc[m][n][r];
    __syncthreads();

    #pragma unroll
    for (int j = 0; j < 4; ++j) {
        const int row = wave * 16 + j * 4 + (lane >> 4);
        const int col = (lane & 15) * 4;
        const float4 v = *(const float4*)&eb[row * 65 + col];
        const size_t gi = (size_t)(brow + row) * ldc + bcol + col;
        if constexpr (EPI == 0) {
            if constexpr (EMIT != 4)
                *(float4*)(C + cks * ks + gi) = v;
            if constexpr (EMIT == 1) {
                us4 h;
                h.x = h_bits(v.x); h.y = h_bits(v.y);
                h.z = h_bits(v.z); h.w = h_bits(v.w);
                *(us4*)(Y2 + gi) = h;
            }
            if constexpr (EMIT == 2) {
                const HL a = split2h(v.x), b = split2h(v.y);
                const HL c2 = split2h(v.z), d = split2h(v.w);
                us4 h, l;
                h.x = a.h; l.x = a.l; h.y = b.h; l.y = b.l;
                h.z = c2.h; l.z = c2.l; h.w = d.h; l.w = d.l;
                *(us4*)(EH + gi) = h;
                *(us4*)(EL + gi) = l;
            }
            if constexpr (EMIT == 4) {
                us4 h;
                h.x = h_bits(v.x); h.y = h_bits(v.y);
                h.z = h_bits(v.z); h.w = h_bits(v.w);
                *(us4*)(Y2 + gi) = h;
                *(us4*)(EH + gi) = h;
            }
        } else if constexpr (EPI == 4) {
            us4 h;
            h.x = h_bits(v.x); h.y = h_bits(v.y);
            h.z = h_bits(v.z); h.w = h_bits(v.w);
            *(us4*)(Y2 + cks * ks + gi) = h;
        } else { // EPI == 3
            const float4 f1 = cvt4h(F1h + gi);
            const float4 ww = cvt4h(Wh + gi);
            const float f1v[4] = {f1.x, f1.y, f1.z, f1.w};
            const float wwv[4] = {ww.x, ww.y, ww.z, ww.w};
            const float vv[4]  = {v.x, v.y, v.z, v.w};
            float wn[4];
            #pragma unroll
            for (int q = 0; q < 4; ++q)
                wn[q] = f1v[q] + wwv[q] - clampl(wwv[q]) - vv[q];
            if constexpr (LASTZ) {
                float4 o;
                o.x = wn[0] - clampl(wn[0]); o.y = wn[1] - clampl(wn[1]);
                o.z = wn[2] - clampl(wn[2]); o.w = wn[3] - clampl(wn[3]);
                *(float4*)(OutZ + gi) = o;
            } else {
                us4 hh, y;
                #pragma unroll
                for (int q = 0; q < 4; ++q) {
                    ((unsigned short*)&hh)[q] = h_bits(wn[q]);
                    ((unsigned short*)&y)[q]  = h_bits(f1v[q] + wn[q] - 2.0f * clampl(wn[q]));
                }
                *(us4*)(Wh + gi) = hh;
                *(us4*)(Y2 + gi) = y;
            }
        }
    }
}

// Normalize rows of weight (3072x768); emit fp16 h/l of wn (row-major ONLY).
__global__ __launch_bounds__(256)
void rownorm_kernel(const float* __restrict__ W,
                    unsigned short* __restrict__ wnH, unsigned short* __restrict__ wnL)
{
    __shared__ float red[256];
    const int row = blockIdx.x;
    const int t = threadIdx.x;
    const float* wr = W + (size_t)row * NN_;
    float s = 0.0f;
    for (int k = t; k < NN_; k += 256) { const float w = wr[k]; s += w * w; }
    red[t] = s; __syncthreads();
    for (int off = 128; off > 0; off >>= 1) {
        if (t < off) red[t] += red[t + off];
        __syncthreads();
    }
    const float rn = 1.0f / sqrtf(red[0]);
    for (int k = t; k < NN_; k += 256) {
        const float v = wr[k] * rn;
        const HL s2 = split2h(v);
        wnH[(size_t)row * NN_ + k] = s2.h;
        wnL[(size_t)row * NN_ + k] = s2.l;
    }
}

// Tiled transpose: wn (3072x768) h/l -> wnT (768x3072) h/l, LDS-coalesced.
__global__ __launch_bounds__(256)
void transp_kernel(const unsigned short* __restrict__ SH,
                   const unsigned short* __restrict__ SL,
                   unsigned short* __restrict__ DH,
                   unsigned short* __restrict__ DL)
{
    __shared__ unsigned short tH[64][68];
    __shared__ unsigned short tL[64][68];
    const int tid = threadIdx.x;
    const int r0 = blockIdx.x * 64;
    const int c0 = blockIdx.y * 64;
    #pragma unroll
    for (int p = 0; p < 2; ++p) {
        const int idx = p * 256 + tid;
        const int r = idx >> 3, c8 = (idx & 7) * 8;
        const size_t g = (size_t)(r0 + r) * NN_ + c0 + c8;
        *(uint4*)&tH[r][c8] = *(const uint4*)(SH + g);
        *(uint4*)&tL[r][c8] = *(const uint4*)(SL + g);
    }
    __syncthreads();
    #pragma unroll
    for (int p = 0; p < 2; ++p) {
        const int idx = p * 256 + tid;
        const int k = idx >> 3, m8 = (idx & 7) * 8;
        us4 h0, h1, l0, l1;
        h0.x = tH[m8+0][k]; h0.y = tH[m8+1][k]; h0.z = tH[m8+2][k]; h0.w = tH[m8+3][k];
        h1.x = tH[m8+4][k]; h1.y = tH[m8+5][k]; h1.z = tH[m8+6][k]; h1.w = tH[m8+7][k];
        l0.x = tL[m8+0][k]; l0.y = tL[m8+1][k]; l0.z = tL[m8+2][k]; l0.w = tL[m8+3][k];
        l1.x = tL[m8+4][k]; l1.y = tL[m8+5][k]; l1.z = tL[m8+6][k]; l1.w = tL[m8+7][k];
        const size_t g = (size_t)(c0 + k) * MM + r0 + m8;
        *(us4*)(DH + g)     = h0;
        *(us4*)(DH + g + 4) = h1;
        *(us4*)(DL + g)     = l0;
        *(us4*)(DL + g + 4) = l1;
    }
}

__global__ __launch_bounds__(256)
void rowabs_kernel(const float* __restrict__ G, float* __restrict__ rowsum)
{
    __shared__ float red[256];
    const int row = blockIdx.x;
    const int t = threadIdx.x;
    const float* gr = G + (size_t)row * NN_;
    float s = 0.0f;
    for (int k = t; k < NN_; k += 256) s += fabsf(gr[k]);
    red[t] = s; __syncthreads();
    for (int off = 128; off > 0; off >>= 1) {
        if (t < off) red[t] += red[t + off];
        __syncthreads();
    }
    if (t == 0) rowsum[row] = red[0];
}

__global__ __launch_bounds__(256)
void cmax_kernel(const float* __restrict__ rowsum, float* __restrict__ cbuf)
{
    __shared__ float red[256];
    const int t = threadIdx.x;
    float mx = 0.0f;
    for (int k = t; k < NN_; k += 256) mx = fmaxf(mx, rowsum[k]);
    red[t] = mx; __syncthreads();
    for (int off = 128; off > 0; off >>= 1) {
        if (t < off) red[t] = fmaxf(red[t], red[t + off]);
        __syncthreads();
    }
    if (t == 0) cbuf[0] = 2.0f / (1.0f + red[0]);
}

__global__ __launch_bounds__(256)
void initdiag_kernel(float* __restrict__ X, const float* __restrict__ c)
{
    const int idx = blockIdx.x * 256 + threadIdx.x;
    const int p = idx / NN_, q = idx - p * NN_;
    X[idx] = (p == q) ? c[0] : 0.0f;
}

// dec = p0 + p1 (float4)
__global__ __launch_bounds__(256)
void add2_kernel(const float* __restrict__ p0, size_t ps, float* __restrict__ o)
{
    const size_t i = ((size_t)blockIdx.x * 256 + threadIdx.x) * 4;
    const float4 a = *(const float4*)(p0 + i);
    const float4 b = *(const float4*)(p0 + ps + i);
    float4 v;
    v.x = a.x + b.x; v.y = a.y + b.y;
    v.z = a.z + b.z; v.w = a.w + b.w;
    *(float4*)(o + i) = v;
}

extern "C" void kernel_launch(void* const* d_in, const int* in_sizes, int n_in,
                              void* d_out, int out_size, void* d_ws, size_t ws_size,
                              hipStream_t stream)
{
    const float* x = (const float*)d_in[0];   // (2048, 768)
    const float* w = (const float*)d_in[1];   // (3072, 768)

    float* out = (float*)d_out;
    float* z   = out;                          // (2048, 3072)
    float* dec = out + (size_t)BB * MM;        // (2048, 768)

    char* wsb = (char*)d_ws;
    size_t off = 0;
    auto alloc = [&](size_t bytes) -> void* {
        void* p = wsb + off;
        off += (bytes + 255) & ~(size_t)255;
        return p;
    };
    // --- persistent ---
    unsigned short* wnH  = (unsigned short*)alloc((size_t)MM * NN_ * 2);
    unsigned short* wnL  = (unsigned short*)alloc((size_t)MM * NN_ * 2);
    unsigned short* wnTH = (unsigned short*)alloc((size_t)MM * NN_ * 2);
    unsigned short* wnTL = (unsigned short*)alloc((size_t)MM * NN_ * 2);
    unsigned short* adh  = (unsigned short*)alloc((size_t)BB * MM * 2);  // fp16 adotb
    unsigned short* wbh  = (unsigned short*)alloc((size_t)BB * MM * 2);  // fp16 w state
    unsigned short* y2h  = (unsigned short*)alloc((size_t)BB * MM * 2);
    unsigned short* QH  = (unsigned short*)alloc((size_t)NN_ * NN_ * 2);
    unsigned short* QL  = (unsigned short*)alloc((size_t)NN_ * NN_ * 2);
    unsigned short* RTH = (unsigned short*)alloc((size_t)MM * NN_ * 2);
    unsigned short* RTL = (unsigned short*)alloc((size_t)MM * NN_ * 2);
    unsigned short* Thp = (unsigned short*)alloc((size_t)2 * BB * NN_ * 2); // fp16 T partials
    // --- overlay: NS temps (dead after RT) aliased with Tp (decode partials) ---
    const size_t overlay = off;
    float* G  = (float*)alloc((size_t)NN_ * NN_ * 4);
    unsigned short* GH  = (unsigned short*)alloc((size_t)NN_ * NN_ * 2);
    unsigned short* GL  = (unsigned short*)alloc((size_t)NN_ * NN_ * 2);
    float* X0 = (float*)alloc((size_t)NN_ * NN_ * 4);
    float* X1 = (float*)alloc((size_t)NN_ * NN_ * 4);
    float* Yb = (float*)alloc((size_t)NN_ * NN_ * 4);
    unsigned short* YbH = (unsigned short*)alloc((size_t)NN_ * NN_ * 2);
    unsigned short* YbL = (unsigned short*)alloc((size_t)NN_ * NN_ * 2);
    float* rowsum = (float*)alloc(NN_ * 4);
    float* cbuf   = (float*)alloc(256);
    float* Pp = (float*)alloc((size_t)4 * NN_ * NN_ * 4);  // split-K f32 partials
    // Tp aliases the NS-temp region; NS temps dead before first Tp use.
    float* Tp = (float*)(wsb + overlay);
    const size_t TPS = (size_t)BB * NN_;

    (void)hipMemsetAsync(wbh, 0, (size_t)BB * MM * sizeof(unsigned short), stream);

    const dim3 blk(256);
    const dim3 gsk(NN_ / 64, NN_ / 64, 4);
    const int  RED = (NN_ * NN_ / 4) / 256;   // 576

    rownorm_kernel<<<MM, blk, 0, stream>>>(w, wnH, wnL);
    transp_kernel<<<dim3(MM / 64, NN_ / 64), blk, 0, stream>>>(wnH, wnL, wnTH, wnTL);

    // adotb = x @ wn^T (M2048 N3072 K768); emit y2_0 AND adh. BK=64 (R20-exact).
    gemm_big<64,32,48,1,8,24,0,0,0,4,0><<<1536, blk, 0, stream>>>(
        x, nullptr, NN_, 0, wnH, wnL, NN_, nullptr, MM, 0, NN_,
        nullptr, nullptr, nullptr, y2h, adh, nullptr);

    // G = wn^T wn + I (768x768, K=3072), split-K=4 + reduce(+I, split)
    gemm_sk<1><<<gsk, blk, 0, stream>>>(
        nullptr, wnTH, wnTL, MM, wnTH, wnTL, MM, Pp, MM / 4);
    red_ns<1><<<RED, blk, 0, stream>>>(Pp, nullptr, G, GH, GL);

    rowabs_kernel<<<NN_, blk, 0, stream>>>(G, rowsum);
    cmax_kernel<<<1, blk, 0, stream>>>(rowsum, cbuf);
    initdiag_kernel<<<(NN_ * NN_) / 256, blk, 0, stream>>>(X0, cbuf);

    // Newton-Schulz X <- 2X - XGX, 7 iterations, split-K=4 per GEMM
    float* Xc = X0;
    float* Xn = X1;
    for (int it = 0; it < 7; ++it) {
        gemm_sk<0><<<gsk, blk, 0, stream>>>(
            Xc, nullptr, nullptr, NN_, GH, GL, NN_, Pp, NN_ / 4);
        red_ns<0><<<RED, blk, 0, stream>>>(Pp, nullptr, Yb, YbH, YbL);
        gemm_sk<0><<<gsk, blk, 0, stream>>>(
            Xc, nullptr, nullptr, NN_, YbH, YbL, NN_, Pp, NN_ / 4);
        red_ns<2><<<RED, blk, 0, stream>>>(Pp, Xc, Xn, QH, QL);
        float* t = Xc; Xc = Xn; Xn = t;
    }
    // QH/QL = fp16 split of G^{-1}

    // RT = wn @ Ginv (M3072 N768 K768); emit RTH/RTL. B 2-term, BK=64.
    gemm_big<64,48,12,1,12,6,1,0,0,2,0><<<576, blk, 0, stream>>>(
        nullptr, wnH, NN_, 0, QH, QL, NN_, Tp, NN_, 0, NN_,
        nullptr, nullptr, nullptr, nullptr, RTH, RTL);

    // ADMM loop: T = y2 @ wn -> fp16 partials Thp (KS=2, B single, BK=128);
    // w-update: A = Thp pair (AMODE=4), B = RT single fp16, BK=128.
    for (int it = 0; it < 20; ++it) {
        gemm_big<128,32,12,2,16,6,1,1,4,0,0><<<768, blk, 0, stream>>>(
            nullptr, y2h, MM, 0, wnTH, nullptr, MM, nullptr, NN_, TPS, MM / 2,
            nullptr, nullptr, nullptr, Thp, nullptr, nullptr);
        if (it < 19) {
            gemm_big<128,32,48,1,8,24,4,1,3,0,0><<<1536, blk, 0, stream>>>(
                nullptr, Thp, NN_, TPS, RTH, nullptr, NN_, nullptr, MM, 0, NN_,
                adh, wbh, nullptr, y2h, nullptr, nullptr);
        } else {
            gemm_big<128,32,48,1,8,24,4,1,3,0,1><<<1536, blk, 0, stream>>>(
                nullptr, Thp, NN_, TPS, RTH, nullptr, NN_, nullptr, MM, 0, NN_,
                adh, wbh, z, y2h, nullptr, nullptr);
        }
    }

    // decoded = z @ wn (M2048 N768 K3072), KS=2 f32 partials + reduce. BK=64.
    gemm_big<64,32,12,2,16,6,0,0,0,0,0><<<768, blk, 0, stream>>>(
        z, nullptr, MM, 0, wnTH, wnTL, MM, Tp, NN_, TPS, MM / 2,
        nullptr, nullptr, nullptr, nullptr, nullptr, nullptr);
    add2_kernel<<<(BB * NN_ / 4) / 256, blk, 0, stream>>>(Tp, TPS, dec);
}

// Round 22
// 1325.373 us; speedup vs baseline: 2.5453x; 1.0029x over previous
//
#include <hip/hip_runtime.h>
#include <math.h>

#define BB   2048
#define NN_  768
#define MM   3072
#define LAMBD 0.1f

typedef __attribute__((ext_vector_type(8))) _Float16 half8;
typedef __attribute__((ext_vector_type(4))) float  f32x4;
typedef __attribute__((ext_vector_type(4))) unsigned short us4;

union HB { _Float16 f; unsigned short u; };
struct HL { unsigned short h, l; };

__device__ __forceinline__ unsigned short h_bits(float f) {
    HB b; b.f = (_Float16)f; return b.u;
}
__device__ __forceinline__ HL split2h(float f) {
    HL r;
    HB b; b.f = (_Float16)f;
    r.h = b.u;
    const float fh = (float)b.f;
    HB c; c.f = (_Float16)(f - fh);
    r.l = c.u;
    return r;
}
__device__ __forceinline__ float clampl(float x) {
    return fminf(fmaxf(x, -LAMBD), LAMBD);
}
__device__ __forceinline__ float4 cvt4h(const unsigned short* p) {
    const us4 u = *(const us4*)p;
    HB a, b, c, d;
    a.u = u.x; b.u = u.y; c.u = u.z; d.u = u.w;
    float4 f;
    f.x = (float)a.f; f.y = (float)b.f; f.z = (float)c.f; f.w = (float)d.f;
    return f;
}

// ---------------------------------------------------------------------------
// Split-K small GEMM (768x768 out, fp16 3-term), 64x64 tile, BK=32,
// reg-prefetch, single LDS buffer + transposed epilogue. (R12/R18-proven.)
// ---------------------------------------------------------------------------
template<int APRE>
__global__ __launch_bounds__(256)
void gemm_sk(const float* __restrict__ A,
             const unsigned short* __restrict__ Ah,
             const unsigned short* __restrict__ Al,
             int lda,
             const unsigned short* __restrict__ Bh,
             const unsigned short* __restrict__ Bl,
             int ldb,
             float* __restrict__ P, int Kper)
{
    __shared__ __align__(16) char smem[20480];
    unsigned short (*AsH)[40] = (unsigned short (*)[40])(smem);
    unsigned short (*AsL)[40] = (unsigned short (*)[40])(smem + 5120);
    unsigned short (*BsH)[40] = (unsigned short (*)[40])(smem + 10240);
    unsigned short (*BsL)[40] = (unsigned short (*)[40])(smem + 15360);

    const int tid  = threadIdx.x;
    const int brow = blockIdx.y * 64;
    const int bcol = blockIdx.x * 64;
    const int koff = blockIdx.z * Kper;
    const int wave = tid >> 6, lane = tid & 63;
    const int wr = wave >> 1, wc = wave & 1;
    const int lrow = lane & 15, kg = lane >> 4;

    const int sk4  = (tid & 7) << 2;

    us4   rAh[2], rAl[2], rBh[2], rBl[2];
    float4 rAf[2];

    auto LOAD = [&](int k0) {
        #pragma unroll
        for (int p = 0; p < 2; ++p) {
            const int row = (p * 256 + tid) >> 3;
            const size_t ga = (size_t)(brow + row) * lda + k0 + sk4;
            const size_t gb = (size_t)(bcol + row) * ldb + k0 + sk4;
            if constexpr (APRE) {
                rAh[p] = *(const us4*)(Ah + ga);
                rAl[p] = *(const us4*)(Al + ga);
            } else {
                rAf[p] = *(const float4*)(A + ga);
            }
            rBh[p] = *(const us4*)(Bh + gb);
            rBl[p] = *(const us4*)(Bl + gb);
        }
    };
    auto STORE = [&]() {
        #pragma unroll
        for (int p = 0; p < 2; ++p) {
            const int row = (p * 256 + tid) >> 3;
            if constexpr (APRE) {
                *(us4*)&AsH[row][sk4] = rAh[p];
                *(us4*)&AsL[row][sk4] = rAl[p];
            } else {
                const HL sx = split2h(rAf[p].x), sy = split2h(rAf[p].y);
                const HL sz = split2h(rAf[p].z), sw = split2h(rAf[p].w);
                us4 h, l;
                h.x = sx.h; l.x = sx.l; h.y = sy.h; l.y = sy.l;
                h.z = sz.h; l.z = sz.l; h.w = sw.h; l.w = sw.l;
                *(us4*)&AsH[row][sk4] = h;
                *(us4*)&AsL[row][sk4] = l;
            }
            *(us4*)&BsH[row][sk4] = rBh[p];
            *(us4*)&BsL[row][sk4] = rBl[p];
        }
    };

    f32x4 acc[2][2];
    #pragma unroll
    for (int m = 0; m < 2; ++m)
        #pragma unroll
        for (int n = 0; n < 2; ++n)
            #pragma unroll
            for (int q = 0; q < 4; ++q) acc[m][n][q] = 0.0f;

    const int NK = Kper / 32;
    LOAD(koff);
    STORE();
    __syncthreads();

    for (int ki = 0; ki < NK; ++ki) {
        if (ki + 1 < NK) LOAD(koff + (ki + 1) * 32);

        half8 ahi[2], alo[2], bhi[2], blo[2];
        #pragma unroll
        for (int m = 0; m < 2; ++m) {
            const int r = wr * 32 + m * 16 + lrow;
            ahi[m] = *(const half8*)&AsH[r][kg * 8];
            alo[m] = *(const half8*)&AsL[r][kg * 8];
        }
        #pragma unroll
        for (int n = 0; n < 2; ++n) {
            const int c = wc * 32 + n * 16 + lrow;
            bhi[n] = *(const half8*)&BsH[c][kg * 8];
            blo[n] = *(const half8*)&BsL[c][kg * 8];
        }
        #pragma unroll
        for (int m = 0; m < 2; ++m)
            #pragma unroll
            for (int n = 0; n < 2; ++n) {
                acc[m][n] = __builtin_amdgcn_mfma_f32_16x16x32_f16(ahi[m], bhi[n], acc[m][n], 0, 0, 0);
                acc[m][n] = __builtin_amdgcn_mfma_f32_16x16x32_f16(ahi[m], blo[n], acc[m][n], 0, 0, 0);
                acc[m][n] = __builtin_amdgcn_mfma_f32_16x16x32_f16(alo[m], bhi[n], acc[m][n], 0, 0, 0);
            }
        __syncthreads();
        if (ki + 1 < NK) { STORE(); __syncthreads(); }
    }

    // transposed epilogue: acc -> LDS [64][65] -> coalesced float4 rows
    float* eb = (float*)smem;
    #pragma unroll
    for (int m = 0; m < 2; ++m)
        #pragma unroll
        for (int n = 0; n < 2; ++n)
            #pragma unroll
            for (int r = 0; r < 4; ++r)
                eb[(wr * 32 + m * 16 + kg * 4 + r) * 65 + wc * 32 + n * 16 + lrow] = acc[m][n][r];
    __syncthreads();
    float* Pk = P + (size_t)blockIdx.z * NN_ * NN_;
    #pragma unroll
    for (int j = 0; j < 4; ++j) {
        const int row = wave * 16 + j * 4 + (lane >> 4);
        const int col = (lane & 15) * 4;
        const float4 v = *(const float4*)&eb[row * 65 + col];
        *(float4*)(Pk + (size_t)(brow + row) * NN_ + bcol + col) = v;
    }
}

// Reduce 4 split-K partials with epilogue. MODE: 0 plain, 1 +I, 2 2*E1-sum.
template<int MODE>
__global__ __launch_bounds__(256)
void red_ns(const float* __restrict__ P,
            const float* __restrict__ E1,
            float* __restrict__ C,
            unsigned short* __restrict__ Ch,
            unsigned short* __restrict__ Cl)
{
    const size_t i4 = ((size_t)blockIdx.x * 256 + threadIdx.x) * 4;
    const size_t sz = (size_t)NN_ * NN_;
    float4 s = *(const float4*)(P + i4);
    const float4 s1 = *(const float4*)(P + sz + i4);
    const float4 s2 = *(const float4*)(P + 2 * sz + i4);
    const float4 s3 = *(const float4*)(P + 3 * sz + i4);
    s.x = (s.x + s1.x) + (s2.x + s3.x);
    s.y = (s.y + s1.y) + (s2.y + s3.y);
    s.z = (s.z + s1.z) + (s2.z + s3.z);
    s.w = (s.w + s1.w) + (s2.w + s3.w);
    float v[4] = {s.x, s.y, s.z, s.w};
    if constexpr (MODE == 1) {
        const int row = (int)(i4 / NN_);
        const int col = (int)(i4 - (size_t)row * NN_);
        #pragma unroll
        for (int j = 0; j < 4; ++j) if (row == col + j) v[j] += 1.0f;
    }
    if constexpr (MODE == 2) {
        const float4 e = *(const float4*)(E1 + i4);
        v[0] = 2.0f * e.x - v[0]; v[1] = 2.0f * e.y - v[1];
        v[2] = 2.0f * e.z - v[2]; v[3] = 2.0f * e.w - v[3];
    }
    float4 o; o.x = v[0]; o.y = v[1]; o.z = v[2]; o.w = v[3];
    *(float4*)(C + i4) = o;
    us4 h, l;
    const HL a = split2h(v[0]), b = split2h(v[1]);
    const HL c = split2h(v[2]), d = split2h(v[3]);
    h.x = a.h; l.x = a.l; h.y = b.h; l.y = b.l;
    h.z = c.h; l.z = c.l; h.w = d.h; l.w = d.l;
    *(us4*)(Ch + i4) = h;
    *(us4*)(Cl + i4) = l;
}

// ---------------------------------------------------------------------------
// Big fp16 GEMM: 64x64 tile, 4 waves (32x32), BK=64 or 128.
// AMODE: 0 f32 A -> cvt; 1 pre-cvt fp16 (Ah); 4 fp16 pair Ah/Ah+psz summed.
// BS: 1 = B single fp16 (Bh only); 0 = B 2-term h/l.
// EPI: 0 C=acc f32 (+EMIT); 3 ADMM w-update; 4 fp16 partial -> Y2[cks*ks+gi].
// EMIT: 0 none, 1 Y2=fp16, 2 EH/EL=split, 4 Y2+EH=fp16(acc), NO C.
// ---------------------------------------------------------------------------
template<int BK, int NBM, int NBN, int KS, int PM, int PN, int AMODE, int BS, int EPI, int EMIT, int LASTZ>
__global__ __launch_bounds__(256)
void gemm_big(const float* __restrict__ A,
              const unsigned short* __restrict__ Ah,
              int lda, size_t psz,
              const unsigned short* __restrict__ Bh,
              const unsigned short* __restrict__ Bl,
              int ldb,
              float* __restrict__ C, int ldc, size_t cks, int Kper,
              const unsigned short* __restrict__ F1h,
              unsigned short* __restrict__ Wh,
              float* __restrict__ OutZ,
              unsigned short* __restrict__ Y2,
              unsigned short* __restrict__ EH,
              unsigned short* __restrict__ EL)
{
    static_assert(NBM % PM == 0 && NBN % PN == 0, "patch divides grid");
    constexpr int XM = NBM / PM, XN = NBN / PN;
    static_assert(XM * XN * KS == 8, "patches x KS must equal 8 XCDs");
    static_assert(PM * PN == (NBM * NBN * KS) / 8, "slot count");
    static_assert(BK == 64 || BK == 128, "BK");

    constexpr int LDR = BK + 8;
    constexpr int MSZ = 64 * LDR * 2;
    constexpr int SMB_STAGE = (BS ? 2 : 3) * MSZ;
    constexpr int SMB = SMB_STAGE > 16640 ? SMB_STAGE : 16640;
    __shared__ __align__(16) char smem[SMB];
    unsigned short (*AsH)[LDR] = (unsigned short (*)[LDR])(smem);
    unsigned short (*BsH)[LDR] = (unsigned short (*)[LDR])(smem + MSZ);
    unsigned short (*BsL)[LDR] = (unsigned short (*)[LDR])(smem + 2 * MSZ);

    const int bid  = blockIdx.x;
    const int xcd  = bid & 7;
    const int slot = bid >> 3;
    const int ks   = xcd % KS;
    const int rest = xcd / KS;
    const int xn   = rest % XN;
    const int xm   = rest / XN;
    const int m_   = xm * PM + slot / PN;
    const int n_   = xn * PN + slot % PN;
    const int brow = m_ * 64;
    const int bcol = n_ * 64;
    const int koff = ks * Kper;

    const int tid  = threadIdx.x;
    const int wave = tid >> 6, lane = tid & 63;
    const int wr = wave >> 1, wc = wave & 1;
    const int lrow = lane & 15, kg = lane >> 4;

    const int srow = tid >> 2, sk16 = (tid & 3) << 4;   // 16 fp16 per thread per 64-half

    // half-0 registers
    uint4  pA0, pA1, pA2, pA3, pB0, pB1, pB2, pB3;
    float4 pF[4];
    // half-1 registers (BK=128 only)
    uint4  qA0, qA1, qA2, qA3, qB0, qB1;
    float4 qF[4];

    auto LOAD = [&](int k0) {
        {
            const size_t ga = (size_t)(brow + srow) * lda + k0 + sk16;
            if constexpr (AMODE == 1) {
                pA0 = *(const uint4*)(Ah + ga);
                pA1 = *(const uint4*)(Ah + ga + 8);
            } else if constexpr (AMODE == 4) {
                pA0 = *(const uint4*)(Ah + ga);
                pA1 = *(const uint4*)(Ah + ga + 8);
                pA2 = *(const uint4*)(Ah + ga + psz);
                pA3 = *(const uint4*)(Ah + ga + psz + 8);
            } else {
                pF[0] = *(const float4*)(A + ga);
                pF[1] = *(const float4*)(A + ga + 4);
                pF[2] = *(const float4*)(A + ga + 8);
                pF[3] = *(const float4*)(A + ga + 12);
            }
            const size_t gb = (size_t)(bcol + srow) * ldb + k0 + sk16;
            pB0 = *(const uint4*)(Bh + gb);
            pB1 = *(const uint4*)(Bh + gb + 8);
            if constexpr (!BS) {
                pB2 = *(const uint4*)(Bl + gb);
                pB3 = *(const uint4*)(Bl + gb + 8);
            }
        }
        if constexpr (BK == 128) {
            const size_t ga = (size_t)(brow + srow) * lda + k0 + 64 + sk16;
            if constexpr (AMODE == 1) {
                qA0 = *(const uint4*)(Ah + ga);
                qA1 = *(const uint4*)(Ah + ga + 8);
            } else if constexpr (AMODE == 4) {
                qA0 = *(const uint4*)(Ah + ga);
                qA1 = *(const uint4*)(Ah + ga + 8);
                qA2 = *(const uint4*)(Ah + ga + psz);
                qA3 = *(const uint4*)(Ah + ga + psz + 8);
            } else {
                qF[0] = *(const float4*)(A + ga);
                qF[1] = *(const float4*)(A + ga + 4);
                qF[2] = *(const float4*)(A + ga + 8);
                qF[3] = *(const float4*)(A + ga + 12);
            }
            const size_t gb = (size_t)(bcol + srow) * ldb + k0 + 64 + sk16;
            qB0 = *(const uint4*)(Bh + gb);
            qB1 = *(const uint4*)(Bh + gb + 8);
        }
    };
    auto STORE = [&]() {
        {
            if constexpr (AMODE == 1) {
                *(uint4*)&AsH[srow][sk16]     = pA0;
                *(uint4*)&AsH[srow][sk16 + 8] = pA1;
            } else if constexpr (AMODE == 4) {
                half8 s0 = *(half8*)&pA0 + *(half8*)&pA2;
                half8 s1 = *(half8*)&pA1 + *(half8*)&pA3;
                *(half8*)&AsH[srow][sk16]     = s0;
                *(half8*)&AsH[srow][sk16 + 8] = s1;
            } else {
                half8 h0, h1;
                h0[0] = (_Float16)pF[0].x; h0[1] = (_Float16)pF[0].y;
                h0[2] = (_Float16)pF[0].z; h0[3] = (_Float16)pF[0].w;
                h0[4] = (_Float16)pF[1].x; h0[5] = (_Float16)pF[1].y;
                h0[6] = (_Float16)pF[1].z; h0[7] = (_Float16)pF[1].w;
                h1[0] = (_Float16)pF[2].x; h1[1] = (_Float16)pF[2].y;
                h1[2] = (_Float16)pF[2].z; h1[3] = (_Float16)pF[2].w;
                h1[4] = (_Float16)pF[3].x; h1[5] = (_Float16)pF[3].y;
                h1[6] = (_Float16)pF[3].z; h1[7] = (_Float16)pF[3].w;
                *(half8*)&AsH[srow][sk16]     = h0;
                *(half8*)&AsH[srow][sk16 + 8] = h1;
            }
            *(uint4*)&BsH[srow][sk16]     = pB0;
            *(uint4*)&BsH[srow][sk16 + 8] = pB1;
            if constexpr (!BS) {
                *(uint4*)&BsL[srow][sk16]     = pB2;
                *(uint4*)&BsL[srow][sk16 + 8] = pB3;
            }
        }
        if constexpr (BK == 128) {
            const int k2 = 64 + sk16;
            if constexpr (AMODE == 1) {
                *(uint4*)&AsH[srow][k2]     = qA0;
                *(uint4*)&AsH[srow][k2 + 8] = qA1;
            } else if constexpr (AMODE == 4) {
                half8 s0 = *(half8*)&qA0 + *(half8*)&qA2;
                half8 s1 = *(half8*)&qA1 + *(half8*)&qA3;
                *(half8*)&AsH[srow][k2]     = s0;
                *(half8*)&AsH[srow][k2 + 8] = s1;
            } else {
                half8 h0, h1;
                h0[0] = (_Float16)qF[0].x; h0[1] = (_Float16)qF[0].y;
                h0[2] = (_Float16)qF[0].z; h0[3] = (_Float16)qF[0].w;
                h0[4] = (_Float16)qF[1].x; h0[5] = (_Float16)qF[1].y;
                h0[6] = (_Float16)qF[1].z; h0[7] = (_Float16)qF[1].w;
                h1[0] = (_Float16)qF[2].x; h1[1] = (_Float16)qF[2].y;
                h1[2] = (_Float16)qF[2].z; h1[3] = (_Float16)qF[2].w;
                h1[4] = (_Float16)qF[3].x; h1[5] = (_Float16)qF[3].y;
                h1[6] = (_Float16)qF[3].z; h1[7] = (_Float16)qF[3].w;
                *(half8*)&AsH[srow][k2]     = h0;
                *(half8*)&AsH[srow][k2 + 8] = h1;
            }
            *(uint4*)&BsH[srow][k2]     = qB0;
            *(uint4*)&BsH[srow][k2 + 8] = qB1;
        }
    };

    f32x4 acc[2][2];
    #pragma unroll
    for (int m = 0; m < 2; ++m)
        #pragma unroll
        for (int n = 0; n < 2; ++n)
            #pragma unroll
            for (int q = 0; q < 4; ++q) acc[m][n][q] = 0.0f;

    const int NK = Kper / BK;
    LOAD(koff);
    STORE();
    __syncthreads();

    for (int ki = 0; ki < NK; ++ki) {
        if (ki + 1 < NK) LOAD(koff + (ki + 1) * BK);

        #pragma unroll
        for (int kk = 0; kk < BK / 32; ++kk) {
            const int kc = kk * 32 + kg * 8;
            half8 a[2], bh[2], bl[2];
            #pragma unroll
            for (int m = 0; m < 2; ++m)
                a[m] = *(const half8*)&AsH[wr * 32 + m * 16 + lrow][kc];
            #pragma unroll
            for (int n = 0; n < 2; ++n) {
                const int c = wc * 32 + n * 16 + lrow;
                bh[n] = *(const half8*)&BsH[c][kc];
                if constexpr (!BS) bl[n] = *(const half8*)&BsL[c][kc];
            }
            #pragma unroll
            for (int m = 0; m < 2; ++m)
                #pragma unroll
                for (int n = 0; n < 2; ++n) {
                    acc[m][n] = __builtin_amdgcn_mfma_f32_16x16x32_f16(a[m], bh[n], acc[m][n], 0, 0, 0);
                    if constexpr (!BS)
                        acc[m][n] = __builtin_amdgcn_mfma_f32_16x16x32_f16(a[m], bl[n], acc[m][n], 0, 0, 0);
                }
        }
        __syncthreads();
        if (ki + 1 < NK) { STORE(); __syncthreads(); }
    }

    // ---- transposed epilogue: acc -> LDS [64][65] -> whole-row float4 I/O ----
    float* eb = (float*)smem;
    #pragma unroll
    for (int m = 0; m < 2; ++m)
        #pragma unroll
        for (int n = 0; n < 2; ++n)
            #pragma unroll
            for (int r = 0; r < 4; ++r)
                eb[(wr * 32 + m * 16 + kg * 4 + r) * 65 + wc * 32 + n * 16 + lrow] = acc[m][n][r];
    __syncthreads();

    #pragma unroll
    for (int j = 0; j < 4; ++j) {
        const int row = wave * 16 + j * 4 + (lane >> 4);
        const int col = (lane & 15) * 4;
        const float4 v = *(const float4*)&eb[row * 65 + col];
        const size_t gi = (size_t)(brow + row) * ldc + bcol + col;
        if constexpr (EPI == 0) {
            if constexpr (EMIT != 4)
                *(float4*)(C + cks * ks + gi) = v;
            if constexpr (EMIT == 1) {
                us4 h;
                h.x = h_bits(v.x); h.y = h_bits(v.y);
                h.z = h_bits(v.z); h.w = h_bits(v.w);
                *(us4*)(Y2 + gi) = h;
            }
            if constexpr (EMIT == 2) {
                const HL a = split2h(v.x), b = split2h(v.y);
                const HL c2 = split2h(v.z), d = split2h(v.w);
                us4 h, l;
                h.x = a.h; l.x = a.l; h.y = b.h; l.y = b.l;
                h.z = c2.h; l.z = c2.l; h.w = d.h; l.w = d.l;
                *(us4*)(EH + gi) = h;
                *(us4*)(EL + gi) = l;
            }
            if constexpr (EMIT == 4) {
                us4 h;
                h.x = h_bits(v.x); h.y = h_bits(v.y);
                h.z = h_bits(v.z); h.w = h_bits(v.w);
                *(us4*)(Y2 + gi) = h;
                *(us4*)(EH + gi) = h;
            }
        } else if constexpr (EPI == 4) {
            us4 h;
            h.x = h_bits(v.x); h.y = h_bits(v.y);
            h.z = h_bits(v.z); h.w = h_bits(v.w);
            *(us4*)(Y2 + cks * ks + gi) = h;
        } else { // EPI == 3
            const float4 f1 = cvt4h(F1h + gi);
            const float4 ww = cvt4h(Wh + gi);
            const float f1v[4] = {f1.x, f1.y, f1.z, f1.w};
            const float wwv[4] = {ww.x, ww.y, ww.z, ww.w};
            const float vv[4]  = {v.x, v.y, v.z, v.w};
            float wn[4];
            #pragma unroll
            for (int q = 0; q < 4; ++q)
                wn[q] = f1v[q] + wwv[q] - clampl(wwv[q]) - vv[q];
            if constexpr (LASTZ) {
                float4 o;
                o.x = wn[0] - clampl(wn[0]); o.y = wn[1] - clampl(wn[1]);
                o.z = wn[2] - clampl(wn[2]); o.w = wn[3] - clampl(wn[3]);
                *(float4*)(OutZ + gi) = o;
            } else {
                us4 hh, y;
                #pragma unroll
                for (int q = 0; q < 4; ++q) {
                    ((unsigned short*)&hh)[q] = h_bits(wn[q]);
                    ((unsigned short*)&y)[q]  = h_bits(f1v[q] + wn[q] - 2.0f * clampl(wn[q]));
                }
                *(us4*)(Wh + gi) = hh;
                *(us4*)(Y2 + gi) = y;
            }
        }
    }
}

// Normalize rows of weight (3072x768); emit fp16 h/l of wn (row-major ONLY).
__global__ __launch_bounds__(256)
void rownorm_kernel(const float* __restrict__ W,
                    unsigned short* __restrict__ wnH, unsigned short* __restrict__ wnL)
{
    __shared__ float red[256];
    const int row = blockIdx.x;
    const int t = threadIdx.x;
    const float* wr = W + (size_t)row * NN_;
    float s = 0.0f;
    for (int k = t; k < NN_; k += 256) { const float w = wr[k]; s += w * w; }
    red[t] = s; __syncthreads();
    for (int off = 128; off > 0; off >>= 1) {
        if (t < off) red[t] += red[t + off];
        __syncthreads();
    }
    const float rn = 1.0f / sqrtf(red[0]);
    for (int k = t; k < NN_; k += 256) {
        const float v = wr[k] * rn;
        const HL s2 = split2h(v);
        wnH[(size_t)row * NN_ + k] = s2.h;
        wnL[(size_t)row * NN_ + k] = s2.l;
    }
}

// Tiled transpose: wn (3072x768) h/l -> wnT (768x3072) h/l, LDS-coalesced.
__global__ __launch_bounds__(256)
void transp_kernel(const unsigned short* __restrict__ SH,
                   const unsigned short* __restrict__ SL,
                   unsigned short* __restrict__ DH,
                   unsigned short* __restrict__ DL)
{
    __shared__ unsigned short tH[64][68];
    __shared__ unsigned short tL[64][68];
    const int tid = threadIdx.x;
    const int r0 = blockIdx.x * 64;
    const int c0 = blockIdx.y * 64;
    #pragma unroll
    for (int p = 0; p < 2; ++p) {
        const int idx = p * 256 + tid;
        const int r = idx >> 3, c8 = (idx & 7) * 8;
        const size_t g = (size_t)(r0 + r) * NN_ + c0 + c8;
        *(uint4*)&tH[r][c8] = *(const uint4*)(SH + g);
        *(uint4*)&tL[r][c8] = *(const uint4*)(SL + g);
    }
    __syncthreads();
    #pragma unroll
    for (int p = 0; p < 2; ++p) {
        const int idx = p * 256 + tid;
        const int k = idx >> 3, m8 = (idx & 7) * 8;
        us4 h0, h1, l0, l1;
        h0.x = tH[m8+0][k]; h0.y = tH[m8+1][k]; h0.z = tH[m8+2][k]; h0.w = tH[m8+3][k];
        h1.x = tH[m8+4][k]; h1.y = tH[m8+5][k]; h1.z = tH[m8+6][k]; h1.w = tH[m8+7][k];
        l0.x = tL[m8+0][k]; l0.y = tL[m8+1][k]; l0.z = tL[m8+2][k]; l0.w = tL[m8+3][k];
        l1.x = tL[m8+4][k]; l1.y = tL[m8+5][k]; l1.z = tL[m8+6][k]; l1.w = tL[m8+7][k];
        const size_t g = (size_t)(c0 + k) * MM + r0 + m8;
        *(us4*)(DH + g)     = h0;
        *(us4*)(DH + g + 4) = h1;
        *(us4*)(DL + g)     = l0;
        *(us4*)(DL + g + 4) = l1;
    }
}

__global__ __launch_bounds__(256)
void rowabs_kernel(const float* __restrict__ G, float* __restrict__ rowsum)
{
    __shared__ float red[256];
    const int row = blockIdx.x;
    const int t = threadIdx.x;
    const float* gr = G + (size_t)row * NN_;
    float s = 0.0f;
    for (int k = t; k < NN_; k += 256) s += fabsf(gr[k]);
    red[t] = s; __syncthreads();
    for (int off = 128; off > 0; off >>= 1) {
        if (t < off) red[t] += red[t + off];
        __syncthreads();
    }
    if (t == 0) rowsum[row] = red[0];
}

__global__ __launch_bounds__(256)
void cmax_kernel(const float* __restrict__ rowsum, float* __restrict__ cbuf)
{
    __shared__ float red[256];
    const int t = threadIdx.x;
    float mx = 0.0f;
    for (int k = t; k < NN_; k += 256) mx = fmaxf(mx, rowsum[k]);
    red[t] = mx; __syncthreads();
    for (int off = 128; off > 0; off >>= 1) {
        if (t < off) red[t] = fmaxf(red[t], red[t + off]);
        __syncthreads();
    }
    if (t == 0) cbuf[0] = 2.0f / (1.0f + red[0]);
}

__global__ __launch_bounds__(256)
void initdiag_kernel(float* __restrict__ X, const float* __restrict__ c)
{
    const int idx = blockIdx.x * 256 + threadIdx.x;
    const int p = idx / NN_, q = idx - p * NN_;
    X[idx] = (p == q) ? c[0] : 0.0f;
}

// dec = p0 + p1 (float4)
__global__ __launch_bounds__(256)
void add2_kernel(const float* __restrict__ p0, size_t ps, float* __restrict__ o)
{
    const size_t i = ((size_t)blockIdx.x * 256 + threadIdx.x) * 4;
    const float4 a = *(const float4*)(p0 + i);
    const float4 b = *(const float4*)(p0 + ps + i);
    float4 v;
    v.x = a.x + b.x; v.y = a.y + b.y;
    v.z = a.z + b.z; v.w = a.w + b.w;
    *(float4*)(o + i) = v;
}

extern "C" void kernel_launch(void* const* d_in, const int* in_sizes, int n_in,
                              void* d_out, int out_size, void* d_ws, size_t ws_size,
                              hipStream_t stream)
{
    const float* x = (const float*)d_in[0];   // (2048, 768)
    const float* w = (const float*)d_in[1];   // (3072, 768)

    float* out = (float*)d_out;
    float* z   = out;                          // (2048, 3072)
    float* dec = out + (size_t)BB * MM;        // (2048, 768)

    char* wsb = (char*)d_ws;
    size_t off = 0;
    auto alloc = [&](size_t bytes) -> void* {
        void* p = wsb + off;
        off += (bytes + 255) & ~(size_t)255;
        return p;
    };
    // --- persistent ---
    unsigned short* wnH  = (unsigned short*)alloc((size_t)MM * NN_ * 2);
    unsigned short* wnL  = (unsigned short*)alloc((size_t)MM * NN_ * 2);
    unsigned short* wnTH = (unsigned short*)alloc((size_t)MM * NN_ * 2);
    unsigned short* wnTL = (unsigned short*)alloc((size_t)MM * NN_ * 2);
    unsigned short* adh  = (unsigned short*)alloc((size_t)BB * MM * 2);  // fp16 adotb
    unsigned short* wbh  = (unsigned short*)alloc((size_t)BB * MM * 2);  // fp16 w state
    unsigned short* y2h  = (unsigned short*)alloc((size_t)BB * MM * 2);
    unsigned short* QH  = (unsigned short*)alloc((size_t)NN_ * NN_ * 2);
    unsigned short* QL  = (unsigned short*)alloc((size_t)NN_ * NN_ * 2);
    unsigned short* RTH = (unsigned short*)alloc((size_t)MM * NN_ * 2);
    unsigned short* RTL = (unsigned short*)alloc((size_t)MM * NN_ * 2);
    unsigned short* Thp = (unsigned short*)alloc((size_t)2 * BB * NN_ * 2); // fp16 T partials
    // --- overlay: NS temps (dead after RT) aliased with Tp (decode partials) ---
    const size_t overlay = off;
    float* G  = (float*)alloc((size_t)NN_ * NN_ * 4);
    unsigned short* GH  = (unsigned short*)alloc((size_t)NN_ * NN_ * 2);
    unsigned short* GL  = (unsigned short*)alloc((size_t)NN_ * NN_ * 2);
    float* X0 = (float*)alloc((size_t)NN_ * NN_ * 4);
    float* X1 = (float*)alloc((size_t)NN_ * NN_ * 4);
    float* Yb = (float*)alloc((size_t)NN_ * NN_ * 4);
    unsigned short* YbH = (unsigned short*)alloc((size_t)NN_ * NN_ * 2);
    unsigned short* YbL = (unsigned short*)alloc((size_t)NN_ * NN_ * 2);
    float* rowsum = (float*)alloc(NN_ * 4);
    float* cbuf   = (float*)alloc(256);
    float* Pp = (float*)alloc((size_t)4 * NN_ * NN_ * 4);  // split-K f32 partials
    // Tp aliases the NS-temp region; NS temps dead before first Tp use.
    float* Tp = (float*)(wsb + overlay);
    const size_t TPS = (size_t)BB * NN_;

    (void)hipMemsetAsync(wbh, 0, (size_t)BB * MM * sizeof(unsigned short), stream);

    const dim3 blk(256);
    const dim3 gsk(NN_ / 64, NN_ / 64, 4);
    const int  RED = (NN_ * NN_ / 4) / 256;   // 576

    rownorm_kernel<<<MM, blk, 0, stream>>>(w, wnH, wnL);
    transp_kernel<<<dim3(MM / 64, NN_ / 64), blk, 0, stream>>>(wnH, wnL, wnTH, wnTL);

    // adotb = x @ wn^T (M2048 N3072 K768); emit y2_0 AND adh. BK=128, B single.
    gemm_big<128,32,48,1,8,24,0,1,0,4,0><<<1536, blk, 0, stream>>>(
        x, nullptr, NN_, 0, wnH, nullptr, NN_, nullptr, MM, 0, NN_,
        nullptr, nullptr, nullptr, y2h, adh, nullptr);

    // G = wn^T wn + I (768x768, K=3072), split-K=4 + reduce(+I, split)
    gemm_sk<1><<<gsk, blk, 0, stream>>>(
        nullptr, wnTH, wnTL, MM, wnTH, wnTL, MM, Pp, MM / 4);
    red_ns<1><<<RED, blk, 0, stream>>>(Pp, nullptr, G, GH, GL);

    rowabs_kernel<<<NN_, blk, 0, stream>>>(G, rowsum);
    cmax_kernel<<<1, blk, 0, stream>>>(rowsum, cbuf);
    initdiag_kernel<<<(NN_ * NN_) / 256, blk, 0, stream>>>(X0, cbuf);

    // Newton-Schulz X <- 2X - XGX, 7 iterations, split-K=4 per GEMM
    float* Xc = X0;
    float* Xn = X1;
    for (int it = 0; it < 7; ++it) {
        gemm_sk<0><<<gsk, blk, 0, stream>>>(
            Xc, nullptr, nullptr, NN_, GH, GL, NN_, Pp, NN_ / 4);
        red_ns<0><<<RED, blk, 0, stream>>>(Pp, nullptr, Yb, YbH, YbL);
        gemm_sk<0><<<gsk, blk, 0, stream>>>(
            Xc, nullptr, nullptr, NN_, YbH, YbL, NN_, Pp, NN_ / 4);
        red_ns<2><<<RED, blk, 0, stream>>>(Pp, Xc, Xn, QH, QL);
        float* t = Xc; Xc = Xn; Xn = t;
    }
    // QH/QL = fp16 split of G^{-1}

    // RT = wn @ Ginv (M3072 N768 K768); emit RTH/RTL. B 2-term, BK=64.
    gemm_big<64,48,12,1,12,6,1,0,0,2,0><<<576, blk, 0, stream>>>(
        nullptr, wnH, NN_, 0, QH, QL, NN_, Tp, NN_, 0, NN_,
        nullptr, nullptr, nullptr, nullptr, RTH, RTL);

    // ADMM loop: T = y2 @ wn -> fp16 partials Thp (KS=2, B single, BK=128);
    // w-update: A = Thp pair (AMODE=4), B = RT single fp16, BK=128.
    for (int it = 0; it < 20; ++it) {
        gemm_big<128,32,12,2,16,6,1,1,4,0,0><<<768, blk, 0, stream>>>(
            nullptr, y2h, MM, 0, wnTH, nullptr, MM, nullptr, NN_, TPS, MM / 2,
            nullptr, nullptr, nullptr, Thp, nullptr, nullptr);
        if (it < 19) {
            gemm_big<128,32,48,1,8,24,4,1,3,0,0><<<1536, blk, 0, stream>>>(
                nullptr, Thp, NN_, TPS, RTH, nullptr, NN_, nullptr, MM, 0, NN_,
                adh, wbh, nullptr, y2h, nullptr, nullptr);
        } else {
            gemm_big<128,32,48,1,8,24,4,1,3,0,1><<<1536, blk, 0, stream>>>(
                nullptr, Thp, NN_, TPS, RTH, nullptr, NN_, nullptr, MM, 0, NN_,
                adh, wbh, z, y2h, nullptr, nullptr);
        }
    }

    // decoded = z @ wn (M2048 N768 K3072), KS=2 f32 partials + reduce. BK=64.
    gemm_big<64,32,12,2,16,6,0,0,0,0,0><<<768, blk, 0, stream>>>(
        z, nullptr, MM, 0, wnTH, wnTL, MM, Tp, NN_, TPS, MM / 2,
        nullptr, nullptr, nullptr, nullptr, nullptr, nullptr);
    add2_kernel<<<(BB * NN_ / 4) / 256, blk, 0, stream>>>(Tp, TPS, dec);
}

// Round 23
// 1306.867 us; speedup vs baseline: 2.5813x; 1.0142x over previous
//
#include <hip/hip_runtime.h>
#include <math.h>

#define BB   2048
#define NN_  768
#define MM   3072
#define LAMBD 0.1f

typedef __attribute__((ext_vector_type(8))) _Float16 half8;
typedef __attribute__((ext_vector_type(4))) float  f32x4;
typedef __attribute__((ext_vector_type(4))) unsigned short us4;

union HB { _Float16 f; unsigned short u; };
struct HL { unsigned short h, l; };

__device__ __forceinline__ unsigned short h_bits(float f) {
    HB b; b.f = (_Float16)f; return b.u;
}
__device__ __forceinline__ HL split2h(float f) {
    HL r;
    HB b; b.f = (_Float16)f;
    r.h = b.u;
    const float fh = (float)b.f;
    HB c; c.f = (_Float16)(f - fh);
    r.l = c.u;
    return r;
}
__device__ __forceinline__ float clampl(float x) {
    return fminf(fmaxf(x, -LAMBD), LAMBD);
}
__device__ __forceinline__ float4 cvt4h(const unsigned short* p) {
    const us4 u = *(const us4*)p;
    HB a, b, c, d;
    a.u = u.x; b.u = u.y; c.u = u.z; d.u = u.w;
    float4 f;
    f.x = (float)a.f; f.y = (float)b.f; f.z = (float)c.f; f.w = (float)d.f;
    return f;
}

// ---------------------------------------------------------------------------
// Split-K small GEMM (768x768 out, fp16 3-term), 64x64 tile, BK=32,
// reg-prefetch, single LDS buffer + transposed epilogue. (R12/R18-proven.)
// ---------------------------------------------------------------------------
template<int APRE>
__global__ __launch_bounds__(256)
void gemm_sk(const float* __restrict__ A,
             const unsigned short* __restrict__ Ah,
             const unsigned short* __restrict__ Al,
             int lda,
             const unsigned short* __restrict__ Bh,
             const unsigned short* __restrict__ Bl,
             int ldb,
             float* __restrict__ P, int Kper)
{
    __shared__ __align__(16) char smem[20480];
    unsigned short (*AsH)[40] = (unsigned short (*)[40])(smem);
    unsigned short (*AsL)[40] = (unsigned short (*)[40])(smem + 5120);
    unsigned short (*BsH)[40] = (unsigned short (*)[40])(smem + 10240);
    unsigned short (*BsL)[40] = (unsigned short (*)[40])(smem + 15360);

    const int tid  = threadIdx.x;
    const int brow = blockIdx.y * 64;
    const int bcol = blockIdx.x * 64;
    const int koff = blockIdx.z * Kper;
    const int wave = tid >> 6, lane = tid & 63;
    const int wr = wave >> 1, wc = wave & 1;
    const int lrow = lane & 15, kg = lane >> 4;

    const int sk4  = (tid & 7) << 2;

    us4   rAh[2], rAl[2], rBh[2], rBl[2];
    float4 rAf[2];

    auto LOAD = [&](int k0) {
        #pragma unroll
        for (int p = 0; p < 2; ++p) {
            const int row = (p * 256 + tid) >> 3;
            const size_t ga = (size_t)(brow + row) * lda + k0 + sk4;
            const size_t gb = (size_t)(bcol + row) * ldb + k0 + sk4;
            if constexpr (APRE) {
                rAh[p] = *(const us4*)(Ah + ga);
                rAl[p] = *(const us4*)(Al + ga);
            } else {
                rAf[p] = *(const float4*)(A + ga);
            }
            rBh[p] = *(const us4*)(Bh + gb);
            rBl[p] = *(const us4*)(Bl + gb);
        }
    };
    auto STORE = [&]() {
        #pragma unroll
        for (int p = 0; p < 2; ++p) {
            const int row = (p * 256 + tid) >> 3;
            if constexpr (APRE) {
                *(us4*)&AsH[row][sk4] = rAh[p];
                *(us4*)&AsL[row][sk4] = rAl[p];
            } else {
                const HL sx = split2h(rAf[p].x), sy = split2h(rAf[p].y);
                const HL sz = split2h(rAf[p].z), sw = split2h(rAf[p].w);
                us4 h, l;
                h.x = sx.h; l.x = sx.l; h.y = sy.h; l.y = sy.l;
                h.z = sz.h; l.z = sz.l; h.w = sw.h; l.w = sw.l;
                *(us4*)&AsH[row][sk4] = h;
                *(us4*)&AsL[row][sk4] = l;
            }
            *(us4*)&BsH[row][sk4] = rBh[p];
            *(us4*)&BsL[row][sk4] = rBl[p];
        }
    };

    f32x4 acc[2][2];
    #pragma unroll
    for (int m = 0; m < 2; ++m)
        #pragma unroll
        for (int n = 0; n < 2; ++n)
            #pragma unroll
            for (int q = 0; q < 4; ++q) acc[m][n][q] = 0.0f;

    const int NK = Kper / 32;
    LOAD(koff);
    STORE();
    __syncthreads();

    for (int ki = 0; ki < NK; ++ki) {
        if (ki + 1 < NK) LOAD(koff + (ki + 1) * 32);

        half8 ahi[2], alo[2], bhi[2], blo[2];
        #pragma unroll
        for (int m = 0; m < 2; ++m) {
            const int r = wr * 32 + m * 16 + lrow;
            ahi[m] = *(const half8*)&AsH[r][kg * 8];
            alo[m] = *(const half8*)&AsL[r][kg * 8];
        }
        #pragma unroll
        for (int n = 0; n < 2; ++n) {
            const int c = wc * 32 + n * 16 + lrow;
            bhi[n] = *(const half8*)&BsH[c][kg * 8];
            blo[n] = *(const half8*)&BsL[c][kg * 8];
        }
        #pragma unroll
        for (int m = 0; m < 2; ++m)
            #pragma unroll
            for (int n = 0; n < 2; ++n) {
                acc[m][n] = __builtin_amdgcn_mfma_f32_16x16x32_f16(ahi[m], bhi[n], acc[m][n], 0, 0, 0);
                acc[m][n] = __builtin_amdgcn_mfma_f32_16x16x32_f16(ahi[m], blo[n], acc[m][n], 0, 0, 0);
                acc[m][n] = __builtin_amdgcn_mfma_f32_16x16x32_f16(alo[m], bhi[n], acc[m][n], 0, 0, 0);
            }
        __syncthreads();
        if (ki + 1 < NK) { STORE(); __syncthreads(); }
    }

    // transposed epilogue: acc -> LDS [64][65] -> coalesced float4 rows
    float* eb = (float*)smem;
    #pragma unroll
    for (int m = 0; m < 2; ++m)
        #pragma unroll
        for (int n = 0; n < 2; ++n)
            #pragma unroll
            for (int r = 0; r < 4; ++r)
                eb[(wr * 32 + m * 16 + kg * 4 + r) * 65 + wc * 32 + n * 16 + lrow] = acc[m][n][r];
    __syncthreads();
    float* Pk = P + (size_t)blockIdx.z * NN_ * NN_;
    #pragma unroll
    for (int j = 0; j < 4; ++j) {
        const int row = wave * 16 + j * 4 + (lane >> 4);
        const int col = (lane & 15) * 4;
        const float4 v = *(const float4*)&eb[row * 65 + col];
        *(float4*)(Pk + (size_t)(brow + row) * NN_ + bcol + col) = v;
    }
}

// Reduce 4 split-K partials with epilogue. MODE: 0 plain, 1 +I, 2 2*E1-sum.
template<int MODE>
__global__ __launch_bounds__(256)
void red_ns(const float* __restrict__ P,
            const float* __restrict__ E1,
            float* __restrict__ C,
            unsigned short* __restrict__ Ch,
            unsigned short* __restrict__ Cl)
{
    const size_t i4 = ((size_t)blockIdx.x * 256 + threadIdx.x) * 4;
    const size_t sz = (size_t)NN_ * NN_;
    float4 s = *(const float4*)(P + i4);
    const float4 s1 = *(const float4*)(P + sz + i4);
    const float4 s2 = *(const float4*)(P + 2 * sz + i4);
    const float4 s3 = *(const float4*)(P + 3 * sz + i4);
    s.x = (s.x + s1.x) + (s2.x + s3.x);
    s.y = (s.y + s1.y) + (s2.y + s3.y);
    s.z = (s.z + s1.z) + (s2.z + s3.z);
    s.w = (s.w + s1.w) + (s2.w + s3.w);
    float v[4] = {s.x, s.y, s.z, s.w};
    if constexpr (MODE == 1) {
        const int row = (int)(i4 / NN_);
        const int col = (int)(i4 - (size_t)row * NN_);
        #pragma unroll
        for (int j = 0; j < 4; ++j) if (row == col + j) v[j] += 1.0f;
    }
    if constexpr (MODE == 2) {
        const float4 e = *(const float4*)(E1 + i4);
        v[0] = 2.0f * e.x - v[0]; v[1] = 2.0f * e.y - v[1];
        v[2] = 2.0f * e.z - v[2]; v[3] = 2.0f * e.w - v[3];
    }
    float4 o; o.x = v[0]; o.y = v[1]; o.z = v[2]; o.w = v[3];
    *(float4*)(C + i4) = o;
    us4 h, l;
    const HL a = split2h(v[0]), b = split2h(v[1]);
    const HL c = split2h(v[2]), d = split2h(v[3]);
    h.x = a.h; l.x = a.l; h.y = b.h; l.y = b.l;
    h.z = c.h; l.z = c.l; h.w = d.h; l.w = d.l;
    *(us4*)(Ch + i4) = h;
    *(us4*)(Cl + i4) = l;
}

// ---------------------------------------------------------------------------
// Big fp16 GEMM: 64x64 tile, 4 waves (32x32), BK=64 or 128.
// AMODE: 0 f32 A -> cvt; 1 pre-cvt fp16 (Ah); 4 fp16 pair Ah/Ah+psz summed.
// BS: 1 = B single fp16 (Bh only); 0 = B 2-term h/l.
// EPI: 0 C=acc f32 (+EMIT); 3 ADMM w-update; 4 fp16 partial -> Y2[cks*ks+gi].
// EMIT: 0 none, 1 Y2=fp16, 2 EH/EL=split, 4 Y2+EH=fp16(acc), NO C.
// FIRST: EPI=3 with w==0 (skip Wh read; first ADMM iteration, no memset).
// ---------------------------------------------------------------------------
template<int BK, int NBM, int NBN, int KS, int PM, int PN, int AMODE, int BS, int EPI, int EMIT, int LASTZ, int FIRST>
__global__ __launch_bounds__(256)
void gemm_big(const float* __restrict__ A,
              const unsigned short* __restrict__ Ah,
              int lda, size_t psz,
              const unsigned short* __restrict__ Bh,
              const unsigned short* __restrict__ Bl,
              int ldb,
              float* __restrict__ C, int ldc, size_t cks, int Kper,
              const unsigned short* __restrict__ F1h,
              unsigned short* __restrict__ Wh,
              float* __restrict__ OutZ,
              unsigned short* __restrict__ Y2,
              unsigned short* __restrict__ EH,
              unsigned short* __restrict__ EL)
{
    static_assert(NBM % PM == 0 && NBN % PN == 0, "patch divides grid");
    constexpr int XM = NBM / PM, XN = NBN / PN;
    static_assert(XM * XN * KS == 8, "patches x KS must equal 8 XCDs");
    static_assert(PM * PN == (NBM * NBN * KS) / 8, "slot count");
    static_assert(BK == 64 || BK == 128, "BK");

    constexpr int LDR = BK + 8;
    constexpr int MSZ = 64 * LDR * 2;
    constexpr int SMB_STAGE = (BS ? 2 : 3) * MSZ;
    constexpr int SMB = SMB_STAGE > 16640 ? SMB_STAGE : 16640;
    __shared__ __align__(16) char smem[SMB];
    unsigned short (*AsH)[LDR] = (unsigned short (*)[LDR])(smem);
    unsigned short (*BsH)[LDR] = (unsigned short (*)[LDR])(smem + MSZ);
    unsigned short (*BsL)[LDR] = (unsigned short (*)[LDR])(smem + 2 * MSZ);

    const int bid  = blockIdx.x;
    const int xcd  = bid & 7;
    const int slot = bid >> 3;
    const int ks   = xcd % KS;
    const int rest = xcd / KS;
    const int xn   = rest % XN;
    const int xm   = rest / XN;
    const int m_   = xm * PM + slot / PN;
    const int n_   = xn * PN + slot % PN;
    const int brow = m_ * 64;
    const int bcol = n_ * 64;
    const int koff = ks * Kper;

    const int tid  = threadIdx.x;
    const int wave = tid >> 6, lane = tid & 63;
    const int wr = wave >> 1, wc = wave & 1;
    const int lrow = lane & 15, kg = lane >> 4;

    const int srow = tid >> 2, sk16 = (tid & 3) << 4;   // 16 fp16 per thread per 64-half

    // half-0 registers
    uint4  pA0, pA1, pA2, pA3, pB0, pB1, pB2, pB3;
    float4 pF[4];
    // half-1 registers (BK=128 only)
    uint4  qA0, qA1, qA2, qA3, qB0, qB1;
    float4 qF[4];

    auto LOAD = [&](int k0) {
        {
            const size_t ga = (size_t)(brow + srow) * lda + k0 + sk16;
            if constexpr (AMODE == 1) {
                pA0 = *(const uint4*)(Ah + ga);
                pA1 = *(const uint4*)(Ah + ga + 8);
            } else if constexpr (AMODE == 4) {
                pA0 = *(const uint4*)(Ah + ga);
                pA1 = *(const uint4*)(Ah + ga + 8);
                pA2 = *(const uint4*)(Ah + ga + psz);
                pA3 = *(const uint4*)(Ah + ga + psz + 8);
            } else {
                pF[0] = *(const float4*)(A + ga);
                pF[1] = *(const float4*)(A + ga + 4);
                pF[2] = *(const float4*)(A + ga + 8);
                pF[3] = *(const float4*)(A + ga + 12);
            }
            const size_t gb = (size_t)(bcol + srow) * ldb + k0 + sk16;
            pB0 = *(const uint4*)(Bh + gb);
            pB1 = *(const uint4*)(Bh + gb + 8);
            if constexpr (!BS) {
                pB2 = *(const uint4*)(Bl + gb);
                pB3 = *(const uint4*)(Bl + gb + 8);
            }
        }
        if constexpr (BK == 128) {
            const size_t ga = (size_t)(brow + srow) * lda + k0 + 64 + sk16;
            if constexpr (AMODE == 1) {
                qA0 = *(const uint4*)(Ah + ga);
                qA1 = *(const uint4*)(Ah + ga + 8);
            } else if constexpr (AMODE == 4) {
                qA0 = *(const uint4*)(Ah + ga);
                qA1 = *(const uint4*)(Ah + ga + 8);
                qA2 = *(const uint4*)(Ah + ga + psz);
                qA3 = *(const uint4*)(Ah + ga + psz + 8);
            } else {
                qF[0] = *(const float4*)(A + ga);
                qF[1] = *(const float4*)(A + ga + 4);
                qF[2] = *(const float4*)(A + ga + 8);
                qF[3] = *(const float4*)(A + ga + 12);
            }
            const size_t gb = (size_t)(bcol + srow) * ldb + k0 + 64 + sk16;
            qB0 = *(const uint4*)(Bh + gb);
            qB1 = *(const uint4*)(Bh + gb + 8);
        }
    };
    auto STORE = [&]() {
        {
            if constexpr (AMODE == 1) {
                *(uint4*)&AsH[srow][sk16]     = pA0;
                *(uint4*)&AsH[srow][sk16 + 8] = pA1;
            } else if constexpr (AMODE == 4) {
                half8 s0 = *(half8*)&pA0 + *(half8*)&pA2;
                half8 s1 = *(half8*)&pA1 + *(half8*)&pA3;
                *(half8*)&AsH[srow][sk16]     = s0;
                *(half8*)&AsH[srow][sk16 + 8] = s1;
            } else {
                half8 h0, h1;
                h0[0] = (_Float16)pF[0].x; h0[1] = (_Float16)pF[0].y;
                h0[2] = (_Float16)pF[0].z; h0[3] = (_Float16)pF[0].w;
                h0[4] = (_Float16)pF[1].x; h0[5] = (_Float16)pF[1].y;
                h0[6] = (_Float16)pF[1].z; h0[7] = (_Float16)pF[1].w;
                h1[0] = (_Float16)pF[2].x; h1[1] = (_Float16)pF[2].y;
                h1[2] = (_Float16)pF[2].z; h1[3] = (_Float16)pF[2].w;
                h1[4] = (_Float16)pF[3].x; h1[5] = (_Float16)pF[3].y;
                h1[6] = (_Float16)pF[3].z; h1[7] = (_Float16)pF[3].w;
                *(half8*)&AsH[srow][sk16]     = h0;
                *(half8*)&AsH[srow][sk16 + 8] = h1;
            }
            *(uint4*)&BsH[srow][sk16]     = pB0;
            *(uint4*)&BsH[srow][sk16 + 8] = pB1;
            if constexpr (!BS) {
                *(uint4*)&BsL[srow][sk16]     = pB2;
                *(uint4*)&BsL[srow][sk16 + 8] = pB3;
            }
        }
        if constexpr (BK == 128) {
            const int k2 = 64 + sk16;
            if constexpr (AMODE == 1) {
                *(uint4*)&AsH[srow][k2]     = qA0;
                *(uint4*)&AsH[srow][k2 + 8] = qA1;
            } else if constexpr (AMODE == 4) {
                half8 s0 = *(half8*)&qA0 + *(half8*)&qA2;
                half8 s1 = *(half8*)&qA1 + *(half8*)&qA3;
                *(half8*)&AsH[srow][k2]     = s0;
                *(half8*)&AsH[srow][k2 + 8] = s1;
            } else {
                half8 h0, h1;
                h0[0] = (_Float16)qF[0].x; h0[1] = (_Float16)qF[0].y;
                h0[2] = (_Float16)qF[0].z; h0[3] = (_Float16)qF[0].w;
                h0[4] = (_Float16)qF[1].x; h0[5] = (_Float16)qF[1].y;
                h0[6] = (_Float16)qF[1].z; h0[7] = (_Float16)qF[1].w;
                h1[0] = (_Float16)qF[2].x; h1[1] = (_Float16)qF[2].y;
                h1[2] = (_Float16)qF[2].z; h1[3] = (_Float16)qF[2].w;
                h1[4] = (_Float16)qF[3].x; h1[5] = (_Float16)qF[3].y;
                h1[6] = (_Float16)qF[3].z; h1[7] = (_Float16)qF[3].w;
                *(half8*)&AsH[srow][k2]     = h0;
                *(half8*)&AsH[srow][k2 + 8] = h1;
            }
            *(uint4*)&BsH[srow][k2]     = qB0;
            *(uint4*)&BsH[srow][k2 + 8] = qB1;
        }
    };

    f32x4 acc[2][2];
    #pragma unroll
    for (int m = 0; m < 2; ++m)
        #pragma unroll
        for (int n = 0; n < 2; ++n)
            #pragma unroll
            for (int q = 0; q < 4; ++q) acc[m][n][q] = 0.0f;

    const int NK = Kper / BK;
    LOAD(koff);
    STORE();
    __syncthreads();

    for (int ki = 0; ki < NK; ++ki) {
        if (ki + 1 < NK) LOAD(koff + (ki + 1) * BK);

        #pragma unroll
        for (int kk = 0; kk < BK / 32; ++kk) {
            const int kc = kk * 32 + kg * 8;
            half8 a[2], bh[2], bl[2];
            #pragma unroll
            for (int m = 0; m < 2; ++m)
                a[m] = *(const half8*)&AsH[wr * 32 + m * 16 + lrow][kc];
            #pragma unroll
            for (int n = 0; n < 2; ++n) {
                const int c = wc * 32 + n * 16 + lrow;
                bh[n] = *(const half8*)&BsH[c][kc];
                if constexpr (!BS) bl[n] = *(const half8*)&BsL[c][kc];
            }
            #pragma unroll
            for (int m = 0; m < 2; ++m)
                #pragma unroll
                for (int n = 0; n < 2; ++n) {
                    acc[m][n] = __builtin_amdgcn_mfma_f32_16x16x32_f16(a[m], bh[n], acc[m][n], 0, 0, 0);
                    if constexpr (!BS)
                        acc[m][n] = __builtin_amdgcn_mfma_f32_16x16x32_f16(a[m], bl[n], acc[m][n], 0, 0, 0);
                }
        }
        __syncthreads();
        if (ki + 1 < NK) { STORE(); __syncthreads(); }
    }

    // ---- transposed epilogue: acc -> LDS [64][65] -> whole-row float4 I/O ----
    float* eb = (float*)smem;
    #pragma unroll
    for (int m = 0; m < 2; ++m)
        #pragma unroll
        for (int n = 0; n < 2; ++n)
            #pragma unroll
            for (int r = 0; r < 4; ++r)
                eb[(wr * 32 + m * 16 + kg * 4 + r) * 65 + wc * 32 + n * 16 + lrow] = acc[m][n][r];
    __syncthreads();

    #pragma unroll
    for (int j = 0; j < 4; ++j) {
        const int row = wave * 16 + j * 4 + (lane >> 4);
        const int col = (lane & 15) * 4;
        const float4 v = *(const float4*)&eb[row * 65 + col];
        const size_t gi = (size_t)(brow + row) * ldc + bcol + col;
        if constexpr (EPI == 0) {
            if constexpr (EMIT != 4)
                *(float4*)(C + cks * ks + gi) = v;
            if constexpr (EMIT == 1) {
                us4 h;
                h.x = h_bits(v.x); h.y = h_bits(v.y);
                h.z = h_bits(v.z); h.w = h_bits(v.w);
                *(us4*)(Y2 + gi) = h;
            }
            if constexpr (EMIT == 2) {
                const HL a = split2h(v.x), b = split2h(v.y);
                const HL c2 = split2h(v.z), d = split2h(v.w);
                us4 h, l;
                h.x = a.h; l.x = a.l; h.y = b.h; l.y = b.l;
                h.z = c2.h; l.z = c2.l; h.w = d.h; l.w = d.l;
                *(us4*)(EH + gi) = h;
                *(us4*)(EL + gi) = l;
            }
            if constexpr (EMIT == 4) {
                us4 h;
                h.x = h_bits(v.x); h.y = h_bits(v.y);
                h.z = h_bits(v.z); h.w = h_bits(v.w);
                *(us4*)(Y2 + gi) = h;
                *(us4*)(EH + gi) = h;
            }
        } else if constexpr (EPI == 4) {
            us4 h;
            h.x = h_bits(v.x); h.y = h_bits(v.y);
            h.z = h_bits(v.z); h.w = h_bits(v.w);
            *(us4*)(Y2 + cks * ks + gi) = h;
        } else { // EPI == 3
            const float4 f1 = cvt4h(F1h + gi);
            float4 ww;
            if constexpr (FIRST) {
                ww.x = 0.0f; ww.y = 0.0f; ww.z = 0.0f; ww.w = 0.0f;
            } else {
                ww = cvt4h(Wh + gi);
            }
            const float f1v[4] = {f1.x, f1.y, f1.z, f1.w};
            const float wwv[4] = {ww.x, ww.y, ww.z, ww.w};
            const float vv[4]  = {v.x, v.y, v.z, v.w};
            float wn[4];
            #pragma unroll
            for (int q = 0; q < 4; ++q)
                wn[q] = f1v[q] + wwv[q] - clampl(wwv[q]) - vv[q];
            if constexpr (LASTZ) {
                float4 o;
                o.x = wn[0] - clampl(wn[0]); o.y = wn[1] - clampl(wn[1]);
                o.z = wn[2] - clampl(wn[2]); o.w = wn[3] - clampl(wn[3]);
                *(float4*)(OutZ + gi) = o;
            } else {
                us4 hh, y;
                #pragma unroll
                for (int q = 0; q < 4; ++q) {
                    ((unsigned short*)&hh)[q] = h_bits(wn[q]);
                    ((unsigned short*)&y)[q]  = h_bits(f1v[q] + wn[q] - 2.0f * clampl(wn[q]));
                }
                *(us4*)(Wh + gi) = hh;
                *(us4*)(Y2 + gi) = y;
            }
        }
    }
}

// Normalize rows of weight (3072x768); emit fp16 h/l of wn (row-major ONLY).
__global__ __launch_bounds__(256)
void rownorm_kernel(const float* __restrict__ W,
                    unsigned short* __restrict__ wnH, unsigned short* __restrict__ wnL)
{
    __shared__ float red[256];
    const int row = blockIdx.x;
    const int t = threadIdx.x;
    const float* wr = W + (size_t)row * NN_;
    float s = 0.0f;
    for (int k = t; k < NN_; k += 256) { const float w = wr[k]; s += w * w; }
    red[t] = s; __syncthreads();
    for (int off = 128; off > 0; off >>= 1) {
        if (t < off) red[t] += red[t + off];
        __syncthreads();
    }
    const float rn = 1.0f / sqrtf(red[0]);
    for (int k = t; k < NN_; k += 256) {
        const float v = wr[k] * rn;
        const HL s2 = split2h(v);
        wnH[(size_t)row * NN_ + k] = s2.h;
        wnL[(size_t)row * NN_ + k] = s2.l;
    }
}

// Tiled transpose: wn (3072x768) h/l -> wnT (768x3072) h/l, LDS-coalesced.
__global__ __launch_bounds__(256)
void transp_kernel(const unsigned short* __restrict__ SH,
                   const unsigned short* __restrict__ SL,
                   unsigned short* __restrict__ DH,
                   unsigned short* __restrict__ DL)
{
    __shared__ unsigned short tH[64][68];
    __shared__ unsigned short tL[64][68];
    const int tid = threadIdx.x;
    const int r0 = blockIdx.x * 64;
    const int c0 = blockIdx.y * 64;
    #pragma unroll
    for (int p = 0; p < 2; ++p) {
        const int idx = p * 256 + tid;
        const int r = idx >> 3, c8 = (idx & 7) * 8;
        const size_t g = (size_t)(r0 + r) * NN_ + c0 + c8;
        *(uint4*)&tH[r][c8] = *(const uint4*)(SH + g);
        *(uint4*)&tL[r][c8] = *(const uint4*)(SL + g);
    }
    __syncthreads();
    #pragma unroll
    for (int p = 0; p < 2; ++p) {
        const int idx = p * 256 + tid;
        const int k = idx >> 3, m8 = (idx & 7) * 8;
        us4 h0, h1, l0, l1;
        h0.x = tH[m8+0][k]; h0.y = tH[m8+1][k]; h0.z = tH[m8+2][k]; h0.w = tH[m8+3][k];
        h1.x = tH[m8+4][k]; h1.y = tH[m8+5][k]; h1.z = tH[m8+6][k]; h1.w = tH[m8+7][k];
        l0.x = tL[m8+0][k]; l0.y = tL[m8+1][k]; l0.z = tL[m8+2][k]; l0.w = tL[m8+3][k];
        l1.x = tL[m8+4][k]; l1.y = tL[m8+5][k]; l1.z = tL[m8+6][k]; l1.w = tL[m8+7][k];
        const size_t g = (size_t)(c0 + k) * MM + r0 + m8;
        *(us4*)(DH + g)     = h0;
        *(us4*)(DH + g + 4) = h1;
        *(us4*)(DL + g)     = l0;
        *(us4*)(DL + g + 4) = l1;
    }
}

__global__ __launch_bounds__(256)
void rowabs_kernel(const float* __restrict__ G, float* __restrict__ rowsum)
{
    __shared__ float red[256];
    const int row = blockIdx.x;
    const int t = threadIdx.x;
    const float* gr = G + (size_t)row * NN_;
    float s = 0.0f;
    for (int k = t; k < NN_; k += 256) s += fabsf(gr[k]);
    red[t] = s; __syncthreads();
    for (int off = 128; off > 0; off >>= 1) {
        if (t < off) red[t] += red[t + off];
        __syncthreads();
    }
    if (t == 0) rowsum[row] = red[0];
}

__global__ __launch_bounds__(256)
void cmax_kernel(const float* __restrict__ rowsum, float* __restrict__ cbuf)
{
    __shared__ float red[256];
    const int t = threadIdx.x;
    float mx = 0.0f;
    for (int k = t; k < NN_; k += 256) mx = fmaxf(mx, rowsum[k]);
    red[t] = mx; __syncthreads();
    for (int off = 128; off > 0; off >>= 1) {
        if (t < off) red[t] = fmaxf(red[t], red[t + off]);
        __syncthreads();
    }
    if (t == 0) cbuf[0] = 2.0f / (1.0f + red[0]);
}

__global__ __launch_bounds__(256)
void initdiag_kernel(float* __restrict__ X, const float* __restrict__ c)
{
    const int idx = blockIdx.x * 256 + threadIdx.x;
    const int p = idx / NN_, q = idx - p * NN_;
    X[idx] = (p == q) ? c[0] : 0.0f;
}

// dec = p0 + p1 (float4)
__global__ __launch_bounds__(256)
void add2_kernel(const float* __restrict__ p0, size_t ps, float* __restrict__ o)
{
    const size_t i = ((size_t)blockIdx.x * 256 + threadIdx.x) * 4;
    const float4 a = *(const float4*)(p0 + i);
    const float4 b = *(const float4*)(p0 + ps + i);
    float4 v;
    v.x = a.x + b.x; v.y = a.y + b.y;
    v.z = a.z + b.z; v.w = a.w + b.w;
    *(float4*)(o + i) = v;
}

extern "C" void kernel_launch(void* const* d_in, const int* in_sizes, int n_in,
                              void* d_out, int out_size, void* d_ws, size_t ws_size,
                              hipStream_t stream)
{
    const float* x = (const float*)d_in[0];   // (2048, 768)
    const float* w = (const float*)d_in[1];   // (3072, 768)

    float* out = (float*)d_out;
    float* z   = out;                          // (2048, 3072)
    float* dec = out + (size_t)BB * MM;        // (2048, 768)

    char* wsb = (char*)d_ws;
    size_t off = 0;
    auto alloc = [&](size_t bytes) -> void* {
        void* p = wsb + off;
        off += (bytes + 255) & ~(size_t)255;
        return p;
    };
    // --- persistent ---
    unsigned short* wnH  = (unsigned short*)alloc((size_t)MM * NN_ * 2);
    unsigned short* wnL  = (unsigned short*)alloc((size_t)MM * NN_ * 2);
    unsigned short* wnTH = (unsigned short*)alloc((size_t)MM * NN_ * 2);
    unsigned short* wnTL = (unsigned short*)alloc((size_t)MM * NN_ * 2);
    unsigned short* adh  = (unsigned short*)alloc((size_t)BB * MM * 2);  // fp16 adotb
    unsigned short* wbh  = (unsigned short*)alloc((size_t)BB * MM * 2);  // fp16 w state
    unsigned short* y2h  = (unsigned short*)alloc((size_t)BB * MM * 2);
    unsigned short* QH  = (unsigned short*)alloc((size_t)NN_ * NN_ * 2);
    unsigned short* QL  = (unsigned short*)alloc((size_t)NN_ * NN_ * 2);
    unsigned short* RTH = (unsigned short*)alloc((size_t)MM * NN_ * 2);
    unsigned short* RTL = (unsigned short*)alloc((size_t)MM * NN_ * 2);
    unsigned short* Thp = (unsigned short*)alloc((size_t)2 * BB * NN_ * 2); // fp16 T partials
    // --- overlay: NS temps (dead after RT) aliased with Tp (decode partials) ---
    const size_t overlay = off;
    float* G  = (float*)alloc((size_t)NN_ * NN_ * 4);
    unsigned short* GH  = (unsigned short*)alloc((size_t)NN_ * NN_ * 2);
    unsigned short* GL  = (unsigned short*)alloc((size_t)NN_ * NN_ * 2);
    float* X0 = (float*)alloc((size_t)NN_ * NN_ * 4);
    float* X1 = (float*)alloc((size_t)NN_ * NN_ * 4);
    float* Yb = (float*)alloc((size_t)NN_ * NN_ * 4);
    unsigned short* YbH = (unsigned short*)alloc((size_t)NN_ * NN_ * 2);
    unsigned short* YbL = (unsigned short*)alloc((size_t)NN_ * NN_ * 2);
    float* rowsum = (float*)alloc(NN_ * 4);
    float* cbuf   = (float*)alloc(256);
    float* Pp = (float*)alloc((size_t)4 * NN_ * NN_ * 4);  // split-K f32 partials
    // Tp aliases the NS-temp region; NS temps dead before first Tp use.
    float* Tp = (float*)(wsb + overlay);
    const size_t TPS = (size_t)BB * NN_;

    const dim3 blk(256);
    const dim3 gsk(NN_ / 64, NN_ / 64, 4);
    const int  RED = (NN_ * NN_ / 4) / 256;   // 576

    rownorm_kernel<<<MM, blk, 0, stream>>>(w, wnH, wnL);
    transp_kernel<<<dim3(MM / 64, NN_ / 64), blk, 0, stream>>>(wnH, wnL, wnTH, wnTL);

    // adotb = x @ wn^T (M2048 N3072 K768); emit y2_0 AND adh. BK=128, B single.
    gemm_big<128,32,48,1,8,24,0,1,0,4,0,0><<<1536, blk, 0, stream>>>(
        x, nullptr, NN_, 0, wnH, nullptr, NN_, nullptr, MM, 0, NN_,
        nullptr, nullptr, nullptr, y2h, adh, nullptr);

    // G = wn^T wn + I (768x768, K=3072), split-K=4 + reduce(+I, split)
    gemm_sk<1><<<gsk, blk, 0, stream>>>(
        nullptr, wnTH, wnTL, MM, wnTH, wnTL, MM, Pp, MM / 4);
    red_ns<1><<<RED, blk, 0, stream>>>(Pp, nullptr, G, GH, GL);

    rowabs_kernel<<<NN_, blk, 0, stream>>>(G, rowsum);
    cmax_kernel<<<1, blk, 0, stream>>>(rowsum, cbuf);
    initdiag_kernel<<<(NN_ * NN_) / 256, blk, 0, stream>>>(X0, cbuf);

    // Newton-Schulz X <- 2X - XGX, 7 iterations, split-K=4 per GEMM
    float* Xc = X0;
    float* Xn = X1;
    for (int it = 0; it < 7; ++it) {
        gemm_sk<0><<<gsk, blk, 0, stream>>>(
            Xc, nullptr, nullptr, NN_, GH, GL, NN_, Pp, NN_ / 4);
        red_ns<0><<<RED, blk, 0, stream>>>(Pp, nullptr, Yb, YbH, YbL);
        gemm_sk<0><<<gsk, blk, 0, stream>>>(
            Xc, nullptr, nullptr, NN_, YbH, YbL, NN_, Pp, NN_ / 4);
        red_ns<2><<<RED, blk, 0, stream>>>(Pp, Xc, Xn, QH, QL);
        float* t = Xc; Xc = Xn; Xn = t;
    }
    // QH/QL = fp16 split of G^{-1}

    // RT = wn @ Ginv (M3072 N768 K768); emit RTH/RTL. B 2-term, BK=64.
    gemm_big<64,48,12,1,12,6,1,0,0,2,0,0><<<576, blk, 0, stream>>>(
        nullptr, wnH, NN_, 0, QH, QL, NN_, Tp, NN_, 0, NN_,
        nullptr, nullptr, nullptr, nullptr, RTH, RTL);

    // ADMM loop: T = y2 @ wn -> fp16 partials Thp (KS=2, B single, BK=128);
    // w-update: A = Thp pair (AMODE=4), B = RT single fp16, BK=128.
    // it=0 uses FIRST=1 (w==0; no memset needed).
    for (int it = 0; it < 20; ++it) {
        gemm_big<128,32,12,2,16,6,1,1,4,0,0,0><<<768, blk, 0, stream>>>(
            nullptr, y2h, MM, 0, wnTH, nullptr, MM, nullptr, NN_, TPS, MM / 2,
            nullptr, nullptr, nullptr, Thp, nullptr, nullptr);
        if (it == 0) {
            gemm_big<128,32,48,1,8,24,4,1,3,0,0,1><<<1536, blk, 0, stream>>>(
                nullptr, Thp, NN_, TPS, RTH, nullptr, NN_, nullptr, MM, 0, NN_,
                adh, wbh, nullptr, y2h, nullptr, nullptr);
        } else if (it < 19) {
            gemm_big<128,32,48,1,8,24,4,1,3,0,0,0><<<1536, blk, 0, stream>>>(
                nullptr, Thp, NN_, TPS, RTH, nullptr, NN_, nullptr, MM, 0, NN_,
                adh, wbh, nullptr, y2h, nullptr, nullptr);
        } else {
            gemm_big<128,32,48,1,8,24,4,1,3,0,1,0><<<1536, blk, 0, stream>>>(
                nullptr, Thp, NN_, TPS, RTH, nullptr, NN_, nullptr, MM, 0, NN_,
                adh, wbh, z, y2h, nullptr, nullptr);
        }
    }

    // decoded = z @ wn (M2048 N768 K3072), KS=2 f32 partials + reduce.
    // BK=128, B single fp16.
    gemm_big<128,32,12,2,16,6,0,1,0,0,0,0><<<768, blk, 0, stream>>>(
        z, nullptr, MM, 0, wnTH, nullptr, MM, Tp, NN_, TPS, MM / 2,
        nullptr, nullptr, nullptr, nullptr, nullptr, nullptr);
    add2_kernel<<<(BB * NN_ / 4) / 256, blk, 0, stream>>>(Tp, TPS, dec);
}

// Round 24
// 1300.709 us; speedup vs baseline: 2.5935x; 1.0047x over previous
//
#include <hip/hip_runtime.h>
#include <math.h>

#define BB   2048
#define NN_  768
#define MM   3072
#define LAMBD 0.1f

typedef __attribute__((ext_vector_type(8))) _Float16 half8;
typedef __attribute__((ext_vector_type(4))) float  f32x4;
typedef __attribute__((ext_vector_type(4))) unsigned short us4;

union HB { _Float16 f; unsigned short u; };
struct HL { unsigned short h, l; };

__device__ __forceinline__ unsigned short h_bits(float f) {
    HB b; b.f = (_Float16)f; return b.u;
}
__device__ __forceinline__ HL split2h(float f) {
    HL r;
    HB b; b.f = (_Float16)f;
    r.h = b.u;
    const float fh = (float)b.f;
    HB c; c.f = (_Float16)(f - fh);
    r.l = c.u;
    return r;
}
__device__ __forceinline__ float clampl(float x) {
    return fminf(fmaxf(x, -LAMBD), LAMBD);
}
__device__ __forceinline__ float4 cvt4h(const unsigned short* p) {
    const us4 u = *(const us4*)p;
    HB a, b, c, d;
    a.u = u.x; b.u = u.y; c.u = u.z; d.u = u.w;
    float4 f;
    f.x = (float)a.f; f.y = (float)b.f; f.z = (float)c.f; f.w = (float)d.f;
    return f;
}

// ---------------------------------------------------------------------------
// Split-K small GEMM (768x768 out, fp16 3-term), 64x64 tile, BK=64,
// explicit named-register prefetch (R18/R21 style), single LDS buffer +
// transposed epilogue. Grid: (12, 12, KS).
// ---------------------------------------------------------------------------
template<int APRE>
__global__ __launch_bounds__(256)
void gemm_sk(const float* __restrict__ A,
             const unsigned short* __restrict__ Ah,
             const unsigned short* __restrict__ Al,
             int lda,
             const unsigned short* __restrict__ Bh,
             const unsigned short* __restrict__ Bl,
             int ldb,
             float* __restrict__ P, int Kper)
{
    // 4 matrices x [64][72] fp16 = 36864 B; epilogue needs 16640 B (fits).
    __shared__ __align__(16) char smem[36864];
    unsigned short (*AsH)[72] = (unsigned short (*)[72])(smem);
    unsigned short (*AsL)[72] = (unsigned short (*)[72])(smem + 9216);
    unsigned short (*BsH)[72] = (unsigned short (*)[72])(smem + 18432);
    unsigned short (*BsL)[72] = (unsigned short (*)[72])(smem + 27648);

    const int tid  = threadIdx.x;
    const int brow = blockIdx.y * 64;
    const int bcol = blockIdx.x * 64;
    const int koff = blockIdx.z * Kper;
    const int wave = tid >> 6, lane = tid & 63;
    const int wr = wave >> 1, wc = wave & 1;
    const int lrow = lane & 15, kg = lane >> 4;

    // stage mapping: row = tid>>2 (0..63), k16 = (tid&3)*16 -> 16 fp16 each
    const int srow = tid >> 2, sk16 = (tid & 3) << 4;

    // named prefetch registers (no arrays)
    uint4  rAh0, rAh1, rAl0, rAl1, rBh0, rBh1, rBl0, rBl1;
    float4 rF0, rF1, rF2, rF3;

    auto LOAD = [&](int k0) {
        const size_t ga = (size_t)(brow + srow) * lda + k0 + sk16;
        if constexpr (APRE) {
            rAh0 = *(const uint4*)(Ah + ga);
            rAh1 = *(const uint4*)(Ah + ga + 8);
            rAl0 = *(const uint4*)(Al + ga);
            rAl1 = *(const uint4*)(Al + ga + 8);
        } else {
            rF0 = *(const float4*)(A + ga);
            rF1 = *(const float4*)(A + ga + 4);
            rF2 = *(const float4*)(A + ga + 8);
            rF3 = *(const float4*)(A + ga + 12);
        }
        const size_t gb = (size_t)(bcol + srow) * ldb + k0 + sk16;
        rBh0 = *(const uint4*)(Bh + gb);
        rBh1 = *(const uint4*)(Bh + gb + 8);
        rBl0 = *(const uint4*)(Bl + gb);
        rBl1 = *(const uint4*)(Bl + gb + 8);
    };
    auto STORE = [&]() {
        if constexpr (APRE) {
            *(uint4*)&AsH[srow][sk16]     = rAh0;
            *(uint4*)&AsH[srow][sk16 + 8] = rAh1;
            *(uint4*)&AsL[srow][sk16]     = rAl0;
            *(uint4*)&AsL[srow][sk16 + 8] = rAl1;
        } else {
            const float vf[16] = {rF0.x, rF0.y, rF0.z, rF0.w,
                                  rF1.x, rF1.y, rF1.z, rF1.w,
                                  rF2.x, rF2.y, rF2.z, rF2.w,
                                  rF3.x, rF3.y, rF3.z, rF3.w};
            half8 h0, h1, l0, l1;
            #pragma unroll
            for (int j = 0; j < 8; ++j) {
                const HL s = split2h(vf[j]);
                HB hb, lb; hb.u = s.h; lb.u = s.l;
                h0[j] = hb.f; l0[j] = lb.f;
            }
            #pragma unroll
            for (int j = 0; j < 8; ++j) {
                const HL s = split2h(vf[8 + j]);
                HB hb, lb; hb.u = s.h; lb.u = s.l;
                h1[j] = hb.f; l1[j] = lb.f;
            }
            *(half8*)&AsH[srow][sk16]     = h0;
            *(half8*)&AsH[srow][sk16 + 8] = h1;
            *(half8*)&AsL[srow][sk16]     = l0;
            *(half8*)&AsL[srow][sk16 + 8] = l1;
        }
        *(uint4*)&BsH[srow][sk16]     = rBh0;
        *(uint4*)&BsH[srow][sk16 + 8] = rBh1;
        *(uint4*)&BsL[srow][sk16]     = rBl0;
        *(uint4*)&BsL[srow][sk16 + 8] = rBl1;
    };

    f32x4 acc[2][2];
    #pragma unroll
    for (int m = 0; m < 2; ++m)
        #pragma unroll
        for (int n = 0; n < 2; ++n)
            #pragma unroll
            for (int q = 0; q < 4; ++q) acc[m][n][q] = 0.0f;

    const int NK = Kper / 64;
    LOAD(koff);
    STORE();
    __syncthreads();

    for (int ki = 0; ki < NK; ++ki) {
        if (ki + 1 < NK) LOAD(koff + (ki + 1) * 64);

        #pragma unroll
        for (int sub = 0; sub < 2; ++sub) {
            const int kc = sub * 32 + kg * 8;
            half8 ahi[2], alo[2], bhi[2], blo[2];
            #pragma unroll
            for (int m = 0; m < 2; ++m) {
                const int r = wr * 32 + m * 16 + lrow;
                ahi[m] = *(const half8*)&AsH[r][kc];
                alo[m] = *(const half8*)&AsL[r][kc];
            }
            #pragma unroll
            for (int n = 0; n < 2; ++n) {
                const int c = wc * 32 + n * 16 + lrow;
                bhi[n] = *(const half8*)&BsH[c][kc];
                blo[n] = *(const half8*)&BsL[c][kc];
            }
            #pragma unroll
            for (int m = 0; m < 2; ++m)
                #pragma unroll
                for (int n = 0; n < 2; ++n) {
                    acc[m][n] = __builtin_amdgcn_mfma_f32_16x16x32_f16(ahi[m], bhi[n], acc[m][n], 0, 0, 0);
                    acc[m][n] = __builtin_amdgcn_mfma_f32_16x16x32_f16(ahi[m], blo[n], acc[m][n], 0, 0, 0);
                    acc[m][n] = __builtin_amdgcn_mfma_f32_16x16x32_f16(alo[m], bhi[n], acc[m][n], 0, 0, 0);
                }
        }
        __syncthreads();
        if (ki + 1 < NK) { STORE(); __syncthreads(); }
    }

    // transposed epilogue: acc -> LDS [64][65] -> coalesced float4 rows
    float* eb = (float*)smem;
    #pragma unroll
    for (int m = 0; m < 2; ++m)
        #pragma unroll
        for (int n = 0; n < 2; ++n)
            #pragma unroll
            for (int r = 0; r < 4; ++r)
                eb[(wr * 32 + m * 16 + kg * 4 + r) * 65 + wc * 32 + n * 16 + lrow] = acc[m][n][r];
    __syncthreads();
    float* Pk = P + (size_t)blockIdx.z * NN_ * NN_;
    #pragma unroll
    for (int j = 0; j < 4; ++j) {
        const int row = wave * 16 + j * 4 + (lane >> 4);
        const int col = (lane & 15) * 4;
        const float4 v = *(const float4*)&eb[row * 65 + col];
        *(float4*)(Pk + (size_t)(brow + row) * NN_ + bcol + col) = v;
    }
}

// Reduce 4 split-K partials with epilogue. MODE: 0 plain, 1 +I, 2 2*E1-sum.
template<int MODE>
__global__ __launch_bounds__(256)
void red_ns(const float* __restrict__ P,
            const float* __restrict__ E1,
            float* __restrict__ C,
            unsigned short* __restrict__ Ch,
            unsigned short* __restrict__ Cl)
{
    const size_t i4 = ((size_t)blockIdx.x * 256 + threadIdx.x) * 4;
    const size_t sz = (size_t)NN_ * NN_;
    float4 s = *(const float4*)(P + i4);
    const float4 s1 = *(const float4*)(P + sz + i4);
    const float4 s2 = *(const float4*)(P + 2 * sz + i4);
    const float4 s3 = *(const float4*)(P + 3 * sz + i4);
    s.x = (s.x + s1.x) + (s2.x + s3.x);
    s.y = (s.y + s1.y) + (s2.y + s3.y);
    s.z = (s.z + s1.z) + (s2.z + s3.z);
    s.w = (s.w + s1.w) + (s2.w + s3.w);
    float v[4] = {s.x, s.y, s.z, s.w};
    if constexpr (MODE == 1) {
        const int row = (int)(i4 / NN_);
        const int col = (int)(i4 - (size_t)row * NN_);
        #pragma unroll
        for (int j = 0; j < 4; ++j) if (row == col + j) v[j] += 1.0f;
    }
    if constexpr (MODE == 2) {
        const float4 e = *(const float4*)(E1 + i4);
        v[0] = 2.0f * e.x - v[0]; v[1] = 2.0f * e.y - v[1];
        v[2] = 2.0f * e.z - v[2]; v[3] = 2.0f * e.w - v[3];
    }
    float4 o; o.x = v[0]; o.y = v[1]; o.z = v[2]; o.w = v[3];
    *(float4*)(C + i4) = o;
    us4 h, l;
    const HL a = split2h(v[0]), b = split2h(v[1]);
    const HL c = split2h(v[2]), d = split2h(v[3]);
    h.x = a.h; l.x = a.l; h.y = b.h; l.y = b.l;
    h.z = c.h; l.z = c.l; h.w = d.h; l.w = d.l;
    *(us4*)(Ch + i4) = h;
    *(us4*)(Cl + i4) = l;
}

// ---------------------------------------------------------------------------
// Big fp16 GEMM: 64x64 tile, 4 waves (32x32), BK=64 or 128. (R21-proven.)
// AMODE: 0 f32 A -> cvt; 1 pre-cvt fp16 (Ah); 4 fp16 pair Ah/Ah+psz summed.
// BS: 1 = B single fp16 (Bh only); 0 = B 2-term h/l.
// EPI: 0 C=acc f32 (+EMIT); 3 ADMM w-update; 4 fp16 partial -> Y2[cks*ks+gi].
// EMIT: 0 none, 1 Y2=fp16, 2 EH/EL=split, 4 Y2+EH=fp16(acc), NO C.
// FIRST: EPI=3 with w==0 (skip Wh read; first ADMM iteration, no memset).
// ---------------------------------------------------------------------------
template<int BK, int NBM, int NBN, int KS, int PM, int PN, int AMODE, int BS, int EPI, int EMIT, int LASTZ, int FIRST>
__global__ __launch_bounds__(256)
void gemm_big(const float* __restrict__ A,
              const unsigned short* __restrict__ Ah,
              int lda, size_t psz,
              const unsigned short* __restrict__ Bh,
              const unsigned short* __restrict__ Bl,
              int ldb,
              float* __restrict__ C, int ldc, size_t cks, int Kper,
              const unsigned short* __restrict__ F1h,
              unsigned short* __restrict__ Wh,
              float* __restrict__ OutZ,
              unsigned short* __restrict__ Y2,
              unsigned short* __restrict__ EH,
              unsigned short* __restrict__ EL)
{
    static_assert(NBM % PM == 0 && NBN % PN == 0, "patch divides grid");
    constexpr int XM = NBM / PM, XN = NBN / PN;
    static_assert(XM * XN * KS == 8, "patches x KS must equal 8 XCDs");
    static_assert(PM * PN == (NBM * NBN * KS) / 8, "slot count");
    static_assert(BK == 64 || BK == 128, "BK");

    constexpr int LDR = BK + 8;
    constexpr int MSZ = 64 * LDR * 2;
    constexpr int SMB_STAGE = (BS ? 2 : 3) * MSZ;
    constexpr int SMB = SMB_STAGE > 16640 ? SMB_STAGE : 16640;
    __shared__ __align__(16) char smem[SMB];
    unsigned short (*AsH)[LDR] = (unsigned short (*)[LDR])(smem);
    unsigned short (*BsH)[LDR] = (unsigned short (*)[LDR])(smem + MSZ);
    unsigned short (*BsL)[LDR] = (unsigned short (*)[LDR])(smem + 2 * MSZ);

    const int bid  = blockIdx.x;
    const int xcd  = bid & 7;
    const int slot = bid >> 3;
    const int ks   = xcd % KS;
    const int rest = xcd / KS;
    const int xn   = rest % XN;
    const int xm   = rest / XN;
    const int m_   = xm * PM + slot / PN;
    const int n_   = xn * PN + slot % PN;
    const int brow = m_ * 64;
    const int bcol = n_ * 64;
    const int koff = ks * Kper;

    const int tid  = threadIdx.x;
    const int wave = tid >> 6, lane = tid & 63;
    const int wr = wave >> 1, wc = wave & 1;
    const int lrow = lane & 15, kg = lane >> 4;

    const int srow = tid >> 2, sk16 = (tid & 3) << 4;

    uint4  pA0, pA1, pA2, pA3, pB0, pB1, pB2, pB3;
    float4 pF[4];
    uint4  qA0, qA1, qA2, qA3, qB0, qB1;
    float4 qF[4];

    auto LOAD = [&](int k0) {
        {
            const size_t ga = (size_t)(brow + srow) * lda + k0 + sk16;
            if constexpr (AMODE == 1) {
                pA0 = *(const uint4*)(Ah + ga);
                pA1 = *(const uint4*)(Ah + ga + 8);
            } else if constexpr (AMODE == 4) {
                pA0 = *(const uint4*)(Ah + ga);
                pA1 = *(const uint4*)(Ah + ga + 8);
                pA2 = *(const uint4*)(Ah + ga + psz);
                pA3 = *(const uint4*)(Ah + ga + psz + 8);
            } else {
                pF[0] = *(const float4*)(A + ga);
                pF[1] = *(const float4*)(A + ga + 4);
                pF[2] = *(const float4*)(A + ga + 8);
                pF[3] = *(const float4*)(A + ga + 12);
            }
            const size_t gb = (size_t)(bcol + srow) * ldb + k0 + sk16;
            pB0 = *(const uint4*)(Bh + gb);
            pB1 = *(const uint4*)(Bh + gb + 8);
            if constexpr (!BS) {
                pB2 = *(const uint4*)(Bl + gb);
                pB3 = *(const uint4*)(Bl + gb + 8);
            }
        }
        if constexpr (BK == 128) {
            const size_t ga = (size_t)(brow + srow) * lda + k0 + 64 + sk16;
            if constexpr (AMODE == 1) {
                qA0 = *(const uint4*)(Ah + ga);
                qA1 = *(const uint4*)(Ah + ga + 8);
            } else if constexpr (AMODE == 4) {
                qA0 = *(const uint4*)(Ah + ga);
                qA1 = *(const uint4*)(Ah + ga + 8);
                qA2 = *(const uint4*)(Ah + ga + psz);
                qA3 = *(const uint4*)(Ah + ga + psz + 8);
            } else {
                qF[0] = *(const float4*)(A + ga);
                qF[1] = *(const float4*)(A + ga + 4);
                qF[2] = *(const float4*)(A + ga + 8);
                qF[3] = *(const float4*)(A + ga + 12);
            }
            const size_t gb = (size_t)(bcol + srow) * ldb + k0 + 64 + sk16;
            qB0 = *(const uint4*)(Bh + gb);
            qB1 = *(const uint4*)(Bh + gb + 8);
        }
    };
    auto STORE = [&]() {
        {
            if constexpr (AMODE == 1) {
                *(uint4*)&AsH[srow][sk16]     = pA0;
                *(uint4*)&AsH[srow][sk16 + 8] = pA1;
            } else if constexpr (AMODE == 4) {
                half8 s0 = *(half8*)&pA0 + *(half8*)&pA2;
                half8 s1 = *(half8*)&pA1 + *(half8*)&pA3;
                *(half8*)&AsH[srow][sk16]     = s0;
                *(half8*)&AsH[srow][sk16 + 8] = s1;
            } else {
                half8 h0, h1;
                h0[0] = (_Float16)pF[0].x; h0[1] = (_Float16)pF[0].y;
                h0[2] = (_Float16)pF[0].z; h0[3] = (_Float16)pF[0].w;
                h0[4] = (_Float16)pF[1].x; h0[5] = (_Float16)pF[1].y;
                h0[6] = (_Float16)pF[1].z; h0[7] = (_Float16)pF[1].w;
                h1[0] = (_Float16)pF[2].x; h1[1] = (_Float16)pF[2].y;
                h1[2] = (_Float16)pF[2].z; h1[3] = (_Float16)pF[2].w;
                h1[4] = (_Float16)pF[3].x; h1[5] = (_Float16)pF[3].y;
                h1[6] = (_Float16)pF[3].z; h1[7] = (_Float16)pF[3].w;
                *(half8*)&AsH[srow][sk16]     = h0;
                *(half8*)&AsH[srow][sk16 + 8] = h1;
            }
            *(uint4*)&BsH[srow][sk16]     = pB0;
            *(uint4*)&BsH[srow][sk16 + 8] = pB1;
            if constexpr (!BS) {
                *(uint4*)&BsL[srow][sk16]     = pB2;
                *(uint4*)&BsL[srow][sk16 + 8] = pB3;
            }
        }
        if constexpr (BK == 128) {
            const int k2 = 64 + sk16;
            if constexpr (AMODE == 1) {
                *(uint4*)&AsH[srow][k2]     = qA0;
                *(uint4*)&AsH[srow][k2 + 8] = qA1;
            } else if constexpr (AMODE == 4) {
                half8 s0 = *(half8*)&qA0 + *(half8*)&qA2;
                half8 s1 = *(half8*)&qA1 + *(half8*)&qA3;
                *(half8*)&AsH[srow][k2]     = s0;
                *(half8*)&AsH[srow][k2 + 8] = s1;
            } else {
                half8 h0, h1;
                h0[0] = (_Float16)qF[0].x; h0[1] = (_Float16)qF[0].y;
                h0[2] = (_Float16)qF[0].z; h0[3] = (_Float16)qF[0].w;
                h0[4] = (_Float16)qF[1].x; h0[5] = (_Float16)qF[1].y;
                h0[6] = (_Float16)qF[1].z; h0[7] = (_Float16)qF[1].w;
                h1[0] = (_Float16)qF[2].x; h1[1] = (_Float16)qF[2].y;
                h1[2] = (_Float16)qF[2].z; h1[3] = (_Float16)qF[2].w;
                h1[4] = (_Float16)qF[3].x; h1[5] = (_Float16)qF[3].y;
                h1[6] = (_Float16)qF[3].z; h1[7] = (_Float16)qF[3].w;
                *(half8*)&AsH[srow][k2]     = h0;
                *(half8*)&AsH[srow][k2 + 8] = h1;
            }
            *(uint4*)&BsH[srow][k2]     = qB0;
            *(uint4*)&BsH[srow][k2 + 8] = qB1;
        }
    };

    f32x4 acc[2][2];
    #pragma unroll
    for (int m = 0; m < 2; ++m)
        #pragma unroll
        for (int n = 0; n < 2; ++n)
            #pragma unroll
            for (int q = 0; q < 4; ++q) acc[m][n][q] = 0.0f;

    const int NK = Kper / BK;
    LOAD(koff);
    STORE();
    __syncthreads();

    for (int ki = 0; ki < NK; ++ki) {
        if (ki + 1 < NK) LOAD(koff + (ki + 1) * BK);

        #pragma unroll
        for (int kk = 0; kk < BK / 32; ++kk) {
            const int kc = kk * 32 + kg * 8;
            half8 a[2], bh[2], bl[2];
            #pragma unroll
            for (int m = 0; m < 2; ++m)
                a[m] = *(const half8*)&AsH[wr * 32 + m * 16 + lrow][kc];
            #pragma unroll
            for (int n = 0; n < 2; ++n) {
                const int c = wc * 32 + n * 16 + lrow;
                bh[n] = *(const half8*)&BsH[c][kc];
                if constexpr (!BS) bl[n] = *(const half8*)&BsL[c][kc];
            }
            #pragma unroll
            for (int m = 0; m < 2; ++m)
                #pragma unroll
                for (int n = 0; n < 2; ++n) {
                    acc[m][n] = __builtin_amdgcn_mfma_f32_16x16x32_f16(a[m], bh[n], acc[m][n], 0, 0, 0);
                    if constexpr (!BS)
                        acc[m][n] = __builtin_amdgcn_mfma_f32_16x16x32_f16(a[m], bl[n], acc[m][n], 0, 0, 0);
                }
        }
        __syncthreads();
        if (ki + 1 < NK) { STORE(); __syncthreads(); }
    }

    // ---- transposed epilogue: acc -> LDS [64][65] -> whole-row float4 I/O ----
    float* eb = (float*)smem;
    #pragma unroll
    for (int m = 0; m < 2; ++m)
        #pragma unroll
        for (int n = 0; n < 2; ++n)
            #pragma unroll
            for (int r = 0; r < 4; ++r)
                eb[(wr * 32 + m * 16 + kg * 4 + r) * 65 + wc * 32 + n * 16 + lrow] = acc[m][n][r];
    __syncthreads();

    #pragma unroll
    for (int j = 0; j < 4; ++j) {
        const int row = wave * 16 + j * 4 + (lane >> 4);
        const int col = (lane & 15) * 4;
        const float4 v = *(const float4*)&eb[row * 65 + col];
        const size_t gi = (size_t)(brow + row) * ldc + bcol + col;
        if constexpr (EPI == 0) {
            if constexpr (EMIT != 4)
                *(float4*)(C + cks * ks + gi) = v;
            if constexpr (EMIT == 1) {
                us4 h;
                h.x = h_bits(v.x); h.y = h_bits(v.y);
                h.z = h_bits(v.z); h.w = h_bits(v.w);
                *(us4*)(Y2 + gi) = h;
            }
            if constexpr (EMIT == 2) {
                const HL a = split2h(v.x), b = split2h(v.y);
                const HL c2 = split2h(v.z), d = split2h(v.w);
                us4 h, l;
                h.x = a.h; l.x = a.l; h.y = b.h; l.y = b.l;
                h.z = c2.h; l.z = c2.l; h.w = d.h; l.w = d.l;
                *(us4*)(EH + gi) = h;
                *(us4*)(EL + gi) = l;
            }
            if constexpr (EMIT == 4) {
                us4 h;
                h.x = h_bits(v.x); h.y = h_bits(v.y);
                h.z = h_bits(v.z); h.w = h_bits(v.w);
                *(us4*)(Y2 + gi) = h;
                *(us4*)(EH + gi) = h;
            }
        } else if constexpr (EPI == 4) {
            us4 h;
            h.x = h_bits(v.x); h.y = h_bits(v.y);
            h.z = h_bits(v.z); h.w = h_bits(v.w);
            *(us4*)(Y2 + cks * ks + gi) = h;
        } else { // EPI == 3
            const float4 f1 = cvt4h(F1h + gi);
            float4 ww;
            if constexpr (FIRST) {
                ww.x = 0.0f; ww.y = 0.0f; ww.z = 0.0f; ww.w = 0.0f;
            } else {
                ww = cvt4h(Wh + gi);
            }
            const float f1v[4] = {f1.x, f1.y, f1.z, f1.w};
            const float wwv[4] = {ww.x, ww.y, ww.z, ww.w};
            const float vv[4]  = {v.x, v.y, v.z, v.w};
            float wn[4];
            #pragma unroll
            for (int q = 0; q < 4; ++q)
                wn[q] = f1v[q] + wwv[q] - clampl(wwv[q]) - vv[q];
            if constexpr (LASTZ) {
                float4 o;
                o.x = wn[0] - clampl(wn[0]); o.y = wn[1] - clampl(wn[1]);
                o.z = wn[2] - clampl(wn[2]); o.w = wn[3] - clampl(wn[3]);
                *(float4*)(OutZ + gi) = o;
            } else {
                us4 hh, y;
                #pragma unroll
                for (int q = 0; q < 4; ++q) {
                    ((unsigned short*)&hh)[q] = h_bits(wn[q]);
                    ((unsigned short*)&y)[q]  = h_bits(f1v[q] + wn[q] - 2.0f * clampl(wn[q]));
                }
                *(us4*)(Wh + gi) = hh;
                *(us4*)(Y2 + gi) = y;
            }
        }
    }
}

// Normalize rows of weight (3072x768); emit fp16 h/l of wn (row-major ONLY).
__global__ __launch_bounds__(256)
void rownorm_kernel(const float* __restrict__ W,
                    unsigned short* __restrict__ wnH, unsigned short* __restrict__ wnL)
{
    __shared__ float red[256];
    const int row = blockIdx.x;
    const int t = threadIdx.x;
    const float* wr = W + (size_t)row * NN_;
    float s = 0.0f;
    for (int k = t; k < NN_; k += 256) { const float w = wr[k]; s += w * w; }
    red[t] = s; __syncthreads();
    for (int off = 128; off > 0; off >>= 1) {
        if (t < off) red[t] += red[t + off];
        __syncthreads();
    }
    const float rn = 1.0f / sqrtf(red[0]);
    for (int k = t; k < NN_; k += 256) {
        const float v = wr[k] * rn;
        const HL s2 = split2h(v);
        wnH[(size_t)row * NN_ + k] = s2.h;
        wnL[(size_t)row * NN_ + k] = s2.l;
    }
}

// Tiled transpose: wn (3072x768) h/l -> wnT (768x3072) h/l, LDS-coalesced.
__global__ __launch_bounds__(256)
void transp_kernel(const unsigned short* __restrict__ SH,
                   const unsigned short* __restrict__ SL,
                   unsigned short* __restrict__ DH,
                   unsigned short* __restrict__ DL)
{
    __shared__ unsigned short tH[64][68];
    __shared__ unsigned short tL[64][68];
    const int tid = threadIdx.x;
    const int r0 = blockIdx.x * 64;
    const int c0 = blockIdx.y * 64;
    #pragma unroll
    for (int p = 0; p < 2; ++p) {
        const int idx = p * 256 + tid;
        const int r = idx >> 3, c8 = (idx & 7) * 8;
        const size_t g = (size_t)(r0 + r) * NN_ + c0 + c8;
        *(uint4*)&tH[r][c8] = *(const uint4*)(SH + g);
        *(uint4*)&tL[r][c8] = *(const uint4*)(SL + g);
    }
    __syncthreads();
    #pragma unroll
    for (int p = 0; p < 2; ++p) {
        const int idx = p * 256 + tid;
        const int k = idx >> 3, m8 = (idx & 7) * 8;
        us4 h0, h1, l0, l1;
        h0.x = tH[m8+0][k]; h0.y = tH[m8+1][k]; h0.z = tH[m8+2][k]; h0.w = tH[m8+3][k];
        h1.x = tH[m8+4][k]; h1.y = tH[m8+5][k]; h1.z = tH[m8+6][k]; h1.w = tH[m8+7][k];
        l0.x = tL[m8+0][k]; l0.y = tL[m8+1][k]; l0.z = tL[m8+2][k]; l0.w = tL[m8+3][k];
        l1.x = tL[m8+4][k]; l1.y = tL[m8+5][k]; l1.z = tL[m8+6][k]; l1.w = tL[m8+7][k];
        const size_t g = (size_t)(c0 + k) * MM + r0 + m8;
        *(us4*)(DH + g)     = h0;
        *(us4*)(DH + g + 4) = h1;
        *(us4*)(DL + g)     = l0;
        *(us4*)(DL + g + 4) = l1;
    }
}

__global__ __launch_bounds__(256)
void rowabs_kernel(const float* __restrict__ G, float* __restrict__ rowsum)
{
    __shared__ float red[256];
    const int row = blockIdx.x;
    const int t = threadIdx.x;
    const float* gr = G + (size_t)row * NN_;
    float s = 0.0f;
    for (int k = t; k < NN_; k += 256) s += fabsf(gr[k]);
    red[t] = s; __syncthreads();
    for (int off = 128; off > 0; off >>= 1) {
        if (t < off) red[t] += red[t + off];
        __syncthreads();
    }
    if (t == 0) rowsum[row] = red[0];
}

__global__ __launch_bounds__(256)
void cmax_kernel(const float* __restrict__ rowsum, float* __restrict__ cbuf)
{
    __shared__ float red[256];
    const int t = threadIdx.x;
    float mx = 0.0f;
    for (int k = t; k < NN_; k += 256) mx = fmaxf(mx, rowsum[k]);
    red[t] = mx; __syncthreads();
    for (int off = 128; off > 0; off >>= 1) {
        if (t < off) red[t] = fmaxf(red[t], red[t + off]);
        __syncthreads();
    }
    if (t == 0) cbuf[0] = 2.0f / (1.0f + red[0]);
}

__global__ __launch_bounds__(256)
void initdiag_kernel(float* __restrict__ X, const float* __restrict__ c)
{
    const int idx = blockIdx.x * 256 + threadIdx.x;
    const int p = idx / NN_, q = idx - p * NN_;
    X[idx] = (p == q) ? c[0] : 0.0f;
}

// dec = p0 + p1 (float4)
__global__ __launch_bounds__(256)
void add2_kernel(const float* __restrict__ p0, size_t ps, float* __restrict__ o)
{
    const size_t i = ((size_t)blockIdx.x * 256 + threadIdx.x) * 4;
    const float4 a = *(const float4*)(p0 + i);
    const float4 b = *(const float4*)(p0 + ps + i);
    float4 v;
    v.x = a.x + b.x; v.y = a.y + b.y;
    v.z = a.z + b.z; v.w = a.w + b.w;
    *(float4*)(o + i) = v;
}

extern "C" void kernel_launch(void* const* d_in, const int* in_sizes, int n_in,
                              void* d_out, int out_size, void* d_ws, size_t ws_size,
                              hipStream_t stream)
{
    const float* x = (const float*)d_in[0];   // (2048, 768)
    const float* w = (const float*)d_in[1];   // (3072, 768)

    float* out = (float*)d_out;
    float* z   = out;                          // (2048, 3072)
    float* dec = out + (size_t)BB * MM;        // (2048, 768)

    char* wsb = (char*)d_ws;
    size_t off = 0;
    auto alloc = [&](size_t bytes) -> void* {
        void* p = wsb + off;
        off += (bytes + 255) & ~(size_t)255;
        return p;
    };
    // --- persistent ---
    unsigned short* wnH  = (unsigned short*)alloc((size_t)MM * NN_ * 2);
    unsigned short* wnL  = (unsigned short*)alloc((size_t)MM * NN_ * 2);
    unsigned short* wnTH = (unsigned short*)alloc((size_t)MM * NN_ * 2);
    unsigned short* wnTL = (unsigned short*)alloc((size_t)MM * NN_ * 2);
    unsigned short* adh  = (unsigned short*)alloc((size_t)BB * MM * 2);  // fp16 adotb
    unsigned short* wbh  = (unsigned short*)alloc((size_t)BB * MM * 2);  // fp16 w state
    unsigned short* y2h  = (unsigned short*)alloc((size_t)BB * MM * 2);
    unsigned short* QH  = (unsigned short*)alloc((size_t)NN_ * NN_ * 2);
    unsigned short* QL  = (unsigned short*)alloc((size_t)NN_ * NN_ * 2);
    unsigned short* RTH = (unsigned short*)alloc((size_t)MM * NN_ * 2);
    unsigned short* RTL = (unsigned short*)alloc((size_t)MM * NN_ * 2);
    unsigned short* Thp = (unsigned short*)alloc((size_t)2 * BB * NN_ * 2); // fp16 T partials
    // --- overlay: NS temps (dead after RT) aliased with Tp (decode partials) ---
    const size_t overlay = off;
    float* G  = (float*)alloc((size_t)NN_ * NN_ * 4);
    unsigned short* GH  = (unsigned short*)alloc((size_t)NN_ * NN_ * 2);
    unsigned short* GL  = (unsigned short*)alloc((size_t)NN_ * NN_ * 2);
    float* X0 = (float*)alloc((size_t)NN_ * NN_ * 4);
    float* X1 = (float*)alloc((size_t)NN_ * NN_ * 4);
    float* Yb = (float*)alloc((size_t)NN_ * NN_ * 4);
    unsigned short* YbH = (unsigned short*)alloc((size_t)NN_ * NN_ * 2);
    unsigned short* YbL = (unsigned short*)alloc((size_t)NN_ * NN_ * 2);
    float* rowsum = (float*)alloc(NN_ * 4);
    float* cbuf   = (float*)alloc(256);
    float* Pp = (float*)alloc((size_t)4 * NN_ * NN_ * 4);  // split-K f32 partials
    // Tp aliases the NS-temp region; NS temps dead before first Tp use.
    float* Tp = (float*)(wsb + overlay);
    const size_t TPS = (size_t)BB * NN_;

    const dim3 blk(256);
    const dim3 gsk(NN_ / 64, NN_ / 64, 4);
    const int  RED = (NN_ * NN_ / 4) / 256;   // 576

    rownorm_kernel<<<MM, blk, 0, stream>>>(w, wnH, wnL);
    transp_kernel<<<dim3(MM / 64, NN_ / 64), blk, 0, stream>>>(wnH, wnL, wnTH, wnTL);

    // adotb = x @ wn^T (M2048 N3072 K768); emit y2_0 AND adh. BK=128, B single.
    gemm_big<128,32,48,1,8,24,0,1,0,4,0,0><<<1536, blk, 0, stream>>>(
        x, nullptr, NN_, 0, wnH, nullptr, NN_, nullptr, MM, 0, NN_,
        nullptr, nullptr, nullptr, y2h, adh, nullptr);

    // G = wn^T wn + I (768x768, K=3072), split-K=4 + reduce(+I, split). BK=64.
    gemm_sk<1><<<gsk, blk, 0, stream>>>(
        nullptr, wnTH, wnTL, MM, wnTH, wnTL, MM, Pp, MM / 4);
    red_ns<1><<<RED, blk, 0, stream>>>(Pp, nullptr, G, GH, GL);

    rowabs_kernel<<<NN_, blk, 0, stream>>>(G, rowsum);
    cmax_kernel<<<1, blk, 0, stream>>>(rowsum, cbuf);
    initdiag_kernel<<<(NN_ * NN_) / 256, blk, 0, stream>>>(X0, cbuf);

    // Newton-Schulz X <- 2X - XGX, 7 iterations, split-K=4 per GEMM. BK=64.
    float* Xc = X0;
    float* Xn = X1;
    for (int it = 0; it < 7; ++it) {
        gemm_sk<0><<<gsk, blk, 0, stream>>>(
            Xc, nullptr, nullptr, NN_, GH, GL, NN_, Pp, NN_ / 4);
        red_ns<0><<<RED, blk, 0, stream>>>(Pp, nullptr, Yb, YbH, YbL);
        gemm_sk<0><<<gsk, blk, 0, stream>>>(
            Xc, nullptr, nullptr, NN_, YbH, YbL, NN_, Pp, NN_ / 4);
        red_ns<2><<<RED, blk, 0, stream>>>(Pp, Xc, Xn, QH, QL);
        float* t = Xc; Xc = Xn; Xn = t;
    }
    // QH/QL = fp16 split of G^{-1}

    // RT = wn @ Ginv (M3072 N768 K768); emit RTH/RTL. B 2-term, BK=64.
    gemm_big<64,48,12,1,12,6,1,0,0,2,0,0><<<576, blk, 0, stream>>>(
        nullptr, wnH, NN_, 0, QH, QL, NN_, Tp, NN_, 0, NN_,
        nullptr, nullptr, nullptr, nullptr, RTH, RTL);

    // ADMM loop: T = y2 @ wn -> fp16 partials Thp (KS=2, B single, BK=128);
    // w-update: A = Thp pair (AMODE=4), B = RT single fp16, BK=128.
    // it=0 uses FIRST=1 (w==0; no memset needed).
    for (int it = 0; it < 20; ++it) {
        gemm_big<128,32,12,2,16,6,1,1,4,0,0,0><<<768, blk, 0, stream>>>(
            nullptr, y2h, MM, 0, wnTH, nullptr, MM, nullptr, NN_, TPS, MM / 2,
            nullptr, nullptr, nullptr, Thp, nullptr, nullptr);
        if (it == 0) {
            gemm_big<128,32,48,1,8,24,4,1,3,0,0,1><<<1536, blk, 0, stream>>>(
                nullptr, Thp, NN_, TPS, RTH, nullptr, NN_, nullptr, MM, 0, NN_,
                adh, wbh, nullptr, y2h, nullptr, nullptr);
        } else if (it < 19) {
            gemm_big<128,32,48,1,8,24,4,1,3,0,0,0><<<1536, blk, 0, stream>>>(
                nullptr, Thp, NN_, TPS, RTH, nullptr, NN_, nullptr, MM, 0, NN_,
                adh, wbh, nullptr, y2h, nullptr, nullptr);
        } else {
            gemm_big<128,32,48,1,8,24,4,1,3,0,1,0><<<1536, blk, 0, stream>>>(
                nullptr, Thp, NN_, TPS, RTH, nullptr, NN_, nullptr, MM, 0, NN_,
                adh, wbh, z, y2h, nullptr, nullptr);
        }
    }

    // decoded = z @ wn (M2048 N768 K3072), KS=2 f32 partials + reduce.
    // BK=128, B single fp16.
    gemm_big<128,32,12,2,16,6,0,1,0,0,0,0><<<768, blk, 0, stream>>>(
        z, nullptr, MM, 0, wnTH, nullptr, MM, Tp, NN_, TPS, MM / 2,
        nullptr, nullptr, nullptr, nullptr, nullptr, nullptr);
    add2_kernel<<<(BB * NN_ / 4) / 256, blk, 0, stream>>>(Tp, TPS, dec);
}